// Round 1
// baseline (2685.907 us; speedup 1.0000x reference)
//
#include <hip/hip_runtime.h>

// CAPTNet block, fp32. B=8, CIN=3, H=W=256, DIM=48, HEADS=4 (ch=12), HID=96.
// Plan:
//  k1: xp = conv1x1(x, 3->48)                       [write xp 100MB]
//  k2: per 16x16 tile (18x18 halo in LDS):
//      t = LN1(xp); u = conv1x1(t) per 48-ch group (q,k,v); dwconv3x3;
//      q,k kept in regs -> LDS; Gram G[c,d], |q|^2, |k|^2 partials -> atomics;
//      v written to HBM.                             [read xp, write v]
//  k3: finalize attn (normalize, *temp, softmax 12-wide), fold attn_out_w:
//      M_b[48][48] = W @ blockdiag(attn)             [tiny]
//  k4: xp += M_b @ v + attn_out_b  (in-place, pixel-local)
//  k5: per tile: t = xp2 (keep s0 = out_proj_w @ xp2), LN2, conv1x1 48->192
//      in 4 groups of (24 y1 + 24 y2), dwconv, gate, ffn_out conv accum,
//      final out = s0 + out_proj_w @ (ffn + ffn_out_b) + out_proj_b.
// ws layout (floats): xp[8*48*65536] | v[8*48*65536] | red[8*672] | M[8*2304]
//   = 201.4 MB total.

#define NPIX 65536
#define HP3 324   // 18*18 halo pixels
#define HS 18

__device__ __forceinline__ void load_tile48(const float* __restrict__ src, float* t,
                                            int tid, int ty0, int tx0) {
  for (int i = tid; i < 48 * HP3; i += 256) {
    const int c = i / HP3, p = i - c * HP3;
    const int hy = p / HS, hx = p - hy * HS;
    const int gy = ty0 + hy - 1, gx = tx0 + hx - 1;
    float val = 0.f;
    if (((unsigned)gy < 256u) && ((unsigned)gx < 256u))
      val = src[c * NPIX + (gy << 8) + gx];
    t[i] = val;
  }
}

__device__ __forceinline__ void ln_inplace(float* t, const float* __restrict__ w,
                                           const float* __restrict__ b, int tid) {
  for (int p = tid; p < HP3; p += 256) {
    float mu = 0.f;
    for (int c = 0; c < 48; ++c) mu += t[c * HP3 + p];
    mu *= (1.f / 48.f);
    float var = 0.f;
    for (int c = 0; c < 48; ++c) { float d = t[c * HP3 + p] - mu; var += d * d; }
    var *= (1.f / 48.f);
    const float rs = rsqrtf(var + 1e-6f);
    for (int c = 0; c < 48; ++c)
      t[c * HP3 + p] = (t[c * HP3 + p] - mu) * rs * w[c] + b[c];
  }
}

// u[o][p] = sum_c wT[c][o] * t[c][p] + bias[o], forced 0 outside the image.
__device__ __forceinline__ void conv1x1_48x48(const float* t, const float* wT,
                                              const float* bias, float* u,
                                              int tid, int ty0, int tx0) {
  for (int uu = tid; uu < HP3; uu += 256) {   // 324 units: 4 o-blocks x 81 px-chunks
    const int ob = uu & 3, chunk = uu >> 2;
    const int p0 = chunk * 4, o0 = ob * 12;
    float acc[12][4];
#pragma unroll
    for (int j = 0; j < 12; ++j) {
      acc[j][0] = 0.f; acc[j][1] = 0.f; acc[j][2] = 0.f; acc[j][3] = 0.f;
    }
#pragma unroll 4
    for (int c = 0; c < 48; ++c) {
      const float4 tv = *(const float4*)&t[c * HP3 + p0];
      const float4 w0 = *(const float4*)&wT[c * 48 + o0];
      const float4 w1 = *(const float4*)&wT[c * 48 + o0 + 4];
      const float4 w2 = *(const float4*)&wT[c * 48 + o0 + 8];
      const float wj[12] = {w0.x, w0.y, w0.z, w0.w, w1.x, w1.y, w1.z, w1.w,
                            w2.x, w2.y, w2.z, w2.w};
#pragma unroll
      for (int j = 0; j < 12; ++j) {
        acc[j][0] += wj[j] * tv.x; acc[j][1] += wj[j] * tv.y;
        acc[j][2] += wj[j] * tv.z; acc[j][3] += wj[j] * tv.w;
      }
    }
#pragma unroll
    for (int pp = 0; pp < 4; ++pp) {
      const int p = p0 + pp;
      const int hy = p / HS, hx = p - hy * HS;
      const int gy = ty0 + hy - 1, gx = tx0 + hx - 1;
      const bool ok = ((unsigned)gy < 256u) && ((unsigned)gx < 256u);
#pragma unroll
      for (int j = 0; j < 12; ++j)
        u[(o0 + j) * HP3 + p] = ok ? (acc[j][pp] + bias[o0 + j]) : 0.f;
    }
  }
}

__device__ __forceinline__ float dw3x3(const float* ur, const float* __restrict__ w) {
  return w[0] * ur[-HS - 1] + w[1] * ur[-HS] + w[2] * ur[-HS + 1]
       + w[3] * ur[-1]      + w[4] * ur[0]   + w[5] * ur[1]
       + w[6] * ur[HS - 1]  + w[7] * ur[HS]  + w[8] * ur[HS + 1];
}

// ---------------- k1: xp = conv1x1(x, 3->48) ----------------
__global__ __launch_bounds__(256) void k1_inproj(const float* __restrict__ x,
                                                 const float* __restrict__ w,
                                                 const float* __restrict__ b,
                                                 float* __restrict__ xp) {
  const int idx = blockIdx.x * 256 + threadIdx.x;   // 8*65536 total
  const int bb = idx >> 16;
  const int n = idx & 65535;
  const float x0 = x[(bb * 3 + 0) * NPIX + n];
  const float x1 = x[(bb * 3 + 1) * NPIX + n];
  const float x2 = x[(bb * 3 + 2) * NPIX + n];
  float* xpb = xp + (size_t)bb * 48 * NPIX;
#pragma unroll
  for (int o = 0; o < 48; ++o)
    xpb[o * NPIX + n] = w[o * 3] * x0 + w[o * 3 + 1] * x1 + w[o * 3 + 2] * x2 + b[o];
}

// ---------------- k2: qkv + Gram/norm partials + v ----------------
__global__ __launch_bounds__(256) void k2_qkv(
    const float* __restrict__ xp, const float* __restrict__ lnw,
    const float* __restrict__ lnb, const float* __restrict__ qw,
    const float* __restrict__ qb, const float* __restrict__ dww,
    const float* __restrict__ dwb, float* __restrict__ vout,
    float* __restrict__ red) {
  __shared__ __align__(16) float t[48 * HP3];
  __shared__ __align__(16) float u[48 * HP3];
  __shared__ __align__(16) float wqT[48 * 48];
  __shared__ float wbias[48];
  float* qs = t;   // [48][260] after t is dead (12480 <= 15552)
  float* ks = u;   // [48][260]
  const int QP = 260;

  const int tid = threadIdx.x;
  const int bb = blockIdx.x >> 8;
  const int tile = blockIdx.x & 255;
  const int ty0 = (tile >> 4) << 4, tx0 = (tile & 15) << 4;
  const float* xpb = xp + (size_t)bb * 48 * NPIX;

  load_tile48(xpb, t, tid, ty0, tx0);
  __syncthreads();
  ln_inplace(t, lnw, lnb, tid);

  const int py = tid >> 4, px = tid & 15;
  const int hp = (py + 1) * HS + (px + 1);
  const int gn = ((ty0 + py) << 8) + (tx0 + px);

  float qreg[48], kreg[48];

#pragma unroll
  for (int grp = 0; grp < 3; ++grp) {
    const int cb = grp * 48;
    __syncthreads();   // prev dwconv done / LN done
    for (int i = tid; i < 2304; i += 256) {
      const int o = i / 48, c = i - o * 48;
      wqT[c * 48 + o] = qw[(cb + o) * 48 + c];
    }
    if (tid < 48) wbias[tid] = qb[cb + tid];
    __syncthreads();
    conv1x1_48x48(t, wqT, wbias, u, tid, ty0, tx0);
    __syncthreads();
#pragma unroll
    for (int o = 0; o < 48; ++o) {
      const int cc = cb + o;
      const float s = dwb[cc] + dw3x3(&u[o * HP3 + hp], &dww[cc * 9]);
      if (grp == 0) qreg[o] = s;
      else if (grp == 1) kreg[o] = s;
      else vout[((size_t)bb * 48 + o) * NPIX + gn] = s;
    }
  }
  __syncthreads();   // t,u free now
#pragma unroll
  for (int c = 0; c < 48; ++c) {
    qs[c * QP + tid] = qreg[c];
    ks[c * QP + tid] = kreg[c];
  }
  __syncthreads();
  // 672 reduction entries per (b): per head h: G[12][12] | sum q^2 [12] | sum k^2 [12]
  for (int e = tid; e < 672; e += 256) {
    const int h = e / 168, r = e - h * 168;
    float s = 0.f;
    if (r < 144) {
      const int c = r / 12, d = r - 12 * (r / 12);
      const float4* qa = (const float4*)&qs[(h * 12 + c) * QP];
      const float4* kb = (const float4*)&ks[(h * 12 + d) * QP];
      for (int p4 = 0; p4 < 64; ++p4) {
        const float4 a = qa[p4], b2 = kb[p4];
        s += a.x * b2.x + a.y * b2.y + a.z * b2.z + a.w * b2.w;
      }
    } else if (r < 156) {
      const float4* qa = (const float4*)&qs[(h * 12 + (r - 144)) * QP];
      for (int p4 = 0; p4 < 64; ++p4) {
        const float4 a = qa[p4];
        s += a.x * a.x + a.y * a.y + a.z * a.z + a.w * a.w;
      }
    } else {
      const float4* kb = (const float4*)&ks[(h * 12 + (r - 156)) * QP];
      for (int p4 = 0; p4 < 64; ++p4) {
        const float4 a = kb[p4];
        s += a.x * a.x + a.y * a.y + a.z * a.z + a.w * a.w;
      }
    }
    atomicAdd(&red[bb * 672 + e], s);
  }
}

// ---------------- k3: finalize attn, build fused M ----------------
__global__ __launch_bounds__(256) void k3_attn(const float* __restrict__ red,
                                               const float* __restrict__ temp,
                                               const float* __restrict__ aow,
                                               float* __restrict__ Mws) {
  __shared__ float attn[4 * 144];
  const int b = blockIdx.x, tid = threadIdx.x;
  const float* rb = red + b * 672;
  for (int e = tid; e < 576; e += 256) {
    const int h = e / 144, r = e - h * 144;
    const int c = r / 12, d = r - c * 12;
    const float g = rb[h * 168 + r];
    const float nq = fmaxf(sqrtf(rb[h * 168 + 144 + c]), 1e-12f);
    const float nk = fmaxf(sqrtf(rb[h * 168 + 156 + d]), 1e-12f);
    attn[e] = g / (nq * nk) * temp[h];
  }
  __syncthreads();
  if (tid < 48) {
    const int h = tid / 12, c = tid - h * 12;
    float* row = &attn[h * 144 + c * 12];
    float m = row[0];
    for (int d = 1; d < 12; ++d) m = fmaxf(m, row[d]);
    float s = 0.f;
    for (int d = 0; d < 12; ++d) { const float e2 = expf(row[d] - m); row[d] = e2; s += e2; }
    const float inv = 1.f / s;
    for (int d = 0; d < 12; ++d) row[d] *= inv;
  }
  __syncthreads();
  // M[o][h*12+d] = sum_c aow[o][h*12+c] * attn[h][c][d]
  for (int e = tid; e < 2304; e += 256) {
    const int o = e / 48, j = e - o * 48;
    const int h = j / 12, d = j - h * 12;
    float s = 0.f;
    for (int c = 0; c < 12; ++c)
      s += aow[o * 48 + h * 12 + c] * attn[h * 144 + c * 12 + d];
    Mws[b * 2304 + e] = s;
  }
}

// ---------------- k4: xp += M_b @ v + attn_out_b (in-place) ----------------
__global__ __launch_bounds__(256) void k4_attnout(const float* __restrict__ vbuf,
                                                  const float* __restrict__ Mws,
                                                  const float* __restrict__ aob,
                                                  float* __restrict__ xp) {
  __shared__ __align__(16) float MT[2304];   // MT[j][o]
  const int tid = threadIdx.x;
  const int b = blockIdx.x >> 8;
  const int n = ((blockIdx.x & 255) << 8) + tid;
  for (int i = tid; i < 2304; i += 256) {
    const int o = i / 48, j = i - o * 48;
    MT[j * 48 + o] = Mws[b * 2304 + i];
  }
  __syncthreads();
  const float* vb = vbuf + (size_t)b * 48 * NPIX;
  float vv[48];
#pragma unroll
  for (int j = 0; j < 48; ++j) vv[j] = vb[j * NPIX + n];
  float y[48];
#pragma unroll
  for (int o = 0; o < 48; ++o) y[o] = aob[o];
  for (int j = 0; j < 48; ++j) {
    const float vj = vv[j];
    const float* mr = &MT[j * 48];
#pragma unroll
    for (int o4 = 0; o4 < 12; ++o4) {
      const float4 m = *(const float4*)&mr[o4 * 4];
      y[o4 * 4 + 0] += m.x * vj; y[o4 * 4 + 1] += m.y * vj;
      y[o4 * 4 + 2] += m.z * vj; y[o4 * 4 + 3] += m.w * vj;
    }
  }
  float* xpb = xp + (size_t)b * 48 * NPIX;
#pragma unroll
  for (int o = 0; o < 48; ++o) xpb[o * NPIX + n] += y[o];
}

// ---------------- k5: FFN + residual + out_proj ----------------
__global__ __launch_bounds__(256) void k5_ffn(
    const float* __restrict__ xp2, const float* __restrict__ lnw,
    const float* __restrict__ lnb, const float* __restrict__ fiw,
    const float* __restrict__ fib, const float* __restrict__ dww,
    const float* __restrict__ dwb, const float* __restrict__ fow,
    const float* __restrict__ fob, const float* __restrict__ opw,
    const float* __restrict__ opb, float* __restrict__ out) {
  __shared__ __align__(16) float t[48 * HP3];
  __shared__ __align__(16) float u[48 * HP3];
  __shared__ __align__(16) float wt[48 * 48];
  __shared__ __align__(16) float fowT[96 * 48];
  __shared__ float wbias[48];

  const int tid = threadIdx.x;
  const int bb = blockIdx.x >> 8;
  const int tile = blockIdx.x & 255;
  const int ty0 = (tile >> 4) << 4, tx0 = (tile & 15) << 4;
  const float* xpb = xp2 + (size_t)bb * 48 * NPIX;

  load_tile48(xpb, t, tid, ty0, tx0);
  for (int i = tid; i < 96 * 48; i += 256) {   // fowT[c][o] = fow[o*96+c]
    const int o = i / 96, c = i - o * 96;
    fowT[c * 48 + o] = fow[i];
  }
  __syncthreads();

  const int py = tid >> 4, px = tid & 15;
  const int hp = (py + 1) * HS + (px + 1);
  const int gn = ((ty0 + py) << 8) + (tx0 + px);

  // s0[oo] = out_proj_w[oo] . xp2 (residual part), from raw t before LN
  float s0[3] = {0.f, 0.f, 0.f};
  for (int c = 0; c < 48; ++c) {
    const float val = t[c * HP3 + hp];
    s0[0] += opw[c] * val; s0[1] += opw[48 + c] * val; s0[2] += opw[96 + c] * val;
  }
  __syncthreads();
  ln_inplace(t, lnw, lnb, tid);

  float facc[48];
#pragma unroll
  for (int o = 0; o < 48; ++o) facc[o] = fob[o];

  for (int grp = 0; grp < 4; ++grp) {
    __syncthreads();   // LN done / prev dwconv done
    for (int i = tid; i < 2304; i += 256) {
      const int o = i / 48, c = i - o * 48;
      const int ch = (o < 24) ? (grp * 24 + o) : (96 + grp * 24 + o - 24);
      wt[c * 48 + o] = fiw[ch * 48 + c];
    }
    if (tid < 48) {
      const int ch = (tid < 24) ? (grp * 24 + tid) : (96 + grp * 24 + tid - 24);
      wbias[tid] = fib[ch];
    }
    __syncthreads();
    conv1x1_48x48(t, wt, wbias, u, tid, ty0, tx0);
    __syncthreads();
    for (int j = 0; j < 24; ++j) {
      const int c1 = grp * 24 + j, c2 = 96 + c1;
      const float a  = dwb[c1] + dw3x3(&u[j * HP3 + hp], &dww[c1 * 9]);
      const float b2 = dwb[c2] + dw3x3(&u[(24 + j) * HP3 + hp], &dww[c2 * 9]);
      const float gate = a * b2;
      const float* fr = &fowT[c1 * 48];
#pragma unroll
      for (int o4 = 0; o4 < 12; ++o4) {
        const float4 m = *(const float4*)&fr[o4 * 4];
        facc[o4 * 4 + 0] += m.x * gate; facc[o4 * 4 + 1] += m.y * gate;
        facc[o4 * 4 + 2] += m.z * gate; facc[o4 * 4 + 3] += m.w * gate;
      }
    }
  }
  float o0 = s0[0] + opb[0], o1 = s0[1] + opb[1], o2 = s0[2] + opb[2];
#pragma unroll
  for (int o = 0; o < 48; ++o) {
    o0 += opw[o] * facc[o]; o1 += opw[48 + o] * facc[o]; o2 += opw[96 + o] * facc[o];
  }
  out[((size_t)bb * 3 + 0) * NPIX + gn] = o0;
  out[((size_t)bb * 3 + 1) * NPIX + gn] = o1;
  out[((size_t)bb * 3 + 2) * NPIX + gn] = o2;
}

extern "C" void kernel_launch(void* const* d_in, const int* in_sizes, int n_in,
                              void* d_out, int out_size, void* d_ws, size_t ws_size,
                              hipStream_t stream) {
  const float* x    = (const float*)d_in[0];
  const float* ipw  = (const float*)d_in[1];
  const float* ipb  = (const float*)d_in[2];
  const float* ln1w = (const float*)d_in[3];
  const float* ln1b = (const float*)d_in[4];
  const float* qw   = (const float*)d_in[5];
  const float* qb   = (const float*)d_in[6];
  const float* qdww = (const float*)d_in[7];
  const float* qdwb = (const float*)d_in[8];
  const float* temp = (const float*)d_in[9];
  const float* aow  = (const float*)d_in[10];
  const float* aob  = (const float*)d_in[11];
  const float* ln2w = (const float*)d_in[12];
  const float* ln2b = (const float*)d_in[13];
  const float* fiw  = (const float*)d_in[14];
  const float* fib  = (const float*)d_in[15];
  const float* fdww = (const float*)d_in[16];
  const float* fdwb = (const float*)d_in[17];
  const float* fow  = (const float*)d_in[18];
  const float* fob  = (const float*)d_in[19];
  const float* opw  = (const float*)d_in[20];
  const float* opb  = (const float*)d_in[21];

  float* xp   = (float*)d_ws;                       // 25165824 floats
  float* vbuf = xp + (size_t)25165824;              // 25165824 floats
  float* red  = vbuf + (size_t)25165824;            // 5376 floats
  float* Mws  = red + 5376;                         // 18432 floats

  hipMemsetAsync(red, 0, 5376 * sizeof(float), stream);
  k1_inproj<<<2048, 256, 0, stream>>>(x, ipw, ipb, xp);
  k2_qkv<<<2048, 256, 0, stream>>>(xp, ln1w, ln1b, qw, qb, qdww, qdwb, vbuf, red);
  k3_attn<<<8, 256, 0, stream>>>(red, temp, aow, Mws);
  k4_attnout<<<2048, 256, 0, stream>>>(vbuf, Mws, aob, xp);
  k5_ffn<<<2048, 256, 0, stream>>>(xp, ln2w, ln2b, fiw, fib, fdww, fdwb,
                                   fow, fob, opw, opb, (float*)d_out);
}

// Round 3
// 1702.067 us; speedup vs baseline: 1.5780x; 1.5780x over previous
//
#include <hip/hip_runtime.h>

// CAPTNet block, fp32. B=8, CIN=3, H=W=256, DIM=48, HEADS=4 (ch=12), HID=96.
// High-occupancy split pipeline (round 3: fixes k2b reduction thread-count bug
// -- round 2 used `tid < 336` in a 256-thread block, so norm sums & part of
// the Gram matrix were never accumulated).
//  k2a: per pixel, regs only: in_proj(3->48) -> write xp; LN1; qkv conv 48->144
//       -> write qkv.                                   [planes 0..47 xp, 48..191 qkv]
//  k2b: per 16x16 tile: dw3x3 stencil on qkv (12-ch halo groups in LDS);
//       q,k -> Gram/norm partials (atomics to red); v -> vdw [planes 192..239]
//  k3 : finalize attn (l2norm, temp, softmax-12), fold attn_out_w -> M[48][48]/batch
//  k4a: per pixel: xp2 = xp + M@vdw + aob (regs); s0 = opw@xp2 -> planes 192..194;
//       LN2; ffn_in conv 48->192 -> y [planes 0..191, aliasing xp+qkv: per-thread
//       reads precede writes, same-pixel indexing -> safe; params non-restrict]
//  k5b: per 16x16 tile: dw3x3 on y (6-pair halo groups), SimpleGate, ffn_out
//       accumulate facc[48], out = s0 + opw@(facc+fob) + opb.
// region layout per batch: 240 planes of 65536 floats (61.4 MB). Chunked over
// batches if ws_size < 8 batches worth (adaptive, deterministic).

#define NPIX 65536
#define PB 240

__device__ __forceinline__ float dw9(const float* h, const float* w) {
  return w[0]*h[-19] + w[1]*h[-18] + w[2]*h[-17]
       + w[3]*h[-1]  + w[4]*h[0]   + w[5]*h[1]
       + w[6]*h[17]  + w[7]*h[18]  + w[8]*h[19];
}

// ---------------- k2a: in_proj + LN1 + qkv conv1x1 ----------------
__global__ __launch_bounds__(256) void k2a(
    const float* __restrict__ x, const float* __restrict__ ipw,
    const float* __restrict__ ipb, const float* __restrict__ lnw,
    const float* __restrict__ lnb, const float* __restrict__ qw,
    const float* __restrict__ qb, float* __restrict__ region) {
  __shared__ __align__(16) float wT[48 * 144];   // wT[c][o] = qw[o][c]
  __shared__ float s_ipw[144], s_ipb[48], s_lnw[48], s_lnb[48], s_qb[144];
  const int tid = threadIdx.x;
  for (int i = tid; i < 6912; i += 256) {
    const int c = i / 144, o = i - c * 144;
    wT[i] = qw[o * 48 + c];
  }
  if (tid < 144) { s_ipw[tid] = ipw[tid]; s_qb[tid] = qb[tid]; }
  if (tid < 48) { s_ipb[tid] = ipb[tid]; s_lnw[tid] = lnw[tid]; s_lnb[tid] = lnb[tid]; }
  __syncthreads();
  const int b = blockIdx.x >> 8;
  const int n = ((blockIdx.x & 255) << 8) + tid;
  const float x0 = x[((size_t)b * 3 + 0) * NPIX + n];
  const float x1 = x[((size_t)b * 3 + 1) * NPIX + n];
  const float x2 = x[((size_t)b * 3 + 2) * NPIX + n];
  float* rb = region + (size_t)b * PB * NPIX + n;
  float xn[48];
  float mu = 0.f;
#pragma unroll
  for (int c = 0; c < 48; ++c) {
    xn[c] = s_ipw[c * 3] * x0 + s_ipw[c * 3 + 1] * x1 + s_ipw[c * 3 + 2] * x2 + s_ipb[c];
    rb[(size_t)c * NPIX] = xn[c];
    mu += xn[c];
  }
  mu *= (1.f / 48.f);
  float var = 0.f;
#pragma unroll
  for (int c = 0; c < 48; ++c) { const float d = xn[c] - mu; var += d * d; }
  const float rs = rsqrtf(var * (1.f / 48.f) + 1e-6f);
#pragma unroll
  for (int c = 0; c < 48; ++c) xn[c] = (xn[c] - mu) * rs * s_lnw[c] + s_lnb[c];
#pragma unroll
  for (int ob = 0; ob < 9; ++ob) {
    const int o0 = ob * 16;
    float acc[16];
#pragma unroll
    for (int j = 0; j < 16; ++j) acc[j] = s_qb[o0 + j];
#pragma unroll 4
    for (int c = 0; c < 48; ++c) {
      const float xv = xn[c];
      const float4 w0 = *(const float4*)&wT[c * 144 + o0];
      const float4 w1 = *(const float4*)&wT[c * 144 + o0 + 4];
      const float4 w2 = *(const float4*)&wT[c * 144 + o0 + 8];
      const float4 w3 = *(const float4*)&wT[c * 144 + o0 + 12];
      acc[0] += w0.x * xv; acc[1] += w0.y * xv; acc[2] += w0.z * xv; acc[3] += w0.w * xv;
      acc[4] += w1.x * xv; acc[5] += w1.y * xv; acc[6] += w1.z * xv; acc[7] += w1.w * xv;
      acc[8] += w2.x * xv; acc[9] += w2.y * xv; acc[10] += w2.z * xv; acc[11] += w2.w * xv;
      acc[12] += w3.x * xv; acc[13] += w3.y * xv; acc[14] += w3.z * xv; acc[15] += w3.w * xv;
    }
#pragma unroll
    for (int j = 0; j < 16; ++j) rb[(size_t)(48 + o0 + j) * NPIX] = acc[j];
  }
}

// ---------------- k2b: dwconv stencil + Gram partials + vdw ----------------
__global__ __launch_bounds__(256) void k2b(
    float* region, const float* __restrict__ dww, const float* __restrict__ dwb,
    float* __restrict__ red) {
  __shared__ __align__(16) float halo[12 * 324];
  __shared__ __align__(16) float qs[12 * 260];
  __shared__ __align__(16) float ks[12 * 260];
  __shared__ float s_dww[144 * 9], s_dwb[144];
  const int tid = threadIdx.x;
  for (int i = tid; i < 1296; i += 256) s_dww[i] = dww[i];
  if (tid < 144) s_dwb[tid] = dwb[tid];
  const int b = blockIdx.x >> 8;
  const int tile = blockIdx.x & 255;
  const int ty0 = (tile >> 4) << 4, tx0 = (tile & 15) << 4;
  const int py = tid >> 4, px = tid & 15;
  const int hp = (py + 1) * 18 + (px + 1);
  const int gn = ((ty0 + py) << 8) + (tx0 + px);
  const float* qkvb = region + ((size_t)b * PB + 48) * NPIX;
  float* vdwb = region + ((size_t)b * PB + 192) * NPIX;

  auto stage = [&](int cbase) {
    for (int i = tid; i < 3888; i += 256) {
      const int c = i / 324, p = i - c * 324;
      const int hy = p / 18, hx = p - hy * 18;
      const int gy = ty0 + hy - 1, gx = tx0 + hx - 1;
      float v = 0.f;
      if (((unsigned)gy < 256u) && ((unsigned)gx < 256u))
        v = qkvb[(size_t)(cbase + c) * NPIX + (gy << 8) + gx];
      halo[i] = v;
    }
  };

  for (int h = 0; h < 4; ++h) {
    __syncthreads();
    stage(h * 12);
    __syncthreads();
#pragma unroll
    for (int j = 0; j < 12; ++j) {
      const int ch = h * 12 + j;
      qs[j * 260 + tid] = s_dwb[ch] + dw9(&halo[j * 324 + hp], &s_dww[ch * 9]);
    }
    __syncthreads();
    stage(48 + h * 12);
    __syncthreads();
#pragma unroll
    for (int j = 0; j < 12; ++j) {
      const int ch = 48 + h * 12 + j;
      ks[j * 260 + tid] = s_dwb[ch] + dw9(&halo[j * 324 + hp], &s_dww[ch * 9]);
    }
    __syncthreads();
    // 168 reduction entries per head: G[12][12] | sum q^2 [12] | sum k^2 [12]
    // (256-thread block: one thread per entry, 64 float4s = all 256 pixels)
    if (tid < 168) {
      const int e = tid;
      float s = 0.f;
      if (e < 144) {
        const int c = e / 12, d = e - c * 12;
        const float4* qa = (const float4*)&qs[c * 260];
        const float4* kb = (const float4*)&ks[d * 260];
        for (int p4 = 0; p4 < 64; ++p4) {
          const float4 a = qa[p4], bb = kb[p4];
          s += a.x * bb.x + a.y * bb.y + a.z * bb.z + a.w * bb.w;
        }
      } else if (e < 156) {
        const float4* qa = (const float4*)&qs[(e - 144) * 260];
        for (int p4 = 0; p4 < 64; ++p4) {
          const float4 a = qa[p4];
          s += a.x * a.x + a.y * a.y + a.z * a.z + a.w * a.w;
        }
      } else {
        const float4* kb = (const float4*)&ks[(e - 156) * 260];
        for (int p4 = 0; p4 < 64; ++p4) {
          const float4 a = kb[p4];
          s += a.x * a.x + a.y * a.y + a.z * a.z + a.w * a.w;
        }
      }
      atomicAdd(&red[b * 672 + h * 168 + e], s);
    }
  }
  for (int g = 0; g < 4; ++g) {
    __syncthreads();
    stage(96 + g * 12);
    __syncthreads();
#pragma unroll
    for (int j = 0; j < 12; ++j) {
      const int ch = 96 + g * 12 + j;
      vdwb[(size_t)(g * 12 + j) * NPIX + gn] =
          s_dwb[ch] + dw9(&halo[j * 324 + hp], &s_dww[ch * 9]);
    }
  }
}

// ---------------- k3: finalize attn, build fused M ----------------
__global__ __launch_bounds__(256) void k3_attn(const float* __restrict__ red,
                                               const float* __restrict__ temp,
                                               const float* __restrict__ aow,
                                               float* __restrict__ Mws) {
  __shared__ float attn[4 * 144];
  const int b = blockIdx.x, tid = threadIdx.x;
  const float* rb = red + b * 672;
  for (int e = tid; e < 576; e += 256) {
    const int h = e / 144, r = e - h * 144;
    const int c = r / 12, d = r - c * 12;
    const float g = rb[h * 168 + r];
    const float nq = fmaxf(sqrtf(rb[h * 168 + 144 + c]), 1e-12f);
    const float nk = fmaxf(sqrtf(rb[h * 168 + 156 + d]), 1e-12f);
    attn[e] = g / (nq * nk) * temp[h];
  }
  __syncthreads();
  if (tid < 48) {
    const int h = tid / 12, c = tid - h * 12;
    float* row = &attn[h * 144 + c * 12];
    float m = row[0];
    for (int d = 1; d < 12; ++d) m = fmaxf(m, row[d]);
    float s = 0.f;
    for (int d = 0; d < 12; ++d) { const float e2 = expf(row[d] - m); row[d] = e2; s += e2; }
    const float inv = 1.f / s;
    for (int d = 0; d < 12; ++d) row[d] *= inv;
  }
  __syncthreads();
  for (int e = tid; e < 2304; e += 256) {
    const int o = e / 48, j = e - o * 48;
    const int h = j / 12, d = j - h * 12;
    float s = 0.f;
    for (int c = 0; c < 12; ++c)
      s += aow[o * 48 + h * 12 + c] * attn[h * 144 + c * 12 + d];
    Mws[b * 2304 + e] = s;
  }
}

// ---------------- k4a: attn-out + residual + LN2 + ffn_in conv ----------------
__global__ __launch_bounds__(256) void k4a(
    float* region, const float* __restrict__ Mws, const float* __restrict__ aob,
    const float* __restrict__ lnw, const float* __restrict__ lnb,
    const float* __restrict__ fiw, const float* __restrict__ fib,
    const float* __restrict__ opw) {
  __shared__ __align__(16) float MT[48 * 48];     // MT[j][o]
  __shared__ __align__(16) float wT[48 * 192];    // wT[c][ch] = fiw[ch][c]
  __shared__ float s_aob[48], s_lnw[48], s_lnb[48], s_fib[192], s_opw[144];
  const int tid = threadIdx.x;
  const int b = blockIdx.x >> 8;
  const int n = ((blockIdx.x & 255) << 8) + tid;
  for (int i = tid; i < 2304; i += 256) {
    const int o = i / 48, j = i - o * 48;
    MT[j * 48 + o] = Mws[b * 2304 + i];
  }
  for (int i = tid; i < 9216; i += 256) {
    const int c = i / 192, ch = i - c * 192;
    wT[i] = fiw[ch * 48 + c];
  }
  if (tid < 192) s_fib[tid] = fib[tid];
  if (tid < 144) s_opw[tid] = opw[tid];
  if (tid < 48) { s_aob[tid] = aob[tid]; s_lnw[tid] = lnw[tid]; s_lnb[tid] = lnb[tid]; }
  __syncthreads();
  float y[48];
#pragma unroll
  for (int o = 0; o < 48; ++o) y[o] = s_aob[o];
  const float* vb = region + ((size_t)b * PB + 192) * NPIX + n;
#pragma unroll 4
  for (int j = 0; j < 48; ++j) {
    const float vj = vb[(size_t)j * NPIX];
    const float* mr = &MT[j * 48];
#pragma unroll
    for (int o4 = 0; o4 < 12; ++o4) {
      const float4 m = *(const float4*)&mr[o4 * 4];
      y[o4 * 4 + 0] += m.x * vj; y[o4 * 4 + 1] += m.y * vj;
      y[o4 * 4 + 2] += m.z * vj; y[o4 * 4 + 3] += m.w * vj;
    }
  }
  float* rb = region + (size_t)b * PB * NPIX + n;
  float mu = 0.f;
#pragma unroll
  for (int c = 0; c < 48; ++c) { y[c] += rb[(size_t)c * NPIX]; mu += y[c]; }
  float s0 = 0.f, s1 = 0.f, s2 = 0.f;
#pragma unroll
  for (int c = 0; c < 48; ++c) {
    s0 += s_opw[c] * y[c]; s1 += s_opw[48 + c] * y[c]; s2 += s_opw[96 + c] * y[c];
  }
  rb[(size_t)192 * NPIX] = s0;
  rb[(size_t)193 * NPIX] = s1;
  rb[(size_t)194 * NPIX] = s2;
  mu *= (1.f / 48.f);
  float var = 0.f;
#pragma unroll
  for (int c = 0; c < 48; ++c) { const float d = y[c] - mu; var += d * d; }
  const float rs2 = rsqrtf(var * (1.f / 48.f) + 1e-6f);
#pragma unroll
  for (int c = 0; c < 48; ++c) y[c] = (y[c] - mu) * rs2 * s_lnw[c] + s_lnb[c];
#pragma unroll
  for (int ob = 0; ob < 12; ++ob) {
    const int o0 = ob * 16;
    float acc[16];
#pragma unroll
    for (int j = 0; j < 16; ++j) acc[j] = s_fib[o0 + j];
#pragma unroll 4
    for (int c = 0; c < 48; ++c) {
      const float xv = y[c];
      const float4 w0 = *(const float4*)&wT[c * 192 + o0];
      const float4 w1 = *(const float4*)&wT[c * 192 + o0 + 4];
      const float4 w2 = *(const float4*)&wT[c * 192 + o0 + 8];
      const float4 w3 = *(const float4*)&wT[c * 192 + o0 + 12];
      acc[0] += w0.x * xv; acc[1] += w0.y * xv; acc[2] += w0.z * xv; acc[3] += w0.w * xv;
      acc[4] += w1.x * xv; acc[5] += w1.y * xv; acc[6] += w1.z * xv; acc[7] += w1.w * xv;
      acc[8] += w2.x * xv; acc[9] += w2.y * xv; acc[10] += w2.z * xv; acc[11] += w2.w * xv;
      acc[12] += w3.x * xv; acc[13] += w3.y * xv; acc[14] += w3.z * xv; acc[15] += w3.w * xv;
    }
#pragma unroll
    for (int j = 0; j < 16; ++j) rb[(size_t)(o0 + j) * NPIX] = acc[j];
  }
}

// ---------------- k5b: dw + SimpleGate + ffn_out + out_proj ----------------
__global__ __launch_bounds__(256) void k5b(
    const float* __restrict__ region, const float* __restrict__ fdww,
    const float* __restrict__ fdwb, const float* __restrict__ fow,
    const float* __restrict__ fob, const float* __restrict__ opw,
    const float* __restrict__ opb, float* __restrict__ out) {
  __shared__ __align__(16) float halo[12 * 324];
  __shared__ __align__(16) float fowT[96 * 48];   // fowT[c1][o] = fow[o][c1]
  __shared__ float s_dww[192 * 9], s_dwb[192], s_opw[144], s_fob[48];
  const int tid = threadIdx.x;
  for (int i = tid; i < 4608; i += 256) {
    const int c = i / 48, o = i - c * 48;
    fowT[i] = fow[o * 96 + c];
  }
  for (int i = tid; i < 1728; i += 256) s_dww[i] = fdww[i];
  if (tid < 192) s_dwb[tid] = fdwb[tid];
  if (tid < 144) s_opw[tid] = opw[tid];
  if (tid < 48) s_fob[tid] = fob[tid];
  const int b = blockIdx.x >> 8;
  const int tile = blockIdx.x & 255;
  const int ty0 = (tile >> 4) << 4, tx0 = (tile & 15) << 4;
  const int py = tid >> 4, px = tid & 15;
  const int hp = (py + 1) * 18 + (px + 1);
  const int gn = ((ty0 + py) << 8) + (tx0 + px);
  const float* yb = region + (size_t)b * PB * NPIX;
  float facc[48];
#pragma unroll
  for (int o = 0; o < 48; ++o) facc[o] = 0.f;
  for (int g = 0; g < 16; ++g) {
    __syncthreads();
    for (int i = tid; i < 3888; i += 256) {
      const int c = i / 324, p = i - c * 324;
      const int ch = (c < 6) ? (g * 6 + c) : (96 + g * 6 + (c - 6));
      const int hy = p / 18, hx = p - hy * 18;
      const int gy = ty0 + hy - 1, gx = tx0 + hx - 1;
      float v = 0.f;
      if (((unsigned)gy < 256u) && ((unsigned)gx < 256u))
        v = yb[(size_t)ch * NPIX + (gy << 8) + gx];
      halo[i] = v;
    }
    __syncthreads();
#pragma unroll
    for (int j = 0; j < 6; ++j) {
      const int c1 = g * 6 + j;
      const float a  = s_dwb[c1]      + dw9(&halo[j * 324 + hp], &s_dww[c1 * 9]);
      const float b2 = s_dwb[96 + c1] + dw9(&halo[(6 + j) * 324 + hp], &s_dww[(96 + c1) * 9]);
      const float gate = a * b2;
      const float* fr = &fowT[c1 * 48];
#pragma unroll
      for (int o4 = 0; o4 < 12; ++o4) {
        const float4 m = *(const float4*)&fr[o4 * 4];
        facc[o4 * 4 + 0] += m.x * gate; facc[o4 * 4 + 1] += m.y * gate;
        facc[o4 * 4 + 2] += m.z * gate; facc[o4 * 4 + 3] += m.w * gate;
      }
    }
  }
  float r0 = region[((size_t)b * PB + 192) * NPIX + gn] + opb[0];
  float r1 = region[((size_t)b * PB + 193) * NPIX + gn] + opb[1];
  float r2 = region[((size_t)b * PB + 194) * NPIX + gn] + opb[2];
#pragma unroll
  for (int o = 0; o < 48; ++o) {
    const float f = facc[o] + s_fob[o];
    r0 += s_opw[o] * f; r1 += s_opw[48 + o] * f; r2 += s_opw[96 + o] * f;
  }
  out[((size_t)b * 3 + 0) * NPIX + gn] = r0;
  out[((size_t)b * 3 + 1) * NPIX + gn] = r1;
  out[((size_t)b * 3 + 2) * NPIX + gn] = r2;
}

extern "C" void kernel_launch(void* const* d_in, const int* in_sizes, int n_in,
                              void* d_out, int out_size, void* d_ws, size_t ws_size,
                              hipStream_t stream) {
  const float* x    = (const float*)d_in[0];
  const float* ipw  = (const float*)d_in[1];
  const float* ipb  = (const float*)d_in[2];
  const float* ln1w = (const float*)d_in[3];
  const float* ln1b = (const float*)d_in[4];
  const float* qw   = (const float*)d_in[5];
  const float* qb   = (const float*)d_in[6];
  const float* qdww = (const float*)d_in[7];
  const float* qdwb = (const float*)d_in[8];
  const float* temp = (const float*)d_in[9];
  const float* aow  = (const float*)d_in[10];
  const float* aob  = (const float*)d_in[11];
  const float* ln2w = (const float*)d_in[12];
  const float* ln2b = (const float*)d_in[13];
  const float* fiw  = (const float*)d_in[14];
  const float* fib  = (const float*)d_in[15];
  const float* fdww = (const float*)d_in[16];
  const float* fdwb = (const float*)d_in[17];
  const float* fow  = (const float*)d_in[18];
  const float* fob  = (const float*)d_in[19];
  const float* opw  = (const float*)d_in[20];
  const float* opb  = (const float*)d_in[21];

  const size_t perb = (size_t)PB * NPIX;   // floats per batch in region
  int bc = 8;
  while (bc > 1 && ((size_t)bc * perb + 5376 + 18432) * sizeof(float) > ws_size)
    bc >>= 1;
  float* region = (float*)d_ws;
  float* red = region + (size_t)bc * perb;
  float* Mws = red + 5376;
  hipMemsetAsync(red, 0, 5376 * sizeof(float), stream);
  for (int b0 = 0; b0 < 8; b0 += bc) {
    k2a<<<bc * 256, 256, 0, stream>>>(x + (size_t)b0 * 3 * NPIX, ipw, ipb,
                                      ln1w, ln1b, qw, qb, region);
    k2b<<<bc * 256, 256, 0, stream>>>(region, qdww, qdwb, red + b0 * 672);
    k3_attn<<<bc, 256, 0, stream>>>(red + b0 * 672, temp, aow,
                                    Mws + (size_t)b0 * 2304);
    k4a<<<bc * 256, 256, 0, stream>>>(region, Mws + (size_t)b0 * 2304, aob,
                                      ln2w, ln2b, fiw, fib, opw);
    k5b<<<bc * 256, 256, 0, stream>>>(region, fdww, fdwb, fow, fob, opw, opb,
                                      (float*)d_out + (size_t)b0 * 3 * NPIX);
  }
}

// Round 4
// 1488.422 us; speedup vs baseline: 1.8045x; 1.1435x over previous
//
#include <hip/hip_runtime.h>

// CAPTNet block, fp32. B=8, CIN=3, H=W=256, DIM=48, HEADS=4 (ch=12), HID=96.
// Round 4: pixel-major layout region[b][n][240] + float4 everywhere + async
// prefetch (global->regs early, regs->LDS after barrier) in stencil kernels.
// Per-pixel slab (240 floats = 960 B, 15 aligned 64B lines):
//   [0..47]   xp (k2a)         -> overwritten by y (k4a, pair-interleaved)
//   [48..95]  q conv out       -> y
//   [96..143] k conv out       -> y
//   [144..191] v conv out      -> y
//   [192..239] vdw (k2b)       -> [192..194] s0 (k4a)
// y interleave: pos 2j = ffn ch j, pos 2j+1 = ffn ch 96+j  (j in 0..95)
// Pipeline: k2a (pixel: in_proj+LN1+qkv conv) -> k2b (tile: dwconv q,k,v +
// Gram/norm atomics + vdw) -> k3 (attn finalize, fold attn_out_w -> M) ->
// k4a (pixel: xp+=M@vdw, s0=opw@xp2, LN2, ffn_in conv -> y) -> k5b (tile:
// dwconv pairs + SimpleGate + ffn_out + out_proj).

#define NPIX 65536
#define PB 240
#define HST 328   // halo LDS channel stride (324 pixels padded)

__device__ __forceinline__ float dw9(const float* h, const float* w) {
  return w[0]*h[-19] + w[1]*h[-18] + w[2]*h[-17]
       + w[3]*h[-1]  + w[4]*h[0]   + w[5]*h[1]
       + w[6]*h[17]  + w[7]*h[18]  + w[8]*h[19];
}

// ---------------- k2a: in_proj + LN1 + qkv conv1x1 ----------------
__global__ __launch_bounds__(256) void k2a(
    const float* __restrict__ x, const float* __restrict__ ipw,
    const float* __restrict__ ipb, const float* __restrict__ lnw,
    const float* __restrict__ lnb, const float* __restrict__ qw,
    const float* __restrict__ qb, float* __restrict__ region) {
  __shared__ __align__(16) float wT[48 * 144];   // wT[c][o] = qw[o][c]
  __shared__ float s_ipw[144], s_ipb[48], s_lnw[48], s_lnb[48], s_qb[144];
  const int tid = threadIdx.x;
  for (int i = tid; i < 6912; i += 256) {
    const int c = i / 144, o = i - c * 144;
    wT[i] = qw[o * 48 + c];
  }
  if (tid < 144) { s_ipw[tid] = ipw[tid]; s_qb[tid] = qb[tid]; }
  if (tid < 48) { s_ipb[tid] = ipb[tid]; s_lnw[tid] = lnw[tid]; s_lnb[tid] = lnb[tid]; }
  __syncthreads();
  const int b = blockIdx.x >> 8;
  const int n = ((blockIdx.x & 255) << 8) + tid;
  const float x0 = x[((size_t)b * 3 + 0) * NPIX + n];
  const float x1 = x[((size_t)b * 3 + 1) * NPIX + n];
  const float x2 = x[((size_t)b * 3 + 2) * NPIX + n];
  float4* rp4 = (float4*)(region + ((size_t)b * NPIX + n) * PB);
  float xn[48];
  float mu = 0.f;
#pragma unroll
  for (int c = 0; c < 48; ++c) {
    xn[c] = s_ipw[c * 3] * x0 + s_ipw[c * 3 + 1] * x1 + s_ipw[c * 3 + 2] * x2 + s_ipb[c];
    mu += xn[c];
  }
#pragma unroll
  for (int c4 = 0; c4 < 12; ++c4) {
    float4 v; v.x = xn[4*c4]; v.y = xn[4*c4+1]; v.z = xn[4*c4+2]; v.w = xn[4*c4+3];
    rp4[c4] = v;
  }
  mu *= (1.f / 48.f);
  float var = 0.f;
#pragma unroll
  for (int c = 0; c < 48; ++c) { const float d = xn[c] - mu; var += d * d; }
  const float rs = rsqrtf(var * (1.f / 48.f) + 1e-6f);
#pragma unroll
  for (int c = 0; c < 48; ++c) xn[c] = (xn[c] - mu) * rs * s_lnw[c] + s_lnb[c];
#pragma unroll
  for (int ob = 0; ob < 9; ++ob) {
    const int o0 = ob * 16;
    float acc[16];
#pragma unroll
    for (int j = 0; j < 16; ++j) acc[j] = s_qb[o0 + j];
#pragma unroll 4
    for (int c = 0; c < 48; ++c) {
      const float xv = xn[c];
      const float4 w0 = *(const float4*)&wT[c * 144 + o0];
      const float4 w1 = *(const float4*)&wT[c * 144 + o0 + 4];
      const float4 w2 = *(const float4*)&wT[c * 144 + o0 + 8];
      const float4 w3 = *(const float4*)&wT[c * 144 + o0 + 12];
      acc[0] += w0.x * xv; acc[1] += w0.y * xv; acc[2] += w0.z * xv; acc[3] += w0.w * xv;
      acc[4] += w1.x * xv; acc[5] += w1.y * xv; acc[6] += w1.z * xv; acc[7] += w1.w * xv;
      acc[8] += w2.x * xv; acc[9] += w2.y * xv; acc[10] += w2.z * xv; acc[11] += w2.w * xv;
      acc[12] += w3.x * xv; acc[13] += w3.y * xv; acc[14] += w3.z * xv; acc[15] += w3.w * xv;
    }
#pragma unroll
    for (int q = 0; q < 4; ++q) {
      float4 v; v.x = acc[4*q]; v.y = acc[4*q+1]; v.z = acc[4*q+2]; v.w = acc[4*q+3];
      rp4[12 + ob * 4 + q] = v;
    }
  }
}

// ---------------- k2b: dwconv stencil + Gram partials + vdw ----------------
__global__ __launch_bounds__(256) void k2b(
    float* region, const float* __restrict__ dww, const float* __restrict__ dwb,
    float* __restrict__ red) {
  __shared__ __align__(16) float halo[12 * HST];
  __shared__ __align__(16) float qs[12 * 260];
  __shared__ __align__(16) float ks[12 * 260];
  __shared__ float s_dww[144 * 9], s_dwb[144];
  const int tid = threadIdx.x;
  for (int i = tid; i < 1296; i += 256) s_dww[i] = dww[i];
  if (tid < 144) s_dwb[tid] = dwb[tid];
  const int b = blockIdx.x >> 8;
  const int tile = blockIdx.x & 255;
  const int ty0 = (tile >> 4) << 4, tx0 = (tile & 15) << 4;
  const int py = tid >> 4, px = tid & 15;
  const int hp = (py + 1) * 18 + (px + 1);
  const int gn = ((ty0 + py) << 8) + (tx0 + px);

  float4 pf[2][3];
  auto prefetch = [&](int cb) {
#pragma unroll
    for (int r = 0; r < 2; ++r) {
      const int p = tid + r * 256;
      float4 z; z.x = z.y = z.z = z.w = 0.f;
      pf[r][0] = z; pf[r][1] = z; pf[r][2] = z;
      if (p < 324) {
        const int hy = p / 18, hx = p - hy * 18;
        const int gy = ty0 + hy - 1, gx = tx0 + hx - 1;
        if (((unsigned)gy < 256u) && ((unsigned)gx < 256u)) {
          const float4* s4 = (const float4*)(region +
              ((size_t)b * NPIX + (gy << 8) + gx) * PB + cb);
          pf[r][0] = s4[0]; pf[r][1] = s4[1]; pf[r][2] = s4[2];
        }
      }
    }
  };
  auto commit = [&]() {
#pragma unroll
    for (int r = 0; r < 2; ++r) {
      const int p = tid + r * 256;
      if (p < 324) {
#pragma unroll
        for (int j = 0; j < 3; ++j) {
          halo[(j * 4 + 0) * HST + p] = pf[r][j].x;
          halo[(j * 4 + 1) * HST + p] = pf[r][j].y;
          halo[(j * 4 + 2) * HST + p] = pf[r][j].z;
          halo[(j * 4 + 3) * HST + p] = pf[r][j].w;
        }
      }
    }
  };

  prefetch(48);                       // q head 0
  for (int h = 0; h < 4; ++h) {
    __syncthreads();                  // prior halo consumers done
    commit();
    __syncthreads();                  // q halo ready
    prefetch(96 + 12 * h);            // k_h
#pragma unroll
    for (int j = 0; j < 12; ++j) {
      const int ch = 12 * h + j;
      qs[j * 260 + tid] = s_dwb[ch] + dw9(&halo[j * HST + hp], &s_dww[ch * 9]);
    }
    __syncthreads();                  // q compute done, halo free
    commit();
    __syncthreads();                  // k halo ready
    prefetch(h < 3 ? 48 + 12 * (h + 1) : 144);   // next q or v0
#pragma unroll
    for (int j = 0; j < 12; ++j) {
      const int ch = 48 + 12 * h + j;
      ks[j * 260 + tid] = s_dwb[ch] + dw9(&halo[j * HST + hp], &s_dww[ch * 9]);
    }
    __syncthreads();                  // qs,ks visible; halo free
    if (tid < 168) {
      const int e = tid;
      float s = 0.f;
      if (e < 144) {
        const int c = e / 12, d = e - c * 12;
        const float4* qa = (const float4*)&qs[c * 260];
        const float4* kb = (const float4*)&ks[d * 260];
        for (int p4 = 0; p4 < 64; ++p4) {
          const float4 a = qa[p4], bb = kb[p4];
          s += a.x * bb.x + a.y * bb.y + a.z * bb.z + a.w * bb.w;
        }
      } else if (e < 156) {
        const float4* qa = (const float4*)&qs[(e - 144) * 260];
        for (int p4 = 0; p4 < 64; ++p4) {
          const float4 a = qa[p4];
          s += a.x * a.x + a.y * a.y + a.z * a.z + a.w * a.w;
        }
      } else {
        const float4* kb = (const float4*)&ks[(e - 156) * 260];
        for (int p4 = 0; p4 < 64; ++p4) {
          const float4 a = kb[p4];
          s += a.x * a.x + a.y * a.y + a.z * a.z + a.w * a.w;
        }
      }
      atomicAdd(&red[b * 672 + h * 168 + e], s);
    }
  }
  for (int g = 0; g < 4; ++g) {
    __syncthreads();
    commit();
    __syncthreads();
    if (g < 3) prefetch(144 + 12 * (g + 1));
    float vr[12];
#pragma unroll
    for (int j = 0; j < 12; ++j) {
      const int ch = 96 + 12 * g + j;
      vr[j] = s_dwb[ch] + dw9(&halo[j * HST + hp], &s_dww[ch * 9]);
    }
    float* wp = region + ((size_t)b * NPIX + gn) * PB + 192 + 12 * g;
#pragma unroll
    for (int q = 0; q < 3; ++q) {
      float4 v; v.x = vr[4*q]; v.y = vr[4*q+1]; v.z = vr[4*q+2]; v.w = vr[4*q+3];
      ((float4*)wp)[q] = v;
    }
  }
}

// ---------------- k3: finalize attn, build fused M ----------------
__global__ __launch_bounds__(256) void k3_attn(const float* __restrict__ red,
                                               const float* __restrict__ temp,
                                               const float* __restrict__ aow,
                                               float* __restrict__ Mws) {
  __shared__ float attn[4 * 144];
  const int b = blockIdx.x, tid = threadIdx.x;
  const float* rb = red + b * 672;
  for (int e = tid; e < 576; e += 256) {
    const int h = e / 144, r = e - h * 144;
    const int c = r / 12, d = r - c * 12;
    const float g = rb[h * 168 + r];
    const float nq = fmaxf(sqrtf(rb[h * 168 + 144 + c]), 1e-12f);
    const float nk = fmaxf(sqrtf(rb[h * 168 + 156 + d]), 1e-12f);
    attn[e] = g / (nq * nk) * temp[h];
  }
  __syncthreads();
  if (tid < 48) {
    const int h = tid / 12, c = tid - h * 12;
    float* row = &attn[h * 144 + c * 12];
    float m = row[0];
    for (int d = 1; d < 12; ++d) m = fmaxf(m, row[d]);
    float s = 0.f;
    for (int d = 0; d < 12; ++d) { const float e2 = expf(row[d] - m); row[d] = e2; s += e2; }
    const float inv = 1.f / s;
    for (int d = 0; d < 12; ++d) row[d] *= inv;
  }
  __syncthreads();
  for (int e = tid; e < 2304; e += 256) {
    const int o = e / 48, j = e - o * 48;
    const int h = j / 12, d = j - h * 12;
    float s = 0.f;
    for (int c = 0; c < 12; ++c)
      s += aow[o * 48 + h * 12 + c] * attn[h * 144 + c * 12 + d];
    Mws[b * 2304 + e] = s;
  }
}

// ---------------- k4a: attn-out + residual + LN2 + ffn_in conv ----------------
__global__ __launch_bounds__(256) void k4a(
    float* region, const float* __restrict__ Mws, const float* __restrict__ aob,
    const float* __restrict__ lnw, const float* __restrict__ lnb,
    const float* __restrict__ fiw, const float* __restrict__ fib,
    const float* __restrict__ opw) {
  __shared__ __align__(16) float MT[48 * 48];     // MT[j][o]
  __shared__ __align__(16) float wT2[48 * 192];   // wT2[c][pos], pos interleaved
  __shared__ float s_aob[48], s_lnw[48], s_lnb[48], s_fib2[192], s_opw[144];
  const int tid = threadIdx.x;
  const int b = blockIdx.x >> 8;
  const int n = ((blockIdx.x & 255) << 8) + tid;
  for (int i = tid; i < 2304; i += 256) {
    const int o = i / 48, j = i - o * 48;
    MT[j * 48 + o] = Mws[b * 2304 + i];
  }
  for (int i = tid; i < 9216; i += 256) {
    const int c = i / 192, pos = i - c * 192;
    const int ch = (pos & 1) ? 96 + (pos >> 1) : (pos >> 1);
    wT2[i] = fiw[ch * 48 + c];
  }
  if (tid < 192) {
    const int ch = (tid & 1) ? 96 + (tid >> 1) : (tid >> 1);
    s_fib2[tid] = fib[ch];
  }
  if (tid < 144) s_opw[tid] = opw[tid];
  if (tid < 48) { s_aob[tid] = aob[tid]; s_lnw[tid] = lnw[tid]; s_lnb[tid] = lnb[tid]; }
  __syncthreads();
  float* rp = region + ((size_t)b * NPIX + n) * PB;
  float4* rp4 = (float4*)rp;
  float vv[48];
#pragma unroll
  for (int j4 = 0; j4 < 12; ++j4) {
    const float4 t4 = ((const float4*)rp)[48 + j4];
    vv[4*j4] = t4.x; vv[4*j4+1] = t4.y; vv[4*j4+2] = t4.z; vv[4*j4+3] = t4.w;
  }
  float y[48];
#pragma unroll
  for (int o = 0; o < 48; ++o) y[o] = s_aob[o];
#pragma unroll 4
  for (int j = 0; j < 48; ++j) {
    const float vj = vv[j];
    const float* mr = &MT[j * 48];
#pragma unroll
    for (int o4 = 0; o4 < 12; ++o4) {
      const float4 m = *(const float4*)&mr[o4 * 4];
      y[o4 * 4 + 0] += m.x * vj; y[o4 * 4 + 1] += m.y * vj;
      y[o4 * 4 + 2] += m.z * vj; y[o4 * 4 + 3] += m.w * vj;
    }
  }
  float mu = 0.f;
#pragma unroll
  for (int j4 = 0; j4 < 12; ++j4) {
    const float4 t4 = ((const float4*)rp)[j4];
    y[4*j4] += t4.x; y[4*j4+1] += t4.y; y[4*j4+2] += t4.z; y[4*j4+3] += t4.w;
    mu += y[4*j4] + y[4*j4+1] + y[4*j4+2] + y[4*j4+3];
  }
  float s0 = 0.f, s1 = 0.f, s2 = 0.f;
#pragma unroll
  for (int c = 0; c < 48; ++c) {
    s0 += s_opw[c] * y[c]; s1 += s_opw[48 + c] * y[c]; s2 += s_opw[96 + c] * y[c];
  }
  rp[192] = s0; rp[193] = s1; rp[194] = s2;
  mu *= (1.f / 48.f);
  float var = 0.f;
#pragma unroll
  for (int c = 0; c < 48; ++c) { const float d = y[c] - mu; var += d * d; }
  const float rs2 = rsqrtf(var * (1.f / 48.f) + 1e-6f);
#pragma unroll
  for (int c = 0; c < 48; ++c) y[c] = (y[c] - mu) * rs2 * s_lnw[c] + s_lnb[c];
#pragma unroll
  for (int ob = 0; ob < 12; ++ob) {
    const int o0 = ob * 16;
    float acc[16];
#pragma unroll
    for (int j = 0; j < 16; ++j) acc[j] = s_fib2[o0 + j];
#pragma unroll 4
    for (int c = 0; c < 48; ++c) {
      const float xv = y[c];
      const float4 w0 = *(const float4*)&wT2[c * 192 + o0];
      const float4 w1 = *(const float4*)&wT2[c * 192 + o0 + 4];
      const float4 w2 = *(const float4*)&wT2[c * 192 + o0 + 8];
      const float4 w3 = *(const float4*)&wT2[c * 192 + o0 + 12];
      acc[0] += w0.x * xv; acc[1] += w0.y * xv; acc[2] += w0.z * xv; acc[3] += w0.w * xv;
      acc[4] += w1.x * xv; acc[5] += w1.y * xv; acc[6] += w1.z * xv; acc[7] += w1.w * xv;
      acc[8] += w2.x * xv; acc[9] += w2.y * xv; acc[10] += w2.z * xv; acc[11] += w2.w * xv;
      acc[12] += w3.x * xv; acc[13] += w3.y * xv; acc[14] += w3.z * xv; acc[15] += w3.w * xv;
    }
#pragma unroll
    for (int q = 0; q < 4; ++q) {
      float4 v; v.x = acc[4*q]; v.y = acc[4*q+1]; v.z = acc[4*q+2]; v.w = acc[4*q+3];
      rp4[ob * 4 + q] = v;
    }
  }
}

// ---------------- k5b: dw + SimpleGate + ffn_out + out_proj ----------------
__global__ __launch_bounds__(256) void k5b(
    const float* __restrict__ region, const float* __restrict__ fdww,
    const float* __restrict__ fdwb, const float* __restrict__ fow,
    const float* __restrict__ fob, const float* __restrict__ opw,
    const float* __restrict__ opb, float* __restrict__ out) {
  __shared__ __align__(16) float halo[12 * HST];
  __shared__ __align__(16) float fowT[96 * 48];   // fowT[c1][o] = fow[o][c1]
  __shared__ float s_dww2[192 * 9], s_dwb2[192], s_opw[144], s_fob[48];
  const int tid = threadIdx.x;
  for (int i = tid; i < 4608; i += 256) {
    const int c = i / 48, o = i - c * 48;
    fowT[i] = fow[o * 96 + c];
  }
  for (int i = tid; i < 1728; i += 256) {
    const int P = i / 9, t = i - P * 9;
    const int ch = (P & 1) ? 96 + (P >> 1) : (P >> 1);
    s_dww2[i] = fdww[ch * 9 + t];
  }
  if (tid < 192) {
    const int ch = (tid & 1) ? 96 + (tid >> 1) : (tid >> 1);
    s_dwb2[tid] = fdwb[ch];
  }
  if (tid < 144) s_opw[tid] = opw[tid];
  if (tid < 48) s_fob[tid] = fob[tid];
  const int b = blockIdx.x >> 8;
  const int tile = blockIdx.x & 255;
  const int ty0 = (tile >> 4) << 4, tx0 = (tile & 15) << 4;
  const int py = tid >> 4, px = tid & 15;
  const int hp = (py + 1) * 18 + (px + 1);
  const int gn = ((ty0 + py) << 8) + (tx0 + px);

  float4 pf[2][3];
  auto prefetch = [&](int cb) {
#pragma unroll
    for (int r = 0; r < 2; ++r) {
      const int p = tid + r * 256;
      float4 z; z.x = z.y = z.z = z.w = 0.f;
      pf[r][0] = z; pf[r][1] = z; pf[r][2] = z;
      if (p < 324) {
        const int hy = p / 18, hx = p - hy * 18;
        const int gy = ty0 + hy - 1, gx = tx0 + hx - 1;
        if (((unsigned)gy < 256u) && ((unsigned)gx < 256u)) {
          const float4* s4 = (const float4*)(region +
              ((size_t)b * NPIX + (gy << 8) + gx) * PB + cb);
          pf[r][0] = s4[0]; pf[r][1] = s4[1]; pf[r][2] = s4[2];
        }
      }
    }
  };
  auto commit = [&]() {
#pragma unroll
    for (int r = 0; r < 2; ++r) {
      const int p = tid + r * 256;
      if (p < 324) {
#pragma unroll
        for (int j = 0; j < 3; ++j) {
          halo[(j * 4 + 0) * HST + p] = pf[r][j].x;
          halo[(j * 4 + 1) * HST + p] = pf[r][j].y;
          halo[(j * 4 + 2) * HST + p] = pf[r][j].z;
          halo[(j * 4 + 3) * HST + p] = pf[r][j].w;
        }
      }
    }
  };

  float facc[48];
#pragma unroll
  for (int o = 0; o < 48; ++o) facc[o] = 0.f;
  prefetch(0);
  for (int g = 0; g < 16; ++g) {
    __syncthreads();
    commit();
    __syncthreads();
    if (g < 15) prefetch(12 * (g + 1));
#pragma unroll
    for (int j = 0; j < 6; ++j) {
      const int PA = g * 12 + 2 * j, PBo = PA + 1;
      const float a  = s_dwb2[PA]  + dw9(&halo[(2*j) * HST + hp], &s_dww2[PA * 9]);
      const float b2 = s_dwb2[PBo] + dw9(&halo[(2*j+1) * HST + hp], &s_dww2[PBo * 9]);
      const float gate = a * b2;
      const float* fr = &fowT[(g * 6 + j) * 48];
#pragma unroll
      for (int o4 = 0; o4 < 12; ++o4) {
        const float4 m = *(const float4*)&fr[o4 * 4];
        facc[o4 * 4 + 0] += m.x * gate; facc[o4 * 4 + 1] += m.y * gate;
        facc[o4 * 4 + 2] += m.z * gate; facc[o4 * 4 + 3] += m.w * gate;
      }
    }
  }
  const float* rp = region + ((size_t)b * NPIX + gn) * PB;
  float r0 = rp[192] + opb[0];
  float r1 = rp[193] + opb[1];
  float r2 = rp[194] + opb[2];
#pragma unroll
  for (int o = 0; o < 48; ++o) {
    const float f = facc[o] + s_fob[o];
    r0 += s_opw[o] * f; r1 += s_opw[48 + o] * f; r2 += s_opw[96 + o] * f;
  }
  out[((size_t)b * 3 + 0) * NPIX + gn] = r0;
  out[((size_t)b * 3 + 1) * NPIX + gn] = r1;
  out[((size_t)b * 3 + 2) * NPIX + gn] = r2;
}

extern "C" void kernel_launch(void* const* d_in, const int* in_sizes, int n_in,
                              void* d_out, int out_size, void* d_ws, size_t ws_size,
                              hipStream_t stream) {
  const float* x    = (const float*)d_in[0];
  const float* ipw  = (const float*)d_in[1];
  const float* ipb  = (const float*)d_in[2];
  const float* ln1w = (const float*)d_in[3];
  const float* ln1b = (const float*)d_in[4];
  const float* qw   = (const float*)d_in[5];
  const float* qb   = (const float*)d_in[6];
  const float* qdww = (const float*)d_in[7];
  const float* qdwb = (const float*)d_in[8];
  const float* temp = (const float*)d_in[9];
  const float* aow  = (const float*)d_in[10];
  const float* aob  = (const float*)d_in[11];
  const float* ln2w = (const float*)d_in[12];
  const float* ln2b = (const float*)d_in[13];
  const float* fiw  = (const float*)d_in[14];
  const float* fib  = (const float*)d_in[15];
  const float* fdww = (const float*)d_in[16];
  const float* fdwb = (const float*)d_in[17];
  const float* fow  = (const float*)d_in[18];
  const float* fob  = (const float*)d_in[19];
  const float* opw  = (const float*)d_in[20];
  const float* opb  = (const float*)d_in[21];

  const size_t perb = (size_t)PB * NPIX;   // floats per batch in region
  int bc = 8;
  while (bc > 1 && ((size_t)bc * perb + 5376 + 18432) * sizeof(float) > ws_size)
    bc >>= 1;
  float* region = (float*)d_ws;
  float* red = region + (size_t)bc * perb;
  float* Mws = red + 5376;
  hipMemsetAsync(red, 0, 5376 * sizeof(float), stream);
  for (int b0 = 0; b0 < 8; b0 += bc) {
    k2a<<<bc * 256, 256, 0, stream>>>(x + (size_t)b0 * 3 * NPIX, ipw, ipb,
                                      ln1w, ln1b, qw, qb, region);
    k2b<<<bc * 256, 256, 0, stream>>>(region, qdww, qdwb, red + b0 * 672);
    k3_attn<<<bc, 256, 0, stream>>>(red + b0 * 672, temp, aow,
                                    Mws + (size_t)b0 * 2304);
    k4a<<<bc * 256, 256, 0, stream>>>(region, Mws + (size_t)b0 * 2304, aob,
                                      ln2w, ln2b, fiw, fib, opw);
    k5b<<<bc * 256, 256, 0, stream>>>(region, fdww, fdwb, fow, fob, opw, opb,
                                      (float*)d_out + (size_t)b0 * 3 * NPIX);
  }
}

// Round 5
// 1416.885 us; speedup vs baseline: 1.8956x; 1.0505x over previous
//
#include <hip/hip_runtime.h>
#include <hip/hip_fp16.h>

// CAPTNet block. B=8, CIN=3, H=W=256, DIM=48, HEADS=4 (ch=12), HID=96.
// Round 5: fp16 intermediate storage (fp32 compute). Pixel-major slab,
// 592 B/pixel (148 floats), 16B-aligned:
//   bytes [0,192)   : xp, 48 x fp32            (k2a -> k4a residual)
//   bytes [192,480) : qkv, 144 x fp16          (k2a -> k2b)  }  overwritten by
//   bytes [480,576) : vdw, 48 x fp16           (k2b -> k4a)  }  y 192 x fp16
//   bytes [576,588) : s0, 3 x fp32             (k4a -> k5b)     (k4a -> k5b)
// y interleave: pos 2j = ffn ch j, pos 2j+1 = ffn ch 96+j  (j in 0..95)
// Pipeline: k2a (pixel: in_proj+LN1+qkv conv) -> k2b (tile: dwconv q,k,v +
// Gram/norm atomics + vdw) -> k3 (attn finalize, fold attn_out_w -> M) ->
// k4a (pixel: xp+=M@vdw, s0=opw@xp2, LN2, ffn_in conv -> y fp16) -> k5b
// (tile: dwconv pairs + SimpleGate + ffn_out + out_proj).

#define NPIX 65536
#define SLABF 148          // floats per pixel slab (592 B)
#define SLABB 592
#define HST 328            // halo LDS channel stride (324 pixels padded)

union H8  { float2 f2; __half2 h2[2]; };
union H16 { float4 f4; __half2 h2[4]; };

__device__ __forceinline__ __half2 pack2(float a, float b) {
  return __halves2half2(__float2half_rn(a), __float2half_rn(b));
}

__device__ __forceinline__ float dw9(const float* h, const float* w) {
  return w[0]*h[-19] + w[1]*h[-18] + w[2]*h[-17]
       + w[3]*h[-1]  + w[4]*h[0]   + w[5]*h[1]
       + w[6]*h[17]  + w[7]*h[18]  + w[8]*h[19];
}

// ---------------- k2a: in_proj + LN1 + qkv conv1x1 ----------------
__global__ __launch_bounds__(256, 4) void k2a(
    const float* __restrict__ x, const float* __restrict__ ipw,
    const float* __restrict__ ipb, const float* __restrict__ lnw,
    const float* __restrict__ lnb, const float* __restrict__ qw,
    const float* __restrict__ qb, float* __restrict__ region) {
  __shared__ __align__(16) float wT[48 * 144];   // wT[c][o] = qw[o][c]
  __shared__ float s_ipw[144], s_ipb[48], s_lnw[48], s_lnb[48], s_qb[144];
  const int tid = threadIdx.x;
  for (int i = tid; i < 6912; i += 256) {
    const int c = i / 144, o = i - c * 144;
    wT[i] = qw[o * 48 + c];
  }
  if (tid < 144) { s_ipw[tid] = ipw[tid]; s_qb[tid] = qb[tid]; }
  if (tid < 48) { s_ipb[tid] = ipb[tid]; s_lnw[tid] = lnw[tid]; s_lnb[tid] = lnb[tid]; }
  __syncthreads();
  const int b = blockIdx.x >> 8;
  const int n = ((blockIdx.x & 255) << 8) + tid;
  const float x0 = x[((size_t)b * 3 + 0) * NPIX + n];
  const float x1 = x[((size_t)b * 3 + 1) * NPIX + n];
  const float x2 = x[((size_t)b * 3 + 2) * NPIX + n];
  char* slab = (char*)region + ((size_t)b * NPIX + n) * SLABB;
  float4* xp4 = (float4*)slab;
  float4* q4 = (float4*)(slab + 192);
  float xn[48];
  float mu = 0.f;
#pragma unroll
  for (int c = 0; c < 48; ++c) {
    xn[c] = s_ipw[c * 3] * x0 + s_ipw[c * 3 + 1] * x1 + s_ipw[c * 3 + 2] * x2 + s_ipb[c];
    mu += xn[c];
  }
#pragma unroll
  for (int c4 = 0; c4 < 12; ++c4) {
    float4 v; v.x = xn[4*c4]; v.y = xn[4*c4+1]; v.z = xn[4*c4+2]; v.w = xn[4*c4+3];
    xp4[c4] = v;
  }
  mu *= (1.f / 48.f);
  float var = 0.f;
#pragma unroll
  for (int c = 0; c < 48; ++c) { const float d = xn[c] - mu; var += d * d; }
  const float rs = rsqrtf(var * (1.f / 48.f) + 1e-6f);
#pragma unroll
  for (int c = 0; c < 48; ++c) xn[c] = (xn[c] - mu) * rs * s_lnw[c] + s_lnb[c];
#pragma unroll
  for (int ob = 0; ob < 9; ++ob) {
    const int o0 = ob * 16;
    float acc[16];
#pragma unroll
    for (int j = 0; j < 16; ++j) acc[j] = s_qb[o0 + j];
#pragma unroll 4
    for (int c = 0; c < 48; ++c) {
      const float xv = xn[c];
      const float4 w0 = *(const float4*)&wT[c * 144 + o0];
      const float4 w1 = *(const float4*)&wT[c * 144 + o0 + 4];
      const float4 w2 = *(const float4*)&wT[c * 144 + o0 + 8];
      const float4 w3 = *(const float4*)&wT[c * 144 + o0 + 12];
      acc[0] += w0.x * xv; acc[1] += w0.y * xv; acc[2] += w0.z * xv; acc[3] += w0.w * xv;
      acc[4] += w1.x * xv; acc[5] += w1.y * xv; acc[6] += w1.z * xv; acc[7] += w1.w * xv;
      acc[8] += w2.x * xv; acc[9] += w2.y * xv; acc[10] += w2.z * xv; acc[11] += w2.w * xv;
      acc[12] += w3.x * xv; acc[13] += w3.y * xv; acc[14] += w3.z * xv; acc[15] += w3.w * xv;
    }
    H16 u;
    u.h2[0] = pack2(acc[0], acc[1]);  u.h2[1] = pack2(acc[2], acc[3]);
    u.h2[2] = pack2(acc[4], acc[5]);  u.h2[3] = pack2(acc[6], acc[7]);
    q4[ob * 2] = u.f4;
    u.h2[0] = pack2(acc[8], acc[9]);  u.h2[1] = pack2(acc[10], acc[11]);
    u.h2[2] = pack2(acc[12], acc[13]); u.h2[3] = pack2(acc[14], acc[15]);
    q4[ob * 2 + 1] = u.f4;
  }
}

// ---------------- k2b: dwconv stencil + Gram partials + vdw ----------------
// qkv channel index within slab: q = 0..47, k = 48..95, v = 96..143.
__global__ __launch_bounds__(256, 3) void k2b(
    float* region, const float* __restrict__ dww, const float* __restrict__ dwb,
    float* __restrict__ red) {
  __shared__ __align__(16) float halo[12 * HST];
  __shared__ __align__(16) float qs[12 * 260];
  __shared__ __align__(16) float ks[12 * 260];
  __shared__ float s_dww[144 * 9], s_dwb[144];
  const int tid = threadIdx.x;
  for (int i = tid; i < 1296; i += 256) s_dww[i] = dww[i];
  if (tid < 144) s_dwb[tid] = dwb[tid];
  const int b = blockIdx.x >> 8;
  const int tile = blockIdx.x & 255;
  const int ty0 = (tile >> 4) << 4, tx0 = (tile & 15) << 4;
  const int py = tid >> 4, px = tid & 15;
  const int hp = (py + 1) * 18 + (px + 1);
  const int gn = ((ty0 + py) << 8) + (tx0 + px);
  char* regb = (char*)region + (size_t)b * NPIX * SLABB;

  float2 pf[2][3];
  auto prefetch = [&](int cq) {   // cq: half-channel offset within qkv block
#pragma unroll
    for (int r = 0; r < 2; ++r) {
      const int p = tid + r * 256;
      float2 z; z.x = z.y = 0.f;
      pf[r][0] = z; pf[r][1] = z; pf[r][2] = z;
      if (p < 324) {
        const int hy = p / 18, hx = p - hy * 18;
        const int gy = ty0 + hy - 1, gx = tx0 + hx - 1;
        if (((unsigned)gy < 256u) && ((unsigned)gx < 256u)) {
          const float2* s2 = (const float2*)(regb +
              ((size_t)((gy << 8) + gx)) * SLABB + 192 + 2 * cq);
          pf[r][0] = s2[0]; pf[r][1] = s2[1]; pf[r][2] = s2[2];
        }
      }
    }
  };
  auto commit = [&]() {
#pragma unroll
    for (int r = 0; r < 2; ++r) {
      const int p = tid + r * 256;
      if (p < 324) {
#pragma unroll
        for (int j = 0; j < 3; ++j) {
          H8 u; u.f2 = pf[r][j];
          halo[(j * 4 + 0) * HST + p] = __low2float(u.h2[0]);
          halo[(j * 4 + 1) * HST + p] = __high2float(u.h2[0]);
          halo[(j * 4 + 2) * HST + p] = __low2float(u.h2[1]);
          halo[(j * 4 + 3) * HST + p] = __high2float(u.h2[1]);
        }
      }
    }
  };

  prefetch(0);                        // q head 0
  for (int h = 0; h < 4; ++h) {
    __syncthreads();                  // prior halo consumers done
    commit();
    __syncthreads();                  // q halo ready
    prefetch(48 + 12 * h);            // k_h
#pragma unroll
    for (int j = 0; j < 12; ++j) {
      const int ch = 12 * h + j;
      qs[j * 260 + tid] = s_dwb[ch] + dw9(&halo[j * HST + hp], &s_dww[ch * 9]);
    }
    __syncthreads();                  // q compute done, halo free
    commit();
    __syncthreads();                  // k halo ready
    prefetch(h < 3 ? 12 * (h + 1) : 96);   // next q or v0
#pragma unroll
    for (int j = 0; j < 12; ++j) {
      const int ch = 48 + 12 * h + j;
      ks[j * 260 + tid] = s_dwb[ch] + dw9(&halo[j * HST + hp], &s_dww[ch * 9]);
    }
    __syncthreads();                  // qs,ks visible; halo free
    if (tid < 168) {
      const int e = tid;
      float s = 0.f;
      if (e < 144) {
        const int c = e / 12, d = e - c * 12;
        const float4* qa = (const float4*)&qs[c * 260];
        const float4* kb = (const float4*)&ks[d * 260];
        for (int p4 = 0; p4 < 64; ++p4) {
          const float4 a = qa[p4], bb = kb[p4];
          s += a.x * bb.x + a.y * bb.y + a.z * bb.z + a.w * bb.w;
        }
      } else if (e < 156) {
        const float4* qa = (const float4*)&qs[(e - 144) * 260];
        for (int p4 = 0; p4 < 64; ++p4) {
          const float4 a = qa[p4];
          s += a.x * a.x + a.y * a.y + a.z * a.z + a.w * a.w;
        }
      } else {
        const float4* kb = (const float4*)&ks[(e - 156) * 260];
        for (int p4 = 0; p4 < 64; ++p4) {
          const float4 a = kb[p4];
          s += a.x * a.x + a.y * a.y + a.z * a.z + a.w * a.w;
        }
      }
      atomicAdd(&red[b * 672 + h * 168 + e], s);
    }
  }
  for (int g = 0; g < 4; ++g) {
    __syncthreads();
    commit();
    __syncthreads();
    if (g < 3) prefetch(96 + 12 * (g + 1));
    float vr[12];
#pragma unroll
    for (int j = 0; j < 12; ++j) {
      const int ch = 96 + 12 * g + j;
      vr[j] = s_dwb[ch] + dw9(&halo[j * HST + hp], &s_dww[ch * 9]);
    }
    float2* d2 = (float2*)(regb + (size_t)gn * SLABB + 480 + 24 * g);
    H8 u;
    u.h2[0] = pack2(vr[0], vr[1]);  u.h2[1] = pack2(vr[2], vr[3]);  d2[0] = u.f2;
    u.h2[0] = pack2(vr[4], vr[5]);  u.h2[1] = pack2(vr[6], vr[7]);  d2[1] = u.f2;
    u.h2[0] = pack2(vr[8], vr[9]);  u.h2[1] = pack2(vr[10], vr[11]); d2[2] = u.f2;
  }
}

// ---------------- k3: finalize attn, build fused M ----------------
__global__ __launch_bounds__(256) void k3_attn(const float* __restrict__ red,
                                               const float* __restrict__ temp,
                                               const float* __restrict__ aow,
                                               float* __restrict__ Mws) {
  __shared__ float attn[4 * 144];
  const int b = blockIdx.x, tid = threadIdx.x;
  const float* rb = red + b * 672;
  for (int e = tid; e < 576; e += 256) {
    const int h = e / 144, r = e - h * 144;
    const int c = r / 12, d = r - c * 12;
    const float g = rb[h * 168 + r];
    const float nq = fmaxf(sqrtf(rb[h * 168 + 144 + c]), 1e-12f);
    const float nk = fmaxf(sqrtf(rb[h * 168 + 156 + d]), 1e-12f);
    attn[e] = g / (nq * nk) * temp[h];
  }
  __syncthreads();
  if (tid < 48) {
    const int h = tid / 12, c = tid - h * 12;
    float* row = &attn[h * 144 + c * 12];
    float m = row[0];
    for (int d = 1; d < 12; ++d) m = fmaxf(m, row[d]);
    float s = 0.f;
    for (int d = 0; d < 12; ++d) { const float e2 = expf(row[d] - m); row[d] = e2; s += e2; }
    const float inv = 1.f / s;
    for (int d = 0; d < 12; ++d) row[d] *= inv;
  }
  __syncthreads();
  for (int e = tid; e < 2304; e += 256) {
    const int o = e / 48, j = e - o * 48;
    const int h = j / 12, d = j - h * 12;
    float s = 0.f;
    for (int c = 0; c < 12; ++c)
      s += aow[o * 48 + h * 12 + c] * attn[h * 144 + c * 12 + d];
    Mws[b * 2304 + e] = s;
  }
}

// ---------------- k4a: attn-out + residual + LN2 + ffn_in conv ----------------
__global__ __launch_bounds__(256, 3) void k4a(
    float* region, const float* __restrict__ Mws, const float* __restrict__ aob,
    const float* __restrict__ lnw, const float* __restrict__ lnb,
    const float* __restrict__ fiw, const float* __restrict__ fib,
    const float* __restrict__ opw) {
  __shared__ __align__(16) float MT[48 * 48];     // MT[j][o]
  __shared__ __align__(16) float wT2[48 * 192];   // wT2[c][pos], pos interleaved
  __shared__ float s_aob[48], s_lnw[48], s_lnb[48], s_fib2[192], s_opw[144];
  const int tid = threadIdx.x;
  const int b = blockIdx.x >> 8;
  const int n = ((blockIdx.x & 255) << 8) + tid;
  for (int i = tid; i < 2304; i += 256) {
    const int o = i / 48, j = i - o * 48;
    MT[j * 48 + o] = Mws[b * 2304 + i];
  }
  for (int i = tid; i < 9216; i += 256) {
    const int c = i / 192, pos = i - c * 192;
    const int ch = (pos & 1) ? 96 + (pos >> 1) : (pos >> 1);
    wT2[i] = fiw[ch * 48 + c];
  }
  if (tid < 192) {
    const int ch = (tid & 1) ? 96 + (tid >> 1) : (tid >> 1);
    s_fib2[tid] = fib[ch];
  }
  if (tid < 144) s_opw[tid] = opw[tid];
  if (tid < 48) { s_aob[tid] = aob[tid]; s_lnw[tid] = lnw[tid]; s_lnb[tid] = lnb[tid]; }
  __syncthreads();
  char* slab = (char*)region + ((size_t)b * NPIX + n) * SLABB;
  float vv[48];
  {
    const float4* v4 = (const float4*)(slab + 480);
#pragma unroll
    for (int i = 0; i < 6; ++i) {
      H16 u; u.f4 = v4[i];
      vv[8*i+0] = __low2float(u.h2[0]);  vv[8*i+1] = __high2float(u.h2[0]);
      vv[8*i+2] = __low2float(u.h2[1]);  vv[8*i+3] = __high2float(u.h2[1]);
      vv[8*i+4] = __low2float(u.h2[2]);  vv[8*i+5] = __high2float(u.h2[2]);
      vv[8*i+6] = __low2float(u.h2[3]);  vv[8*i+7] = __high2float(u.h2[3]);
    }
  }
  float y[48];
#pragma unroll
  for (int o = 0; o < 48; ++o) y[o] = s_aob[o];
#pragma unroll 4
  for (int j = 0; j < 48; ++j) {
    const float vj = vv[j];
    const float* mr = &MT[j * 48];
#pragma unroll
    for (int o4 = 0; o4 < 12; ++o4) {
      const float4 m = *(const float4*)&mr[o4 * 4];
      y[o4 * 4 + 0] += m.x * vj; y[o4 * 4 + 1] += m.y * vj;
      y[o4 * 4 + 2] += m.z * vj; y[o4 * 4 + 3] += m.w * vj;
    }
  }
  float mu = 0.f;
  {
    const float4* xp4 = (const float4*)slab;
#pragma unroll
    for (int j4 = 0; j4 < 12; ++j4) {
      const float4 t4 = xp4[j4];
      y[4*j4] += t4.x; y[4*j4+1] += t4.y; y[4*j4+2] += t4.z; y[4*j4+3] += t4.w;
      mu += y[4*j4] + y[4*j4+1] + y[4*j4+2] + y[4*j4+3];
    }
  }
  float s0 = 0.f, s1 = 0.f, s2 = 0.f;
#pragma unroll
  for (int c = 0; c < 48; ++c) {
    s0 += s_opw[c] * y[c]; s1 += s_opw[48 + c] * y[c]; s2 += s_opw[96 + c] * y[c];
  }
  float* s0p = (float*)(slab + 576);
  s0p[0] = s0; s0p[1] = s1; s0p[2] = s2;
  mu *= (1.f / 48.f);
  float var = 0.f;
#pragma unroll
  for (int c = 0; c < 48; ++c) { const float d = y[c] - mu; var += d * d; }
  const float rs2 = rsqrtf(var * (1.f / 48.f) + 1e-6f);
#pragma unroll
  for (int c = 0; c < 48; ++c) y[c] = (y[c] - mu) * rs2 * s_lnw[c] + s_lnb[c];
  float4* y4 = (float4*)(slab + 192);
#pragma unroll
  for (int ob = 0; ob < 12; ++ob) {
    const int o0 = ob * 16;
    float acc[16];
#pragma unroll
    for (int j = 0; j < 16; ++j) acc[j] = s_fib2[o0 + j];
#pragma unroll 4
    for (int c = 0; c < 48; ++c) {
      const float xv = y[c];
      const float4 w0 = *(const float4*)&wT2[c * 192 + o0];
      const float4 w1 = *(const float4*)&wT2[c * 192 + o0 + 4];
      const float4 w2 = *(const float4*)&wT2[c * 192 + o0 + 8];
      const float4 w3 = *(const float4*)&wT2[c * 192 + o0 + 12];
      acc[0] += w0.x * xv; acc[1] += w0.y * xv; acc[2] += w0.z * xv; acc[3] += w0.w * xv;
      acc[4] += w1.x * xv; acc[5] += w1.y * xv; acc[6] += w1.z * xv; acc[7] += w1.w * xv;
      acc[8] += w2.x * xv; acc[9] += w2.y * xv; acc[10] += w2.z * xv; acc[11] += w2.w * xv;
      acc[12] += w3.x * xv; acc[13] += w3.y * xv; acc[14] += w3.z * xv; acc[15] += w3.w * xv;
    }
    H16 u;
    u.h2[0] = pack2(acc[0], acc[1]);  u.h2[1] = pack2(acc[2], acc[3]);
    u.h2[2] = pack2(acc[4], acc[5]);  u.h2[3] = pack2(acc[6], acc[7]);
    y4[ob * 2] = u.f4;
    u.h2[0] = pack2(acc[8], acc[9]);  u.h2[1] = pack2(acc[10], acc[11]);
    u.h2[2] = pack2(acc[12], acc[13]); u.h2[3] = pack2(acc[14], acc[15]);
    y4[ob * 2 + 1] = u.f4;
  }
}

// ---------------- k5b: dw + SimpleGate + ffn_out + out_proj ----------------
__global__ __launch_bounds__(256, 3) void k5b(
    const float* __restrict__ region, const float* __restrict__ fdww,
    const float* __restrict__ fdwb, const float* __restrict__ fow,
    const float* __restrict__ fob, const float* __restrict__ opw,
    const float* __restrict__ opb, float* __restrict__ out) {
  __shared__ __align__(16) float halo[12 * HST];
  __shared__ __align__(16) float fowT[96 * 48];   // fowT[c1][o] = fow[o][c1]
  __shared__ float s_dww2[192 * 9], s_dwb2[192], s_opw[144], s_fob[48];
  const int tid = threadIdx.x;
  for (int i = tid; i < 4608; i += 256) {
    const int c = i / 48, o = i - c * 48;
    fowT[i] = fow[o * 96 + c];
  }
  for (int i = tid; i < 1728; i += 256) {
    const int P = i / 9, t = i - P * 9;
    const int ch = (P & 1) ? 96 + (P >> 1) : (P >> 1);
    s_dww2[i] = fdww[ch * 9 + t];
  }
  if (tid < 192) {
    const int ch = (tid & 1) ? 96 + (tid >> 1) : (tid >> 1);
    s_dwb2[tid] = fdwb[ch];
  }
  if (tid < 144) s_opw[tid] = opw[tid];
  if (tid < 48) s_fob[tid] = fob[tid];
  const int b = blockIdx.x >> 8;
  const int tile = blockIdx.x & 255;
  const int ty0 = (tile >> 4) << 4, tx0 = (tile & 15) << 4;
  const int py = tid >> 4, px = tid & 15;
  const int hp = (py + 1) * 18 + (px + 1);
  const int gn = ((ty0 + py) << 8) + (tx0 + px);
  const char* regb = (const char*)region + (size_t)b * NPIX * SLABB;

  float2 pf[2][3];
  auto prefetch = [&](int cy) {   // cy: y-position offset (halves) in [0,192)
#pragma unroll
    for (int r = 0; r < 2; ++r) {
      const int p = tid + r * 256;
      float2 z; z.x = z.y = 0.f;
      pf[r][0] = z; pf[r][1] = z; pf[r][2] = z;
      if (p < 324) {
        const int hy = p / 18, hx = p - hy * 18;
        const int gy = ty0 + hy - 1, gx = tx0 + hx - 1;
        if (((unsigned)gy < 256u) && ((unsigned)gx < 256u)) {
          const float2* s2 = (const float2*)(regb +
              ((size_t)((gy << 8) + gx)) * SLABB + 192 + 2 * cy);
          pf[r][0] = s2[0]; pf[r][1] = s2[1]; pf[r][2] = s2[2];
        }
      }
    }
  };
  auto commit = [&]() {
#pragma unroll
    for (int r = 0; r < 2; ++r) {
      const int p = tid + r * 256;
      if (p < 324) {
#pragma unroll
        for (int j = 0; j < 3; ++j) {
          H8 u; u.f2 = pf[r][j];
          halo[(j * 4 + 0) * HST + p] = __low2float(u.h2[0]);
          halo[(j * 4 + 1) * HST + p] = __high2float(u.h2[0]);
          halo[(j * 4 + 2) * HST + p] = __low2float(u.h2[1]);
          halo[(j * 4 + 3) * HST + p] = __high2float(u.h2[1]);
        }
      }
    }
  };

  float facc[48];
#pragma unroll
  for (int o = 0; o < 48; ++o) facc[o] = 0.f;
  prefetch(0);
  for (int g = 0; g < 16; ++g) {
    __syncthreads();
    commit();
    __syncthreads();
    if (g < 15) prefetch(12 * (g + 1));
#pragma unroll
    for (int j = 0; j < 6; ++j) {
      const int PA = g * 12 + 2 * j, PBo = PA + 1;
      const float a  = s_dwb2[PA]  + dw9(&halo[(2*j) * HST + hp], &s_dww2[PA * 9]);
      const float b2 = s_dwb2[PBo] + dw9(&halo[(2*j+1) * HST + hp], &s_dww2[PBo * 9]);
      const float gate = a * b2;
      const float* fr = &fowT[(g * 6 + j) * 48];
#pragma unroll
      for (int o4 = 0; o4 < 12; ++o4) {
        const float4 m = *(const float4*)&fr[o4 * 4];
        facc[o4 * 4 + 0] += m.x * gate; facc[o4 * 4 + 1] += m.y * gate;
        facc[o4 * 4 + 2] += m.z * gate; facc[o4 * 4 + 3] += m.w * gate;
      }
    }
  }
  const float* s0p = (const float*)(regb + (size_t)gn * SLABB + 576);
  float r0 = s0p[0] + opb[0];
  float r1 = s0p[1] + opb[1];
  float r2 = s0p[2] + opb[2];
#pragma unroll
  for (int o = 0; o < 48; ++o) {
    const float f = facc[o] + s_fob[o];
    r0 += s_opw[o] * f; r1 += s_opw[48 + o] * f; r2 += s_opw[96 + o] * f;
  }
  out[((size_t)b * 3 + 0) * NPIX + gn] = r0;
  out[((size_t)b * 3 + 1) * NPIX + gn] = r1;
  out[((size_t)b * 3 + 2) * NPIX + gn] = r2;
}

extern "C" void kernel_launch(void* const* d_in, const int* in_sizes, int n_in,
                              void* d_out, int out_size, void* d_ws, size_t ws_size,
                              hipStream_t stream) {
  const float* x    = (const float*)d_in[0];
  const float* ipw  = (const float*)d_in[1];
  const float* ipb  = (const float*)d_in[2];
  const float* ln1w = (const float*)d_in[3];
  const float* ln1b = (const float*)d_in[4];
  const float* qw   = (const float*)d_in[5];
  const float* qb   = (const float*)d_in[6];
  const float* qdww = (const float*)d_in[7];
  const float* qdwb = (const float*)d_in[8];
  const float* temp = (const float*)d_in[9];
  const float* aow  = (const float*)d_in[10];
  const float* aob  = (const float*)d_in[11];
  const float* ln2w = (const float*)d_in[12];
  const float* ln2b = (const float*)d_in[13];
  const float* fiw  = (const float*)d_in[14];
  const float* fib  = (const float*)d_in[15];
  const float* fdww = (const float*)d_in[16];
  const float* fdwb = (const float*)d_in[17];
  const float* fow  = (const float*)d_in[18];
  const float* fob  = (const float*)d_in[19];
  const float* opw  = (const float*)d_in[20];
  const float* opb  = (const float*)d_in[21];

  const size_t perb = (size_t)SLABF * NPIX;   // floats per batch in region
  int bc = 8;
  while (bc > 1 && ((size_t)bc * perb + 5376 + 18432) * sizeof(float) > ws_size)
    bc >>= 1;
  float* region = (float*)d_ws;
  float* red = region + (size_t)bc * perb;
  float* Mws = red + 5376;
  hipMemsetAsync(red, 0, 5376 * sizeof(float), stream);
  for (int b0 = 0; b0 < 8; b0 += bc) {
    k2a<<<bc * 256, 256, 0, stream>>>(x + (size_t)b0 * 3 * NPIX, ipw, ipb,
                                      ln1w, ln1b, qw, qb, region);
    k2b<<<bc * 256, 256, 0, stream>>>(region, qdww, qdwb, red + b0 * 672);
    k3_attn<<<bc, 256, 0, stream>>>(red + b0 * 672, temp, aow,
                                    Mws + (size_t)b0 * 2304);
    k4a<<<bc * 256, 256, 0, stream>>>(region, Mws + (size_t)b0 * 2304, aob,
                                      ln2w, ln2b, fiw, fib, opw);
    k5b<<<bc * 256, 256, 0, stream>>>(region, fdww, fdwb, fow, fob, opw, opb,
                                      (float*)d_out + (size_t)b0 * 3 * NPIX);
  }
}

// Round 6
// 1290.535 us; speedup vs baseline: 2.0812x; 1.0979x over previous
//
#include <hip/hip_runtime.h>
#include <hip/hip_fp16.h>

// CAPTNet block. B=8, CIN=3, H=W=256, DIM=48, HEADS=4 (ch=12), HID=96.
// Round 6: 448-B line-aligned pixel slab, xp eliminated (k4a recomputes
// in_proj), coalesced 48-B float4 halo staging with fp16 LDS.
// Slab (448 B = 7 x 64B lines) per pixel:
//   [0,288)   qkv 144 fp16 (k2a)   -+ overwritten by y 192 fp16 [0,384) (k4a)
//   [288,320) pad (zeros, k2a)     -+
//   [320,416) vdw 48 fp16 (k2b)
//   [416,448) pad (zeros, k2b)
// s0: separate float4-per-pixel array (k4a -> k5b).
// Pipeline: k2a (pixel: in_proj+LN1+qkv conv -> qkv fp16) -> k2b (tile:
// 6-stage dwconv q/k/v + per-head-pair Gram atomics + vdw) -> k3 (attn
// finalize, fold attn_out_w -> M) -> k4a (pixel: recompute in_proj, += M@vdw,
// s0=opw@xp2, LN2, ffn_in conv -> y fp16) -> k5b (tile: 8-stage dwconv pairs
// + SimpleGate + ffn_out + out_proj).

#define NPIX 65536
#define SLABB 448
#define HSTRIDE 332   // halo LDS row stride (half2 elems), 324 px + pad
#define QSTRIDE 258   // qs/ks LDS row stride (half2 elems), 256 px + pad

union F4U { float4 f4; unsigned int u[4]; };

__device__ __forceinline__ float2 uh2f(unsigned int u) {
  __half2 h; *(unsigned int*)&h = u; return __half22float2(h);
}
__device__ __forceinline__ unsigned int fpack(float a, float b) {
  __half2 h = __halves2half2(__float2half_rn(a), __float2half_rn(b));
  return *(unsigned int*)&h;
}

// ---------------- k2a: in_proj + LN1 + qkv conv1x1 -> qkv fp16 ----------------
__global__ __launch_bounds__(256, 4) void k2a(
    const float* __restrict__ x, const float* __restrict__ ipw,
    const float* __restrict__ ipb, const float* __restrict__ lnw,
    const float* __restrict__ lnb, const float* __restrict__ qw,
    const float* __restrict__ qb, char* __restrict__ region) {
  __shared__ __align__(16) float wT[48 * 144];   // wT[c][o] = qw[o][c]
  __shared__ float s_ipw[144], s_ipb[48], s_lnw[48], s_lnb[48], s_qb[144];
  const int tid = threadIdx.x;
  for (int i = tid; i < 6912; i += 256) {
    const int c = i / 144, o = i - c * 144;
    wT[i] = qw[o * 48 + c];
  }
  if (tid < 144) { s_ipw[tid] = ipw[tid]; s_qb[tid] = qb[tid]; }
  if (tid < 48) { s_ipb[tid] = ipb[tid]; s_lnw[tid] = lnw[tid]; s_lnb[tid] = lnb[tid]; }
  __syncthreads();
  const int b = blockIdx.x >> 8;
  const int n = ((blockIdx.x & 255) << 8) + tid;
  const float x0 = x[((size_t)b * 3 + 0) * NPIX + n];
  const float x1 = x[((size_t)b * 3 + 1) * NPIX + n];
  const float x2 = x[((size_t)b * 3 + 2) * NPIX + n];
  float4* q4 = (float4*)(region + ((size_t)b * NPIX + n) * SLABB);
  float xn[48];
  float mu = 0.f;
#pragma unroll
  for (int c = 0; c < 48; ++c) {
    xn[c] = s_ipw[c * 3] * x0 + s_ipw[c * 3 + 1] * x1 + s_ipw[c * 3 + 2] * x2 + s_ipb[c];
    mu += xn[c];
  }
  mu *= (1.f / 48.f);
  float var = 0.f;
#pragma unroll
  for (int c = 0; c < 48; ++c) { const float d = xn[c] - mu; var += d * d; }
  const float rs = rsqrtf(var * (1.f / 48.f) + 1e-6f);
#pragma unroll
  for (int c = 0; c < 48; ++c) xn[c] = (xn[c] - mu) * rs * s_lnw[c] + s_lnb[c];
#pragma unroll
  for (int ob = 0; ob < 9; ++ob) {
    const int o0 = ob * 16;
    float acc[16];
#pragma unroll
    for (int j = 0; j < 16; ++j) acc[j] = s_qb[o0 + j];
#pragma unroll 4
    for (int c = 0; c < 48; ++c) {
      const float xv = xn[c];
      const float4 w0 = *(const float4*)&wT[c * 144 + o0];
      const float4 w1 = *(const float4*)&wT[c * 144 + o0 + 4];
      const float4 w2 = *(const float4*)&wT[c * 144 + o0 + 8];
      const float4 w3 = *(const float4*)&wT[c * 144 + o0 + 12];
      acc[0] += w0.x * xv; acc[1] += w0.y * xv; acc[2] += w0.z * xv; acc[3] += w0.w * xv;
      acc[4] += w1.x * xv; acc[5] += w1.y * xv; acc[6] += w1.z * xv; acc[7] += w1.w * xv;
      acc[8] += w2.x * xv; acc[9] += w2.y * xv; acc[10] += w2.z * xv; acc[11] += w2.w * xv;
      acc[12] += w3.x * xv; acc[13] += w3.y * xv; acc[14] += w3.z * xv; acc[15] += w3.w * xv;
    }
    F4U u;
    u.u[0] = fpack(acc[0], acc[1]);   u.u[1] = fpack(acc[2], acc[3]);
    u.u[2] = fpack(acc[4], acc[5]);   u.u[3] = fpack(acc[6], acc[7]);
    q4[ob * 2] = u.f4;
    u.u[0] = fpack(acc[8], acc[9]);   u.u[1] = fpack(acc[10], acc[11]);
    u.u[2] = fpack(acc[12], acc[13]); u.u[3] = fpack(acc[14], acc[15]);
    q4[ob * 2 + 1] = u.f4;
  }
  const float4 z = {0.f, 0.f, 0.f, 0.f};
  q4[18] = z; q4[19] = z;   // pad [288,320) -> full-line writes
}

// ---------------- k2b: 6-stage dwconv + Gram + vdw ----------------
__global__ __launch_bounds__(256, 3) void k2b(
    char* __restrict__ region, const float* __restrict__ dww,
    const float* __restrict__ dwb, float* __restrict__ red) {
  __shared__ unsigned int halo[12 * HSTRIDE];
  __shared__ unsigned int qsm[12 * QSTRIDE];
  __shared__ unsigned int ksm[12 * QSTRIDE];
  __shared__ float s_dww[1296], s_dwb[144];
  const int tid = threadIdx.x;
  for (int i = tid; i < 1296; i += 256) s_dww[i] = dww[i];
  if (tid < 144) s_dwb[tid] = dwb[tid];
  const int b = blockIdx.x >> 8;
  const int tile = blockIdx.x & 255;
  const int ty0 = (tile >> 4) << 4, tx0 = (tile & 15) << 4;
  const int py = tid >> 4, px = tid & 15;
  const int hp = (py + 1) * 18 + (px + 1);
  const int gn = ((ty0 + py) << 8) + (tx0 + px);
  char* regb = region + (size_t)b * NPIX * SLABB;

  float4 pf[4];
  auto prefetch = [&](int boff) {
#pragma unroll
    for (int r = 0; r < 4; ++r) {
      const int i = tid + (r << 8);
      float4 z = {0.f, 0.f, 0.f, 0.f}; pf[r] = z;
      if (i < 972) {
        const int p = i / 3, c4 = i - p * 3;
        const int hy = p / 18, hx = p - hy * 18;
        const int gy = ty0 + hy - 1, gx = tx0 + hx - 1;
        if (((unsigned)gy < 256u) && ((unsigned)gx < 256u))
          pf[r] = *(const float4*)(regb + (size_t)((gy << 8) + gx) * SLABB + boff + (c4 << 4));
      }
    }
  };
  auto commit = [&]() {
#pragma unroll
    for (int r = 0; r < 4; ++r) {
      const int i = tid + (r << 8);
      if (i < 972) {
        const int p = i / 3, c4 = i - p * 3;
        F4U u; u.f4 = pf[r];
        const int pb = c4 << 2;
#pragma unroll
        for (int j = 0; j < 4; ++j) halo[(pb + j) * HSTRIDE + p] = u.u[j];
      }
    }
  };
  auto dwconv24 = [&](int cb, unsigned int* dst) {
    const int offs[9] = {-19, -18, -17, -1, 0, 1, 17, 18, 19};
#pragma unroll
    for (int pp = 0; pp < 12; ++pp) {
      const float* w0 = &s_dww[(cb + 2 * pp) * 9];
      const float* w1 = w0 + 9;
      const unsigned int* hrow = &halo[pp * HSTRIDE + hp];
      float a = s_dwb[cb + 2 * pp], b2 = s_dwb[cb + 2 * pp + 1];
#pragma unroll
      for (int t = 0; t < 9; ++t) {
        const float2 f = uh2f(hrow[offs[t]]);
        a += w0[t] * f.x; b2 += w1[t] * f.y;
      }
      dst[pp * QSTRIDE + tid] = fpack(a, b2);
    }
  };
  auto gram2 = [&](int hbase) {
    for (int e = tid; e < 336; e += 256) {
      const int hh = e / 168, r = e - hh * 168;
      float s = 0.f;
      if (r < 144) {
        const int c = r / 12, d = r - (r / 12) * 12;
        const int qc = 12 * hh + c, kd = 12 * hh + d;
        const unsigned int* qr = &qsm[(qc >> 1) * QSTRIDE];
        const unsigned int* kr = &ksm[(kd >> 1) * QSTRIDE];
        const int q1 = qc & 1, k1 = kd & 1;
        for (int p = 0; p < 256; ++p) {
          const float2 fq = uh2f(qr[p]); const float2 fk = uh2f(kr[p]);
          s += (q1 ? fq.y : fq.x) * (k1 ? fk.y : fk.x);
        }
      } else if (r < 156) {
        const int qc = 12 * hh + (r - 144);
        const unsigned int* qr = &qsm[(qc >> 1) * QSTRIDE];
        const int q1 = qc & 1;
        for (int p = 0; p < 256; ++p) {
          const float2 fq = uh2f(qr[p]);
          const float v = q1 ? fq.y : fq.x;
          s += v * v;
        }
      } else {
        const int kd = 12 * hh + (r - 156);
        const unsigned int* kr = &ksm[(kd >> 1) * QSTRIDE];
        const int k1 = kd & 1;
        for (int p = 0; p < 256; ++p) {
          const float2 fk = uh2f(kr[p]);
          const float v = k1 ? fk.y : fk.x;
          s += v * v;
        }
      }
      atomicAdd(&red[b * 672 + (hbase + hh) * 168 + r], s);
    }
  };

  prefetch(0);                                   // q ch 0-23
  __syncthreads(); commit(); __syncthreads();
  prefetch(96);  dwconv24(0, qsm);               // next: k ch 0-23
  __syncthreads(); commit(); __syncthreads();
  prefetch(48);  dwconv24(48, ksm);              // next: q ch 24-47
  __syncthreads(); commit(); gram2(0); __syncthreads();
  prefetch(144); dwconv24(24, qsm);              // next: k ch 24-47
  __syncthreads(); commit(); __syncthreads();
  prefetch(192); dwconv24(72, ksm);              // next: v ch 0-23
  __syncthreads(); commit(); gram2(2); __syncthreads();
  prefetch(240);                                 // v ch 24-47
  unsigned int vp[24];
  {
    const int offs[9] = {-19, -18, -17, -1, 0, 1, 17, 18, 19};
#pragma unroll
    for (int pp = 0; pp < 12; ++pp) {
      const float* w0 = &s_dww[(96 + 2 * pp) * 9];
      const float* w1 = w0 + 9;
      const unsigned int* hrow = &halo[pp * HSTRIDE + hp];
      float a = s_dwb[96 + 2 * pp], b2 = s_dwb[96 + 2 * pp + 1];
#pragma unroll
      for (int t = 0; t < 9; ++t) {
        const float2 f = uh2f(hrow[offs[t]]);
        a += w0[t] * f.x; b2 += w1[t] * f.y;
      }
      vp[pp] = fpack(a, b2);
    }
  }
  __syncthreads(); commit(); __syncthreads();
  {
    const int offs[9] = {-19, -18, -17, -1, 0, 1, 17, 18, 19};
#pragma unroll
    for (int pp = 0; pp < 12; ++pp) {
      const float* w0 = &s_dww[(120 + 2 * pp) * 9];
      const float* w1 = w0 + 9;
      const unsigned int* hrow = &halo[pp * HSTRIDE + hp];
      float a = s_dwb[120 + 2 * pp], b2 = s_dwb[120 + 2 * pp + 1];
#pragma unroll
      for (int t = 0; t < 9; ++t) {
        const float2 f = uh2f(hrow[offs[t]]);
        a += w0[t] * f.x; b2 += w1[t] * f.y;
      }
      vp[12 + pp] = fpack(a, b2);
    }
  }
  float4* wv = (float4*)(regb + (size_t)gn * SLABB + 320);
#pragma unroll
  for (int q = 0; q < 6; ++q) {
    F4U u;
    u.u[0] = vp[4 * q]; u.u[1] = vp[4 * q + 1];
    u.u[2] = vp[4 * q + 2]; u.u[3] = vp[4 * q + 3];
    wv[q] = u.f4;
  }
  const float4 z = {0.f, 0.f, 0.f, 0.f};
  wv[6] = z; wv[7] = z;   // pad [416,448)
}

// ---------------- k3: finalize attn, build fused M ----------------
__global__ __launch_bounds__(256) void k3_attn(const float* __restrict__ red,
                                               const float* __restrict__ temp,
                                               const float* __restrict__ aow,
                                               float* __restrict__ Mws) {
  __shared__ float attn[4 * 144];
  const int b = blockIdx.x, tid = threadIdx.x;
  const float* rb = red + b * 672;
  for (int e = tid; e < 576; e += 256) {
    const int h = e / 144, r = e - h * 144;
    const int c = r / 12, d = r - c * 12;
    const float g = rb[h * 168 + r];
    const float nq = fmaxf(sqrtf(rb[h * 168 + 144 + c]), 1e-12f);
    const float nk = fmaxf(sqrtf(rb[h * 168 + 156 + d]), 1e-12f);
    attn[e] = g / (nq * nk) * temp[h];
  }
  __syncthreads();
  if (tid < 48) {
    const int h = tid / 12, c = tid - h * 12;
    float* row = &attn[h * 144 + c * 12];
    float m = row[0];
    for (int d = 1; d < 12; ++d) m = fmaxf(m, row[d]);
    float s = 0.f;
    for (int d = 0; d < 12; ++d) { const float e2 = expf(row[d] - m); row[d] = e2; s += e2; }
    const float inv = 1.f / s;
    for (int d = 0; d < 12; ++d) row[d] *= inv;
  }
  __syncthreads();
  for (int e = tid; e < 2304; e += 256) {
    const int o = e / 48, j = e - o * 48;
    const int h = j / 12, d = j - h * 12;
    float s = 0.f;
    for (int c = 0; c < 12; ++c)
      s += aow[o * 48 + h * 12 + c] * attn[h * 144 + c * 12 + d];
    Mws[b * 2304 + e] = s;
  }
}

// ---------------- k4a: recompute in_proj, attn-out, LN2, ffn_in ----------------
__global__ __launch_bounds__(256, 3) void k4a(
    char* __restrict__ region, float4* __restrict__ s0arr,
    const float* __restrict__ x, const float* __restrict__ ipw,
    const float* __restrict__ ipb, const float* __restrict__ Mws,
    const float* __restrict__ aob, const float* __restrict__ lnw,
    const float* __restrict__ lnb, const float* __restrict__ fiw,
    const float* __restrict__ fib, const float* __restrict__ opw) {
  __shared__ __align__(16) float MT[48 * 48];     // MT[j][o]
  __shared__ __align__(16) float wT2[48 * 192];   // wT2[c][pos], pos interleaved
  __shared__ float s_aob[48], s_lnw[48], s_lnb[48], s_fib2[192], s_opw[144];
  __shared__ float s_ipw[144], s_ipb[48];
  const int tid = threadIdx.x;
  const int b = blockIdx.x >> 8;
  const int n = ((blockIdx.x & 255) << 8) + tid;
  for (int i = tid; i < 2304; i += 256) {
    const int o = i / 48, j = i - o * 48;
    MT[j * 48 + o] = Mws[b * 2304 + i];
  }
  for (int i = tid; i < 9216; i += 256) {
    const int c = i / 192, pos = i - c * 192;
    const int ch = (pos & 1) ? 96 + (pos >> 1) : (pos >> 1);
    wT2[i] = fiw[ch * 48 + c];
  }
  if (tid < 192) {
    const int ch = (tid & 1) ? 96 + (tid >> 1) : (tid >> 1);
    s_fib2[tid] = fib[ch];
  }
  if (tid < 144) { s_opw[tid] = opw[tid]; s_ipw[tid] = ipw[tid]; }
  if (tid < 48) {
    s_aob[tid] = aob[tid]; s_lnw[tid] = lnw[tid]; s_lnb[tid] = lnb[tid];
    s_ipb[tid] = ipb[tid];
  }
  __syncthreads();
  char* slab = region + ((size_t)b * NPIX + n) * SLABB;
  float vv[48];
  {
    const float4* v4 = (const float4*)(slab + 320);
#pragma unroll
    for (int i = 0; i < 6; ++i) {
      F4U u; u.f4 = v4[i];
#pragma unroll
      for (int j = 0; j < 4; ++j) {
        const float2 f = uh2f(u.u[j]);
        vv[8 * i + 2 * j] = f.x; vv[8 * i + 2 * j + 1] = f.y;
      }
    }
  }
  float y[48];
#pragma unroll
  for (int o = 0; o < 48; ++o) y[o] = s_aob[o];
#pragma unroll 4
  for (int j = 0; j < 48; ++j) {
    const float vj = vv[j];
    const float* mr = &MT[j * 48];
#pragma unroll
    for (int o4 = 0; o4 < 12; ++o4) {
      const float4 m = *(const float4*)&mr[o4 * 4];
      y[o4 * 4 + 0] += m.x * vj; y[o4 * 4 + 1] += m.y * vj;
      y[o4 * 4 + 2] += m.z * vj; y[o4 * 4 + 3] += m.w * vj;
    }
  }
  // recompute in_proj (xp) and add residual
  const float x0 = x[((size_t)b * 3 + 0) * NPIX + n];
  const float x1 = x[((size_t)b * 3 + 1) * NPIX + n];
  const float x2 = x[((size_t)b * 3 + 2) * NPIX + n];
  float mu = 0.f;
#pragma unroll
  for (int c = 0; c < 48; ++c) {
    y[c] += s_ipw[c * 3] * x0 + s_ipw[c * 3 + 1] * x1 + s_ipw[c * 3 + 2] * x2 + s_ipb[c];
    mu += y[c];
  }
  float s0 = 0.f, s1 = 0.f, s2 = 0.f;
#pragma unroll
  for (int c = 0; c < 48; ++c) {
    s0 += s_opw[c] * y[c]; s1 += s_opw[48 + c] * y[c]; s2 += s_opw[96 + c] * y[c];
  }
  float4 s0v; s0v.x = s0; s0v.y = s1; s0v.z = s2; s0v.w = 0.f;
  s0arr[(size_t)b * NPIX + n] = s0v;
  mu *= (1.f / 48.f);
  float var = 0.f;
#pragma unroll
  for (int c = 0; c < 48; ++c) { const float d = y[c] - mu; var += d * d; }
  const float rs2 = rsqrtf(var * (1.f / 48.f) + 1e-6f);
#pragma unroll
  for (int c = 0; c < 48; ++c) y[c] = (y[c] - mu) * rs2 * s_lnw[c] + s_lnb[c];
  float4* y4 = (float4*)slab;
#pragma unroll
  for (int ob = 0; ob < 12; ++ob) {
    const int o0 = ob * 16;
    float acc[16];
#pragma unroll
    for (int j = 0; j < 16; ++j) acc[j] = s_fib2[o0 + j];
#pragma unroll 4
    for (int c = 0; c < 48; ++c) {
      const float xv = y[c];
      const float4 w0 = *(const float4*)&wT2[c * 192 + o0];
      const float4 w1 = *(const float4*)&wT2[c * 192 + o0 + 4];
      const float4 w2 = *(const float4*)&wT2[c * 192 + o0 + 8];
      const float4 w3 = *(const float4*)&wT2[c * 192 + o0 + 12];
      acc[0] += w0.x * xv; acc[1] += w0.y * xv; acc[2] += w0.z * xv; acc[3] += w0.w * xv;
      acc[4] += w1.x * xv; acc[5] += w1.y * xv; acc[6] += w1.z * xv; acc[7] += w1.w * xv;
      acc[8] += w2.x * xv; acc[9] += w2.y * xv; acc[10] += w2.z * xv; acc[11] += w2.w * xv;
      acc[12] += w3.x * xv; acc[13] += w3.y * xv; acc[14] += w3.z * xv; acc[15] += w3.w * xv;
    }
    F4U u;
    u.u[0] = fpack(acc[0], acc[1]);   u.u[1] = fpack(acc[2], acc[3]);
    u.u[2] = fpack(acc[4], acc[5]);   u.u[3] = fpack(acc[6], acc[7]);
    y4[ob * 2] = u.f4;
    u.u[0] = fpack(acc[8], acc[9]);   u.u[1] = fpack(acc[10], acc[11]);
    u.u[2] = fpack(acc[12], acc[13]); u.u[3] = fpack(acc[14], acc[15]);
    y4[ob * 2 + 1] = u.f4;
  }
}

// ---------------- k5b: 8-stage dwconv + SimpleGate + ffn_out + out_proj ----------------
__global__ __launch_bounds__(256, 3) void k5b(
    const char* __restrict__ region, const float4* __restrict__ s0arr,
    const float* __restrict__ fdww, const float* __restrict__ fdwb,
    const float* __restrict__ fow, const float* __restrict__ fob,
    const float* __restrict__ opw, const float* __restrict__ opb,
    float* __restrict__ out) {
  __shared__ unsigned int halo[12 * HSTRIDE];
  __shared__ __align__(16) float fowT[96 * 48];   // fowT[c1][o] = fow[o][c1]
  __shared__ float s_dww2[1728], s_dwb2[192], s_opw[144], s_fob[48];
  const int tid = threadIdx.x;
  for (int i = tid; i < 4608; i += 256) {
    const int c = i / 48, o = i - c * 48;
    fowT[i] = fow[o * 96 + c];
  }
  for (int i = tid; i < 1728; i += 256) {
    const int P = i / 9, t = i - P * 9;
    const int ch = (P & 1) ? 96 + (P >> 1) : (P >> 1);
    s_dww2[i] = fdww[ch * 9 + t];
  }
  if (tid < 192) {
    const int ch = (tid & 1) ? 96 + (tid >> 1) : (tid >> 1);
    s_dwb2[tid] = fdwb[ch];
  }
  if (tid < 144) s_opw[tid] = opw[tid];
  if (tid < 48) s_fob[tid] = fob[tid];
  const int b = blockIdx.x >> 8;
  const int tile = blockIdx.x & 255;
  const int ty0 = (tile >> 4) << 4, tx0 = (tile & 15) << 4;
  const int py = tid >> 4, px = tid & 15;
  const int hp = (py + 1) * 18 + (px + 1);
  const int gn = ((ty0 + py) << 8) + (tx0 + px);
  const char* regb = region + (size_t)b * NPIX * SLABB;

  float4 pf[4];
  auto prefetch = [&](int boff) {
#pragma unroll
    for (int r = 0; r < 4; ++r) {
      const int i = tid + (r << 8);
      float4 z = {0.f, 0.f, 0.f, 0.f}; pf[r] = z;
      if (i < 972) {
        const int p = i / 3, c4 = i - p * 3;
        const int hy = p / 18, hx = p - hy * 18;
        const int gy = ty0 + hy - 1, gx = tx0 + hx - 1;
        if (((unsigned)gy < 256u) && ((unsigned)gx < 256u))
          pf[r] = *(const float4*)(regb + (size_t)((gy << 8) + gx) * SLABB + boff + (c4 << 4));
      }
    }
  };
  auto commit = [&]() {
#pragma unroll
    for (int r = 0; r < 4; ++r) {
      const int i = tid + (r << 8);
      if (i < 972) {
        const int p = i / 3, c4 = i - p * 3;
        F4U u; u.f4 = pf[r];
        const int pb = c4 << 2;
#pragma unroll
        for (int j = 0; j < 4; ++j) halo[(pb + j) * HSTRIDE + p] = u.u[j];
      }
    }
  };

  float facc[48];
#pragma unroll
  for (int o = 0; o < 48; ++o) facc[o] = 0.f;
  prefetch(0);
  for (int s = 0; s < 8; ++s) {
    __syncthreads(); commit(); __syncthreads();
    if (s < 7) prefetch(48 * (s + 1));
    const int offs[9] = {-19, -18, -17, -1, 0, 1, 17, 18, 19};
#pragma unroll
    for (int pp = 0; pp < 12; ++pp) {
      const int P = 24 * s + 2 * pp;
      const float* w0 = &s_dww2[P * 9];
      const float* w1 = w0 + 9;
      const unsigned int* hrow = &halo[pp * HSTRIDE + hp];
      float a = s_dwb2[P], b2 = s_dwb2[P + 1];
#pragma unroll
      for (int t = 0; t < 9; ++t) {
        const float2 f = uh2f(hrow[offs[t]]);
        a += w0[t] * f.x; b2 += w1[t] * f.y;
      }
      const float gate = a * b2;
      const float* fr = &fowT[(12 * s + pp) * 48];
#pragma unroll
      for (int o4 = 0; o4 < 12; ++o4) {
        const float4 m = *(const float4*)&fr[o4 * 4];
        facc[o4 * 4 + 0] += m.x * gate; facc[o4 * 4 + 1] += m.y * gate;
        facc[o4 * 4 + 2] += m.z * gate; facc[o4 * 4 + 3] += m.w * gate;
      }
    }
  }
  const float4 s0v = s0arr[(size_t)b * NPIX + gn];
  float r0 = s0v.x + opb[0];
  float r1 = s0v.y + opb[1];
  float r2 = s0v.z + opb[2];
#pragma unroll
  for (int o = 0; o < 48; ++o) {
    const float f = facc[o] + s_fob[o];
    r0 += s_opw[o] * f; r1 += s_opw[48 + o] * f; r2 += s_opw[96 + o] * f;
  }
  out[((size_t)b * 3 + 0) * NPIX + gn] = r0;
  out[((size_t)b * 3 + 1) * NPIX + gn] = r1;
  out[((size_t)b * 3 + 2) * NPIX + gn] = r2;
}

extern "C" void kernel_launch(void* const* d_in, const int* in_sizes, int n_in,
                              void* d_out, int out_size, void* d_ws, size_t ws_size,
                              hipStream_t stream) {
  const float* x    = (const float*)d_in[0];
  const float* ipw  = (const float*)d_in[1];
  const float* ipb  = (const float*)d_in[2];
  const float* ln1w = (const float*)d_in[3];
  const float* ln1b = (const float*)d_in[4];
  const float* qw   = (const float*)d_in[5];
  const float* qb   = (const float*)d_in[6];
  const float* qdww = (const float*)d_in[7];
  const float* qdwb = (const float*)d_in[8];
  const float* temp = (const float*)d_in[9];
  const float* aow  = (const float*)d_in[10];
  const float* aob  = (const float*)d_in[11];
  const float* ln2w = (const float*)d_in[12];
  const float* ln2b = (const float*)d_in[13];
  const float* fiw  = (const float*)d_in[14];
  const float* fib  = (const float*)d_in[15];
  const float* fdww = (const float*)d_in[16];
  const float* fdwb = (const float*)d_in[17];
  const float* fow  = (const float*)d_in[18];
  const float* fob  = (const float*)d_in[19];
  const float* opw  = (const float*)d_in[20];
  const float* opb  = (const float*)d_in[21];

  const size_t slabPer = (size_t)NPIX * SLABB;   // bytes per batch (slabs)
  const size_t s0Per = (size_t)NPIX * 16;        // bytes per batch (s0)
  int bc = 8;
  while (bc > 1 &&
         (size_t)bc * (slabPer + s0Per) + (5376 + 18432) * 4 > ws_size)
    bc >>= 1;
  char* region = (char*)d_ws;
  float4* s0arr = (float4*)(region + (size_t)bc * slabPer);
  float* red = (float*)((char*)s0arr + (size_t)bc * s0Per);
  float* Mws = red + 5376;
  hipMemsetAsync(red, 0, 5376 * sizeof(float), stream);
  for (int b0 = 0; b0 < 8; b0 += bc) {
    k2a<<<bc * 256, 256, 0, stream>>>(x + (size_t)b0 * 3 * NPIX, ipw, ipb,
                                      ln1w, ln1b, qw, qb, region);
    k2b<<<bc * 256, 256, 0, stream>>>(region, qdww, qdwb, red + b0 * 672);
    k3_attn<<<bc, 256, 0, stream>>>(red + b0 * 672, temp, aow,
                                    Mws + (size_t)b0 * 2304);
    k4a<<<bc * 256, 256, 0, stream>>>(region, s0arr, x + (size_t)b0 * 3 * NPIX,
                                      ipw, ipb, Mws + (size_t)b0 * 2304, aob,
                                      ln2w, ln2b, fiw, fib, opw);
    k5b<<<bc * 256, 256, 0, stream>>>(region, s0arr, fdww, fdwb, fow, fob,
                                      opw, opb,
                                      (float*)d_out + (size_t)b0 * 3 * NPIX);
  }
}

// Round 7
// 1153.768 us; speedup vs baseline: 2.3279x; 1.1185x over previous
//
#include <hip/hip_runtime.h>
#include <hip/hip_fp16.h>

// CAPTNet block. B=8, CIN=3, H=W=256, DIM=48, HEADS=4 (ch=12), HID=96.
// Round 7: chunk-interleaved fp16 layout for full write/read coalescing.
// Per image row (gy) and batch b: 24 chunk-planes of 4096 B; pixel gx owns
// 16 B at chunk*4096 + gx*16. Chunk c holds fp16 positions 8c..8c+7.
//   chunks 0..17  : qkv 144 fp16 (k2a -> k2b), overwritten by y 192 fp16
//                   (k4a -> k5b, chunks 0..23)
//   chunks 18..23 : vdw 48 fp16 (k2b -> k4a; k4a reads then overwrites)
// s0 (3 fp32) in separate float4/pixel array (k4a -> k5b).
// addr(b,gy,c,gx) = region + (b*256+gy)*98304 + c*4096 + gx*16
// Pipeline: k2a (pixel: in_proj+LN1+qkv conv) -> k2b (tile: dwconv q,k,v +
// Gram/norm atomics + vdw) -> k3 (attn finalize, fold attn_out_w -> M) ->
// k4a (pixel: recompute in_proj, += M@vdw, s0, LN2, ffn_in conv -> y) ->
// k5b (tile: dwconv pairs + SimpleGate + ffn_out + out_proj).

#define NPIX 65536
#define ROWB 98304        // bytes per (batch,row): 24 chunks * 4096
#define REGPB 25165824ull // bytes per batch in region: 256 rows * ROWB
#define HSTRIDE 332       // halo LDS row stride (half2 elems)
#define QSTRIDE 258       // qs/ks LDS row stride (half2 elems)

union F4U { float4 f4; unsigned int u[4]; };

__device__ __forceinline__ float2 uh2f(unsigned int u) {
  __half2 h; *(unsigned int*)&h = u; return __half22float2(h);
}
__device__ __forceinline__ unsigned int fpack(float a, float b) {
  __half2 h = __halves2half2(__float2half_rn(a), __float2half_rn(b));
  return *(unsigned int*)&h;
}

// ---------------- k2a: in_proj + LN1 + qkv conv1x1 -> qkv fp16 ----------------
__global__ __launch_bounds__(256, 4) void k2a(
    const float* __restrict__ x, const float* __restrict__ ipw,
    const float* __restrict__ ipb, const float* __restrict__ lnw,
    const float* __restrict__ lnb, const float* __restrict__ qw,
    const float* __restrict__ qb, char* __restrict__ region) {
  __shared__ __align__(16) float wT[48 * 144];   // wT[c][o] = qw[o][c]
  __shared__ float s_ipw[144], s_ipb[48], s_lnw[48], s_lnb[48], s_qb[144];
  const int tid = threadIdx.x;
  for (int i = tid; i < 6912; i += 256) {
    const int c = i / 144, o = i - c * 144;
    wT[i] = qw[o * 48 + c];
  }
  if (tid < 144) { s_ipw[tid] = ipw[tid]; s_qb[tid] = qb[tid]; }
  if (tid < 48) { s_ipb[tid] = ipb[tid]; s_lnw[tid] = lnw[tid]; s_lnb[tid] = lnb[tid]; }
  __syncthreads();
  const int b = blockIdx.x >> 8;
  const int gy = blockIdx.x & 255;
  const int n = (gy << 8) + tid;
  const float x0 = x[((size_t)b * 3 + 0) * NPIX + n];
  const float x1 = x[((size_t)b * 3 + 1) * NPIX + n];
  const float x2 = x[((size_t)b * 3 + 2) * NPIX + n];
  char* rowp = region + (size_t)((b << 8) + gy) * ROWB + (tid << 4);
  float xn[48];
  float mu = 0.f;
#pragma unroll
  for (int c = 0; c < 48; ++c) {
    xn[c] = s_ipw[c * 3] * x0 + s_ipw[c * 3 + 1] * x1 + s_ipw[c * 3 + 2] * x2 + s_ipb[c];
    mu += xn[c];
  }
  mu *= (1.f / 48.f);
  float var = 0.f;
#pragma unroll
  for (int c = 0; c < 48; ++c) { const float d = xn[c] - mu; var += d * d; }
  const float rs = rsqrtf(var * (1.f / 48.f) + 1e-6f);
#pragma unroll
  for (int c = 0; c < 48; ++c) xn[c] = (xn[c] - mu) * rs * s_lnw[c] + s_lnb[c];
#pragma unroll
  for (int ob = 0; ob < 9; ++ob) {
    const int o0 = ob * 16;
    float acc[16];
#pragma unroll
    for (int j = 0; j < 16; ++j) acc[j] = s_qb[o0 + j];
#pragma unroll 4
    for (int c = 0; c < 48; ++c) {
      const float xv = xn[c];
      const float4 w0 = *(const float4*)&wT[c * 144 + o0];
      const float4 w1 = *(const float4*)&wT[c * 144 + o0 + 4];
      const float4 w2 = *(const float4*)&wT[c * 144 + o0 + 8];
      const float4 w3 = *(const float4*)&wT[c * 144 + o0 + 12];
      acc[0] += w0.x * xv; acc[1] += w0.y * xv; acc[2] += w0.z * xv; acc[3] += w0.w * xv;
      acc[4] += w1.x * xv; acc[5] += w1.y * xv; acc[6] += w1.z * xv; acc[7] += w1.w * xv;
      acc[8] += w2.x * xv; acc[9] += w2.y * xv; acc[10] += w2.z * xv; acc[11] += w2.w * xv;
      acc[12] += w3.x * xv; acc[13] += w3.y * xv; acc[14] += w3.z * xv; acc[15] += w3.w * xv;
    }
    F4U u;
    u.u[0] = fpack(acc[0], acc[1]);   u.u[1] = fpack(acc[2], acc[3]);
    u.u[2] = fpack(acc[4], acc[5]);   u.u[3] = fpack(acc[6], acc[7]);
    *(float4*)(rowp + (2 * ob) * 4096) = u.f4;
    u.u[0] = fpack(acc[8], acc[9]);   u.u[1] = fpack(acc[10], acc[11]);
    u.u[2] = fpack(acc[12], acc[13]); u.u[3] = fpack(acc[14], acc[15]);
    *(float4*)(rowp + (2 * ob + 1) * 4096) = u.f4;
  }
}

// ---------------- k2b: 6-stage dwconv + Gram + vdw ----------------
__global__ __launch_bounds__(256, 3) void k2b(
    char* __restrict__ region, const float* __restrict__ dww,
    const float* __restrict__ dwb, float* __restrict__ red) {
  __shared__ unsigned int halo[12 * HSTRIDE];
  __shared__ unsigned int qsm[12 * QSTRIDE];
  __shared__ unsigned int ksm[12 * QSTRIDE];
  __shared__ float s_dww[1296], s_dwb[144];
  const int tid = threadIdx.x;
  for (int i = tid; i < 1296; i += 256) s_dww[i] = dww[i];
  if (tid < 144) s_dwb[tid] = dwb[tid];
  const int b = blockIdx.x >> 8;
  const int tile = blockIdx.x & 255;
  const int ty0 = (tile >> 4) << 4, tx0 = (tile & 15) << 4;
  const int py = tid >> 4, px = tid & 15;
  const int hp = (py + 1) * 18 + (px + 1);
  char* regb = region + (size_t)b * REGPB;

  float4 pf[4];
  auto prefetch = [&](int cb) {   // cb = chunk base (3 chunks per stage)
#pragma unroll
    for (int r = 0; r < 4; ++r) {
      const int i = tid + (r << 8);
      float4 z = {0.f, 0.f, 0.f, 0.f}; pf[r] = z;
      if (i < 972) {
        const int c4 = i / 324, p = i - c4 * 324;
        const int hy = p / 18, hx = p - hy * 18;
        const int gy = ty0 + hy - 1, gx = tx0 + hx - 1;
        if (((unsigned)gy < 256u) && ((unsigned)gx < 256u))
          pf[r] = *(const float4*)(regb + (size_t)gy * ROWB + (cb + c4) * 4096 + (gx << 4));
      }
    }
  };
  auto commit = [&]() {
#pragma unroll
    for (int r = 0; r < 4; ++r) {
      const int i = tid + (r << 8);
      if (i < 972) {
        const int c4 = i / 324, p = i - c4 * 324;
        F4U u; u.f4 = pf[r];
        const int pb = c4 << 2;
#pragma unroll
        for (int j = 0; j < 4; ++j) halo[(pb + j) * HSTRIDE + p] = u.u[j];
      }
    }
  };
  auto dwconv24 = [&](int cb, unsigned int* dst) {
    const int offs[9] = {-19, -18, -17, -1, 0, 1, 17, 18, 19};
#pragma unroll
    for (int pp = 0; pp < 12; ++pp) {
      const float* w0 = &s_dww[(cb + 2 * pp) * 9];
      const float* w1 = w0 + 9;
      const unsigned int* hrow = &halo[pp * HSTRIDE + hp];
      float a = s_dwb[cb + 2 * pp], b2 = s_dwb[cb + 2 * pp + 1];
#pragma unroll
      for (int t = 0; t < 9; ++t) {
        const float2 f = uh2f(hrow[offs[t]]);
        a += w0[t] * f.x; b2 += w1[t] * f.y;
      }
      dst[pp * QSTRIDE + tid] = fpack(a, b2);
    }
  };
  auto gram2 = [&](int hbase) {
    for (int e = tid; e < 336; e += 256) {
      const int hh = e / 168, r = e - hh * 168;
      float s = 0.f;
      if (r < 144) {
        const int c = r / 12, d = r - (r / 12) * 12;
        const int qc = 12 * hh + c, kd = 12 * hh + d;
        const unsigned int* qr = &qsm[(qc >> 1) * QSTRIDE];
        const unsigned int* kr = &ksm[(kd >> 1) * QSTRIDE];
        const int q1 = qc & 1, k1 = kd & 1;
        for (int p = 0; p < 256; ++p) {
          const float2 fq = uh2f(qr[p]); const float2 fk = uh2f(kr[p]);
          s += (q1 ? fq.y : fq.x) * (k1 ? fk.y : fk.x);
        }
      } else if (r < 156) {
        const int qc = 12 * hh + (r - 144);
        const unsigned int* qr = &qsm[(qc >> 1) * QSTRIDE];
        const int q1 = qc & 1;
        for (int p = 0; p < 256; ++p) {
          const float2 fq = uh2f(qr[p]);
          const float v = q1 ? fq.y : fq.x;
          s += v * v;
        }
      } else {
        const int kd = 12 * hh + (r - 156);
        const unsigned int* kr = &ksm[(kd >> 1) * QSTRIDE];
        const int k1 = kd & 1;
        for (int p = 0; p < 256; ++p) {
          const float2 fk = uh2f(kr[p]);
          const float v = k1 ? fk.y : fk.x;
          s += v * v;
        }
      }
      atomicAdd(&red[b * 672 + (hbase + hh) * 168 + r], s);
    }
  };

  prefetch(0);                                   // q ch 0-23
  __syncthreads(); commit(); __syncthreads();
  prefetch(6);  dwconv24(0, qsm);                // next: k ch 0-23
  __syncthreads(); commit(); __syncthreads();
  prefetch(3);  dwconv24(48, ksm);               // next: q ch 24-47
  __syncthreads(); commit(); gram2(0); __syncthreads();
  prefetch(9);  dwconv24(24, qsm);               // next: k ch 24-47
  __syncthreads(); commit(); __syncthreads();
  prefetch(12); dwconv24(72, ksm);               // next: v ch 0-23
  __syncthreads(); commit(); gram2(2); __syncthreads();
  prefetch(15);                                  // v ch 24-47
  unsigned int vp[24];
  {
    const int offs[9] = {-19, -18, -17, -1, 0, 1, 17, 18, 19};
#pragma unroll
    for (int pp = 0; pp < 12; ++pp) {
      const float* w0 = &s_dww[(96 + 2 * pp) * 9];
      const float* w1 = w0 + 9;
      const unsigned int* hrow = &halo[pp * HSTRIDE + hp];
      float a = s_dwb[96 + 2 * pp], b2 = s_dwb[96 + 2 * pp + 1];
#pragma unroll
      for (int t = 0; t < 9; ++t) {
        const float2 f = uh2f(hrow[offs[t]]);
        a += w0[t] * f.x; b2 += w1[t] * f.y;
      }
      vp[pp] = fpack(a, b2);
    }
  }
  __syncthreads(); commit(); __syncthreads();
  {
    const int offs[9] = {-19, -18, -17, -1, 0, 1, 17, 18, 19};
#pragma unroll
    for (int pp = 0; pp < 12; ++pp) {
      const float* w0 = &s_dww[(120 + 2 * pp) * 9];
      const float* w1 = w0 + 9;
      const unsigned int* hrow = &halo[pp * HSTRIDE + hp];
      float a = s_dwb[120 + 2 * pp], b2 = s_dwb[120 + 2 * pp + 1];
#pragma unroll
      for (int t = 0; t < 9; ++t) {
        const float2 f = uh2f(hrow[offs[t]]);
        a += w0[t] * f.x; b2 += w1[t] * f.y;
      }
      vp[12 + pp] = fpack(a, b2);
    }
  }
  char* rowp = regb + (size_t)(ty0 + py) * ROWB + ((tx0 + px) << 4);
#pragma unroll
  for (int q = 0; q < 6; ++q) {
    F4U u;
    u.u[0] = vp[4 * q]; u.u[1] = vp[4 * q + 1];
    u.u[2] = vp[4 * q + 2]; u.u[3] = vp[4 * q + 3];
    *(float4*)(rowp + (18 + q) * 4096) = u.f4;
  }
}

// ---------------- k3: finalize attn, build fused M ----------------
__global__ __launch_bounds__(256) void k3_attn(const float* __restrict__ red,
                                               const float* __restrict__ temp,
                                               const float* __restrict__ aow,
                                               float* __restrict__ Mws) {
  __shared__ float attn[4 * 144];
  const int b = blockIdx.x, tid = threadIdx.x;
  const float* rb = red + b * 672;
  for (int e = tid; e < 576; e += 256) {
    const int h = e / 144, r = e - h * 144;
    const int c = r / 12, d = r - c * 12;
    const float g = rb[h * 168 + r];
    const float nq = fmaxf(sqrtf(rb[h * 168 + 144 + c]), 1e-12f);
    const float nk = fmaxf(sqrtf(rb[h * 168 + 156 + d]), 1e-12f);
    attn[e] = g / (nq * nk) * temp[h];
  }
  __syncthreads();
  if (tid < 48) {
    const int h = tid / 12, c = tid - h * 12;
    float* row = &attn[h * 144 + c * 12];
    float m = row[0];
    for (int d = 1; d < 12; ++d) m = fmaxf(m, row[d]);
    float s = 0.f;
    for (int d = 0; d < 12; ++d) { const float e2 = expf(row[d] - m); row[d] = e2; s += e2; }
    const float inv = 1.f / s;
    for (int d = 0; d < 12; ++d) row[d] *= inv;
  }
  __syncthreads();
  for (int e = tid; e < 2304; e += 256) {
    const int o = e / 48, j = e - o * 48;
    const int h = j / 12, d = j - h * 12;
    float s = 0.f;
    for (int c = 0; c < 12; ++c)
      s += aow[o * 48 + h * 12 + c] * attn[h * 144 + c * 12 + d];
    Mws[b * 2304 + e] = s;
  }
}

// ---------------- k4a: recompute in_proj, attn-out, LN2, ffn_in ----------------
__global__ __launch_bounds__(256, 3) void k4a(
    char* __restrict__ region, float4* __restrict__ s0arr,
    const float* __restrict__ x, const float* __restrict__ ipw,
    const float* __restrict__ ipb, const float* __restrict__ Mws,
    const float* __restrict__ aob, const float* __restrict__ lnw,
    const float* __restrict__ lnb, const float* __restrict__ fiw,
    const float* __restrict__ fib, const float* __restrict__ opw) {
  __shared__ __align__(16) float MT[48 * 48];     // MT[j][o]
  __shared__ __align__(16) float wT2[48 * 192];   // wT2[c][pos], pos interleaved
  __shared__ float s_aob[48], s_lnw[48], s_lnb[48], s_fib2[192], s_opw[144];
  __shared__ float s_ipw[144], s_ipb[48];
  const int tid = threadIdx.x;
  const int b = blockIdx.x >> 8;
  const int gy = blockIdx.x & 255;
  const int n = (gy << 8) + tid;
  for (int i = tid; i < 2304; i += 256) {
    const int o = i / 48, j = i - o * 48;
    MT[j * 48 + o] = Mws[b * 2304 + i];
  }
  for (int i = tid; i < 9216; i += 256) {
    const int c = i / 192, pos = i - c * 192;
    const int ch = (pos & 1) ? 96 + (pos >> 1) : (pos >> 1);
    wT2[i] = fiw[ch * 48 + c];
  }
  if (tid < 192) {
    const int ch = (tid & 1) ? 96 + (tid >> 1) : (tid >> 1);
    s_fib2[tid] = fib[ch];
  }
  if (tid < 144) { s_opw[tid] = opw[tid]; s_ipw[tid] = ipw[tid]; }
  if (tid < 48) {
    s_aob[tid] = aob[tid]; s_lnw[tid] = lnw[tid]; s_lnb[tid] = lnb[tid];
    s_ipb[tid] = ipb[tid];
  }
  __syncthreads();
  char* rowp = region + (size_t)((b << 8) + gy) * ROWB + (tid << 4);
  float vv[48];
#pragma unroll
  for (int q = 0; q < 6; ++q) {
    F4U u; u.f4 = *(const float4*)(rowp + (18 + q) * 4096);
#pragma unroll
    for (int j = 0; j < 4; ++j) {
      const float2 f = uh2f(u.u[j]);
      vv[8 * q + 2 * j] = f.x; vv[8 * q + 2 * j + 1] = f.y;
    }
  }
  float y[48];
#pragma unroll
  for (int o = 0; o < 48; ++o) y[o] = s_aob[o];
#pragma unroll 4
  for (int j = 0; j < 48; ++j) {
    const float vj = vv[j];
    const float* mr = &MT[j * 48];
#pragma unroll
    for (int o4 = 0; o4 < 12; ++o4) {
      const float4 m = *(const float4*)&mr[o4 * 4];
      y[o4 * 4 + 0] += m.x * vj; y[o4 * 4 + 1] += m.y * vj;
      y[o4 * 4 + 2] += m.z * vj; y[o4 * 4 + 3] += m.w * vj;
    }
  }
  // recompute in_proj (xp) and add residual
  const float x0 = x[((size_t)b * 3 + 0) * NPIX + n];
  const float x1 = x[((size_t)b * 3 + 1) * NPIX + n];
  const float x2 = x[((size_t)b * 3 + 2) * NPIX + n];
  float mu = 0.f;
#pragma unroll
  for (int c = 0; c < 48; ++c) {
    y[c] += s_ipw[c * 3] * x0 + s_ipw[c * 3 + 1] * x1 + s_ipw[c * 3 + 2] * x2 + s_ipb[c];
    mu += y[c];
  }
  float s0 = 0.f, s1 = 0.f, s2 = 0.f;
#pragma unroll
  for (int c = 0; c < 48; ++c) {
    s0 += s_opw[c] * y[c]; s1 += s_opw[48 + c] * y[c]; s2 += s_opw[96 + c] * y[c];
  }
  float4 s0v; s0v.x = s0; s0v.y = s1; s0v.z = s2; s0v.w = 0.f;
  s0arr[(size_t)b * NPIX + n] = s0v;
  mu *= (1.f / 48.f);
  float var = 0.f;
#pragma unroll
  for (int c = 0; c < 48; ++c) { const float d = y[c] - mu; var += d * d; }
  const float rs2 = rsqrtf(var * (1.f / 48.f) + 1e-6f);
#pragma unroll
  for (int c = 0; c < 48; ++c) y[c] = (y[c] - mu) * rs2 * s_lnw[c] + s_lnb[c];
#pragma unroll
  for (int ob = 0; ob < 12; ++ob) {
    const int o0 = ob * 16;
    float acc[16];
#pragma unroll
    for (int j = 0; j < 16; ++j) acc[j] = s_fib2[o0 + j];
#pragma unroll 4
    for (int c = 0; c < 48; ++c) {
      const float xv = y[c];
      const float4 w0 = *(const float4*)&wT2[c * 192 + o0];
      const float4 w1 = *(const float4*)&wT2[c * 192 + o0 + 4];
      const float4 w2 = *(const float4*)&wT2[c * 192 + o0 + 8];
      const float4 w3 = *(const float4*)&wT2[c * 192 + o0 + 12];
      acc[0] += w0.x * xv; acc[1] += w0.y * xv; acc[2] += w0.z * xv; acc[3] += w0.w * xv;
      acc[4] += w1.x * xv; acc[5] += w1.y * xv; acc[6] += w1.z * xv; acc[7] += w1.w * xv;
      acc[8] += w2.x * xv; acc[9] += w2.y * xv; acc[10] += w2.z * xv; acc[11] += w2.w * xv;
      acc[12] += w3.x * xv; acc[13] += w3.y * xv; acc[14] += w3.z * xv; acc[15] += w3.w * xv;
    }
    F4U u;
    u.u[0] = fpack(acc[0], acc[1]);   u.u[1] = fpack(acc[2], acc[3]);
    u.u[2] = fpack(acc[4], acc[5]);   u.u[3] = fpack(acc[6], acc[7]);
    *(float4*)(rowp + (2 * ob) * 4096) = u.f4;
    u.u[0] = fpack(acc[8], acc[9]);   u.u[1] = fpack(acc[10], acc[11]);
    u.u[2] = fpack(acc[12], acc[13]); u.u[3] = fpack(acc[14], acc[15]);
    *(float4*)(rowp + (2 * ob + 1) * 4096) = u.f4;
  }
}

// ---------------- k5b: 8-stage dwconv + SimpleGate + ffn_out + out_proj ----------------
__global__ __launch_bounds__(256, 3) void k5b(
    const char* __restrict__ region, const float4* __restrict__ s0arr,
    const float* __restrict__ fdww, const float* __restrict__ fdwb,
    const float* __restrict__ fow, const float* __restrict__ fob,
    const float* __restrict__ opw, const float* __restrict__ opb,
    float* __restrict__ out) {
  __shared__ unsigned int halo[12 * HSTRIDE];
  __shared__ __align__(16) float fowT[96 * 48];   // fowT[c1][o] = fow[o][c1]
  __shared__ float s_dww2[1728], s_dwb2[192], s_opw[144], s_fob[48];
  const int tid = threadIdx.x;
  for (int i = tid; i < 4608; i += 256) {
    const int c = i / 48, o = i - c * 48;
    fowT[i] = fow[o * 96 + c];
  }
  for (int i = tid; i < 1728; i += 256) {
    const int P = i / 9, t = i - P * 9;
    const int ch = (P & 1) ? 96 + (P >> 1) : (P >> 1);
    s_dww2[i] = fdww[ch * 9 + t];
  }
  if (tid < 192) {
    const int ch = (tid & 1) ? 96 + (tid >> 1) : (tid >> 1);
    s_dwb2[tid] = fdwb[ch];
  }
  if (tid < 144) s_opw[tid] = opw[tid];
  if (tid < 48) s_fob[tid] = fob[tid];
  const int b = blockIdx.x >> 8;
  const int tile = blockIdx.x & 255;
  const int ty0 = (tile >> 4) << 4, tx0 = (tile & 15) << 4;
  const int py = tid >> 4, px = tid & 15;
  const int hp = (py + 1) * 18 + (px + 1);
  const int gn = ((ty0 + py) << 8) + (tx0 + px);
  const char* regb = region + (size_t)b * REGPB;

  float4 pf[4];
  auto prefetch = [&](int cb) {
#pragma unroll
    for (int r = 0; r < 4; ++r) {
      const int i = tid + (r << 8);
      float4 z = {0.f, 0.f, 0.f, 0.f}; pf[r] = z;
      if (i < 972) {
        const int c4 = i / 324, p = i - c4 * 324;
        const int hy = p / 18, hx = p - hy * 18;
        const int gy = ty0 + hy - 1, gx = tx0 + hx - 1;
        if (((unsigned)gy < 256u) && ((unsigned)gx < 256u))
          pf[r] = *(const float4*)(regb + (size_t)gy * ROWB + (cb + c4) * 4096 + (gx << 4));
      }
    }
  };
  auto commit = [&]() {
#pragma unroll
    for (int r = 0; r < 4; ++r) {
      const int i = tid + (r << 8);
      if (i < 972) {
        const int c4 = i / 324, p = i - c4 * 324;
        F4U u; u.f4 = pf[r];
        const int pb = c4 << 2;
#pragma unroll
        for (int j = 0; j < 4; ++j) halo[(pb + j) * HSTRIDE + p] = u.u[j];
      }
    }
  };

  float facc[48];
#pragma unroll
  for (int o = 0; o < 48; ++o) facc[o] = 0.f;
  prefetch(0);
  for (int s = 0; s < 8; ++s) {
    __syncthreads(); commit(); __syncthreads();
    if (s < 7) prefetch(3 * (s + 1));
    const int offs[9] = {-19, -18, -17, -1, 0, 1, 17, 18, 19};
#pragma unroll
    for (int pp = 0; pp < 12; ++pp) {
      const int P = 24 * s + 2 * pp;
      const float* w0 = &s_dww2[P * 9];
      const float* w1 = w0 + 9;
      const unsigned int* hrow = &halo[pp * HSTRIDE + hp];
      float a = s_dwb2[P], b2 = s_dwb2[P + 1];
#pragma unroll
      for (int t = 0; t < 9; ++t) {
        const float2 f = uh2f(hrow[offs[t]]);
        a += w0[t] * f.x; b2 += w1[t] * f.y;
      }
      const float gate = a * b2;
      const float* fr = &fowT[(12 * s + pp) * 48];
#pragma unroll
      for (int o4 = 0; o4 < 12; ++o4) {
        const float4 m = *(const float4*)&fr[o4 * 4];
        facc[o4 * 4 + 0] += m.x * gate; facc[o4 * 4 + 1] += m.y * gate;
        facc[o4 * 4 + 2] += m.z * gate; facc[o4 * 4 + 3] += m.w * gate;
      }
    }
  }
  const float4 s0v = s0arr[(size_t)b * NPIX + gn];
  float r0 = s0v.x + opb[0];
  float r1 = s0v.y + opb[1];
  float r2 = s0v.z + opb[2];
#pragma unroll
  for (int o = 0; o < 48; ++o) {
    const float f = facc[o] + s_fob[o];
    r0 += s_opw[o] * f; r1 += s_opw[48 + o] * f; r2 += s_opw[96 + o] * f;
  }
  out[((size_t)b * 3 + 0) * NPIX + gn] = r0;
  out[((size_t)b * 3 + 1) * NPIX + gn] = r1;
  out[((size_t)b * 3 + 2) * NPIX + gn] = r2;
}

extern "C" void kernel_launch(void* const* d_in, const int* in_sizes, int n_in,
                              void* d_out, int out_size, void* d_ws, size_t ws_size,
                              hipStream_t stream) {
  const float* x    = (const float*)d_in[0];
  const float* ipw  = (const float*)d_in[1];
  const float* ipb  = (const float*)d_in[2];
  const float* ln1w = (const float*)d_in[3];
  const float* ln1b = (const float*)d_in[4];
  const float* qw   = (const float*)d_in[5];
  const float* qb   = (const float*)d_in[6];
  const float* qdww = (const float*)d_in[7];
  const float* qdwb = (const float*)d_in[8];
  const float* temp = (const float*)d_in[9];
  const float* aow  = (const float*)d_in[10];
  const float* aob  = (const float*)d_in[11];
  const float* ln2w = (const float*)d_in[12];
  const float* ln2b = (const float*)d_in[13];
  const float* fiw  = (const float*)d_in[14];
  const float* fib  = (const float*)d_in[15];
  const float* fdww = (const float*)d_in[16];
  const float* fdwb = (const float*)d_in[17];
  const float* fow  = (const float*)d_in[18];
  const float* fob  = (const float*)d_in[19];
  const float* opw  = (const float*)d_in[20];
  const float* opb  = (const float*)d_in[21];

  const size_t s0Per = (size_t)NPIX * 16;
  int bc = 8;
  while (bc > 1 &&
         (size_t)bc * (REGPB + s0Per) + (5376 + 18432) * 4 > ws_size)
    bc >>= 1;
  char* region = (char*)d_ws;
  float4* s0arr = (float4*)(region + (size_t)bc * REGPB);
  float* red = (float*)((char*)s0arr + (size_t)bc * s0Per);
  float* Mws = red + 5376;
  hipMemsetAsync(red, 0, 5376 * sizeof(float), stream);
  for (int b0 = 0; b0 < 8; b0 += bc) {
    k2a<<<bc * 256, 256, 0, stream>>>(x + (size_t)b0 * 3 * NPIX, ipw, ipb,
                                      ln1w, ln1b, qw, qb, region);
    k2b<<<bc * 256, 256, 0, stream>>>(region, qdww, qdwb, red + b0 * 672);
    k3_attn<<<bc, 256, 0, stream>>>(red + b0 * 672, temp, aow,
                                    Mws + (size_t)b0 * 2304);
    k4a<<<bc * 256, 256, 0, stream>>>(region, s0arr, x + (size_t)b0 * 3 * NPIX,
                                      ipw, ipb, Mws + (size_t)b0 * 2304, aob,
                                      ln2w, ln2b, fiw, fib, opw);
    k5b<<<bc * 256, 256, 0, stream>>>(region, s0arr, fdww, fdwb, fow, fob,
                                      opw, opb,
                                      (float*)d_out + (size_t)b0 * 3 * NPIX);
  }
}

// Round 10
// 1105.196 us; speedup vs baseline: 2.4303x; 1.0439x over previous
//
#include <hip/hip_runtime.h>
#include <hip/hip_fp16.h>

// CAPTNet block. B=8, CIN=3, H=W=256, DIM=48, HEADS=4 (ch=12), HID=96.
// Round 10: round-7 passing pipeline with ONLY the first half fused.
//  kA2 (tile 16x16): per halo px recompute in_proj+LN1 in fp32 regs; 6x
//     [qkv conv 48->24 fp32 -> um fp16 LDS -> dwconv fp32-weights]; q,k kept
//     FP32 in LDS -> Gram/norm atomics; v -> region chunks 18..23 (fp16).
//  k3, k4a, k5b: verbatim round 7 (passing, absmax 9.77e-4).
// region layout (r7): (b*256+gy)*98304 + chunk*4096 + gx*16, 24 chunks.
//   chunks 0..17 unused by kA2; k4a writes y fp16 to chunks 0..23;
//   chunks 18..23: vdw fp16 (kA2 -> k4a, k4a reads then overwrites).
// s0 (3 fp32) separate float4/pixel array (k4a -> k5b).

#define NPIX 65536
#define ROWB 98304        // bytes per (batch,row): 24 chunks * 4096
#define REGPB 25165824ull // bytes per batch in region
#define HSTRIDE 332       // k4a/k5b halo LDS row stride (half2 elems) [r7]
#define HA 324            // kA2 halo LDS row stride (half2 elems)
#define QP 260            // kA2 q/k fp32 LDS row stride (floats) [r7 k2b]

union F4U { float4 f4; unsigned int u[4]; };

__device__ __forceinline__ float2 uh2f(unsigned int u) {
  __half2 h; *(unsigned int*)&h = u; return __half22float2(h);
}
__device__ __forceinline__ unsigned int fpack(float a, float b) {
  __half2 h = __halves2half2(__float2half_rn(a), __float2half_rn(b));
  return *(unsigned int*)&h;
}

// ================= kA2: in_proj+LN1+qkv conv+dwconv+Gram+v =================
__global__ __launch_bounds__(256, 2) void kA2(
    const float* __restrict__ x, const float* __restrict__ ipw,
    const float* __restrict__ ipb, const float* __restrict__ lnw,
    const float* __restrict__ lnb, const float* __restrict__ qw,
    const float* __restrict__ qb, const float* __restrict__ dww,
    const float* __restrict__ dwb, char* __restrict__ region,
    float* __restrict__ red) {
  __shared__ unsigned int um[12 * HA];          // conv out 24ch fp16 pairs
  __shared__ __align__(16) float qs[24 * QP];   // q dwconv fp32
  __shared__ __align__(16) float ks[24 * QP];   // k dwconv fp32
  __shared__ __align__(16) float wg[48 * 24];   // group conv w fp32 [c][o]
  __shared__ float qbf[24];
  __shared__ float s_dww[1296], s_dwb[144];
  __shared__ float s_ipw[144], s_ipb[48], s_lnw[48], s_lnb[48];
  const int tid = threadIdx.x;
  for (int i = tid; i < 1296; i += 256) s_dww[i] = dww[i];
  if (tid < 144) { s_dwb[tid] = dwb[tid]; s_ipw[tid] = ipw[tid]; }
  if (tid < 48) { s_ipb[tid] = ipb[tid]; s_lnw[tid] = lnw[tid]; s_lnb[tid] = lnb[tid]; }
  const int b = blockIdx.x >> 8;
  const int tile = blockIdx.x & 255;
  const int ty0 = (tile >> 4) << 4, tx0 = (tile & 15) << 4;
  const int py = tid >> 4, px = tid & 15;
  const int hp = (py + 1) * 18 + (px + 1);
  char* regb = region + (size_t)b * REGPB;
  const int offs[9] = {-19, -18, -17, -1, 0, 1, 17, 18, 19};

  // two halo pixels per thread
  const int p0 = tid, p1 = tid + 256;
  const int h0y = p0 / 18, h0x = p0 - h0y * 18;
  const int g0y = ty0 + h0y - 1, g0x = tx0 + h0x - 1;
  const bool ok0 = ((unsigned)g0y < 256u) && ((unsigned)g0x < 256u);
  const bool has1 = (p1 < 324);
  const int h1y = has1 ? p1 / 18 : 0, h1x = has1 ? p1 - h1y * 18 : 0;
  const int g1y = ty0 + h1y - 1, g1x = tx0 + h1x - 1;
  const bool ok1 = has1 && ((unsigned)g1y < 256u) && ((unsigned)g1x < 256u);
  float xA0 = 0.f, xA1 = 0.f, xA2 = 0.f, xB0 = 0.f, xB1 = 0.f, xB2 = 0.f;
  if (ok0) {
    const int gn = (g0y << 8) + g0x;
    xA0 = x[((size_t)b * 3 + 0) * NPIX + gn];
    xA1 = x[((size_t)b * 3 + 1) * NPIX + gn];
    xA2 = x[((size_t)b * 3 + 2) * NPIX + gn];
  }
  if (ok1) {
    const int gn = (g1y << 8) + g1x;
    xB0 = x[((size_t)b * 3 + 0) * NPIX + gn];
    xB1 = x[((size_t)b * 3 + 1) * NPIX + gn];
    xB2 = x[((size_t)b * 3 + 2) * NPIX + gn];
  }
  __syncthreads();   // shared params ready

  // per-pixel LN1 stats (fp32, two-pass like r7)
  float muA = 0.f, rsA = 0.f, muB = 0.f, rsB = 0.f;
  {
    float m = 0.f;
#pragma unroll
    for (int c = 0; c < 48; ++c)
      m += s_ipw[3*c]*xA0 + s_ipw[3*c+1]*xA1 + s_ipw[3*c+2]*xA2 + s_ipb[c];
    m *= (1.f / 48.f);
    float v = 0.f;
#pragma unroll
    for (int c = 0; c < 48; ++c) {
      const float d = s_ipw[3*c]*xA0 + s_ipw[3*c+1]*xA1 + s_ipw[3*c+2]*xA2 + s_ipb[c] - m;
      v += d * d;
    }
    muA = m; rsA = rsqrtf(v * (1.f / 48.f) + 1e-6f);
    m = 0.f;
#pragma unroll
    for (int c = 0; c < 48; ++c)
      m += s_ipw[3*c]*xB0 + s_ipw[3*c+1]*xB1 + s_ipw[3*c+2]*xB2 + s_ipb[c];
    m *= (1.f / 48.f);
    v = 0.f;
#pragma unroll
    for (int c = 0; c < 48; ++c) {
      const float d = s_ipw[3*c]*xB0 + s_ipw[3*c+1]*xB1 + s_ipw[3*c+2]*xB2 + s_ipb[c] - m;
      v += d * d;
    }
    muB = m; rsB = rsqrtf(v * (1.f / 48.f) + 1e-6f);
  }

  auto loadwg = [&](int cb) {   // cb = qkv output channel base (24 ch)
    for (int i = tid; i < 1152; i += 256) {
      const int c = i / 24, o = i - (i / 24) * 24;
      wg[c * 24 + o] = qw[(cb + o) * 48 + c];
    }
    if (tid < 24) qbf[tid] = qb[cb + tid];
  };
  auto convPhase = [&]() {   // conv 48->24 at both pixels; LN1 recomputed fp32
    for (int r = 0; r < 2; ++r) {
      const int p = r ? p1 : p0;
      if (p >= 324) break;
      const bool ok = r ? ok1 : ok0;
      const float y0 = r ? xB0 : xA0, y1 = r ? xB1 : xA1, y2 = r ? xB2 : xA2;
      const float mu = r ? muB : muA, rs = r ? rsB : rsA;
      float acc[24];
#pragma unroll
      for (int j = 0; j < 24; ++j) acc[j] = qbf[j];
#pragma unroll 4
      for (int c = 0; c < 48; ++c) {
        const float ip = s_ipw[3*c]*y0 + s_ipw[3*c+1]*y1 + s_ipw[3*c+2]*y2 + s_ipb[c];
        const float t = (ip - mu) * rs * s_lnw[c] + s_lnb[c];
        const float* w = &wg[c * 24];
#pragma unroll
        for (int o4 = 0; o4 < 6; ++o4) {
          const float4 wv = *(const float4*)&w[4 * o4];
          acc[4*o4+0] += wv.x * t; acc[4*o4+1] += wv.y * t;
          acc[4*o4+2] += wv.z * t; acc[4*o4+3] += wv.w * t;
        }
      }
#pragma unroll
      for (int j = 0; j < 12; ++j)
        um[j * HA + p] = ok ? fpack(acc[2 * j], acc[2 * j + 1]) : 0u;
    }
  };
  auto dwqk = [&](int cb, float* dst) {   // dwconv 24ch -> fp32 dst rows 0..23
#pragma unroll
    for (int j = 0; j < 12; ++j) {
      float a = s_dwb[cb + 2 * j], bb = s_dwb[cb + 2 * j + 1];
      const unsigned int* hrow = &um[j * HA + hp];
      const float* w0 = &s_dww[(cb + 2 * j) * 9];
      const float* w1 = w0 + 9;
#pragma unroll
      for (int t = 0; t < 9; ++t) {
        const float2 f = uh2f(hrow[offs[t]]);
        a += w0[t] * f.x; bb += w1[t] * f.y;
      }
      dst[(2 * j) * QP + tid] = a;
      dst[(2 * j + 1) * QP + tid] = bb;
    }
  };
  auto dwv = [&](int cb, int chunk0) {   // dwconv v 24ch -> fp16 chunks
    unsigned int vp[12];
#pragma unroll
    for (int j = 0; j < 12; ++j) {
      float a = s_dwb[cb + 2 * j], bb = s_dwb[cb + 2 * j + 1];
      const unsigned int* hrow = &um[j * HA + hp];
      const float* w0 = &s_dww[(cb + 2 * j) * 9];
      const float* w1 = w0 + 9;
#pragma unroll
      for (int t = 0; t < 9; ++t) {
        const float2 f = uh2f(hrow[offs[t]]);
        a += w0[t] * f.x; bb += w1[t] * f.y;
      }
      vp[j] = fpack(a, bb);
    }
    char* vrow = regb + (size_t)(ty0 + py) * ROWB + ((tx0 + px) << 4);
#pragma unroll
    for (int q = 0; q < 3; ++q) {
      F4U u;
      u.u[0] = vp[4 * q]; u.u[1] = vp[4 * q + 1];
      u.u[2] = vp[4 * q + 2]; u.u[3] = vp[4 * q + 3];
      *(float4*)(vrow + (chunk0 + q) * 4096) = u.f4;
    }
  };
  auto gram2 = [&](int hbase) {   // 2 heads from fp32 qs/ks
    for (int e = tid; e < 336; e += 256) {
      const int hh = e / 168, r2 = e - hh * 168;
      float s = 0.f;
      if (r2 < 144) {
        const int c = r2 / 12, d = r2 - (r2 / 12) * 12;
        const float4* qa = (const float4*)&qs[(12 * hh + c) * QP];
        const float4* kb = (const float4*)&ks[(12 * hh + d) * QP];
        for (int p4 = 0; p4 < 64; ++p4) {
          const float4 a = qa[p4], b2 = kb[p4];
          s += a.x * b2.x + a.y * b2.y + a.z * b2.z + a.w * b2.w;
        }
      } else if (r2 < 156) {
        const float4* qa = (const float4*)&qs[(12 * hh + (r2 - 144)) * QP];
        for (int p4 = 0; p4 < 64; ++p4) {
          const float4 a = qa[p4];
          s += a.x * a.x + a.y * a.y + a.z * a.z + a.w * a.w;
        }
      } else {
        const float4* kb = (const float4*)&ks[(12 * hh + (r2 - 156)) * QP];
        for (int p4 = 0; p4 < 64; ++p4) {
          const float4 a = kb[p4];
          s += a.x * a.x + a.y * a.y + a.z * a.z + a.w * a.w;
        }
      }
      atomicAdd(&red[b * 672 + (hbase + hh) * 168 + r2], s);
    }
  };

  loadwg(0);   __syncthreads(); convPhase(); __syncthreads(); dwqk(0, qs);
  loadwg(48);  __syncthreads(); convPhase(); __syncthreads(); dwqk(48, ks);
  __syncthreads(); gram2(0);
  loadwg(24);  __syncthreads(); convPhase(); __syncthreads(); dwqk(24, qs);
  loadwg(72);  __syncthreads(); convPhase(); __syncthreads(); dwqk(72, ks);
  __syncthreads(); gram2(2);
  loadwg(96);  __syncthreads(); convPhase(); __syncthreads(); dwv(96, 18);
  loadwg(120); __syncthreads(); convPhase(); __syncthreads(); dwv(120, 21);
}

// ================= k3: finalize attn, build fused M [r7 verbatim] ==========
__global__ __launch_bounds__(256) void k3_attn(const float* __restrict__ red,
                                               const float* __restrict__ temp,
                                               const float* __restrict__ aow,
                                               float* __restrict__ Mws) {
  __shared__ float attn[4 * 144];
  const int b = blockIdx.x, tid = threadIdx.x;
  const float* rb = red + b * 672;
  for (int e = tid; e < 576; e += 256) {
    const int h = e / 144, r = e - h * 144;
    const int c = r / 12, d = r - c * 12;
    const float g = rb[h * 168 + r];
    const float nq = fmaxf(sqrtf(rb[h * 168 + 144 + c]), 1e-12f);
    const float nk = fmaxf(sqrtf(rb[h * 168 + 156 + d]), 1e-12f);
    attn[e] = g / (nq * nk) * temp[h];
  }
  __syncthreads();
  if (tid < 48) {
    const int h = tid / 12, c = tid - h * 12;
    float* row = &attn[h * 144 + c * 12];
    float m = row[0];
    for (int d = 1; d < 12; ++d) m = fmaxf(m, row[d]);
    float s = 0.f;
    for (int d = 0; d < 12; ++d) { const float e2 = expf(row[d] - m); row[d] = e2; s += e2; }
    const float inv = 1.f / s;
    for (int d = 0; d < 12; ++d) row[d] *= inv;
  }
  __syncthreads();
  for (int e = tid; e < 2304; e += 256) {
    const int o = e / 48, j = e - o * 48;
    const int h = j / 12, d = j - h * 12;
    float s = 0.f;
    for (int c = 0; c < 12; ++c)
      s += aow[o * 48 + h * 12 + c] * attn[h * 144 + c * 12 + d];
    Mws[b * 2304 + e] = s;
  }
}

// ========== k4a: recompute in_proj, attn-out, LN2, ffn_in [r7 verbatim] ====
__global__ __launch_bounds__(256, 3) void k4a(
    char* __restrict__ region, float4* __restrict__ s0arr,
    const float* __restrict__ x, const float* __restrict__ ipw,
    const float* __restrict__ ipb, const float* __restrict__ Mws,
    const float* __restrict__ aob, const float* __restrict__ lnw,
    const float* __restrict__ lnb, const float* __restrict__ fiw,
    const float* __restrict__ fib, const float* __restrict__ opw) {
  __shared__ __align__(16) float MT[48 * 48];     // MT[j][o]
  __shared__ __align__(16) float wT2[48 * 192];   // wT2[c][pos], pos interleaved
  __shared__ float s_aob[48], s_lnw[48], s_lnb[48], s_fib2[192], s_opw[144];
  __shared__ float s_ipw[144], s_ipb[48];
  const int tid = threadIdx.x;
  const int b = blockIdx.x >> 8;
  const int gy = blockIdx.x & 255;
  const int n = (gy << 8) + tid;
  for (int i = tid; i < 2304; i += 256) {
    const int o = i / 48, j = i - o * 48;
    MT[j * 48 + o] = Mws[b * 2304 + i];
  }
  for (int i = tid; i < 9216; i += 256) {
    const int c = i / 192, pos = i - c * 192;
    const int ch = (pos & 1) ? 96 + (pos >> 1) : (pos >> 1);
    wT2[i] = fiw[ch * 48 + c];
  }
  if (tid < 192) {
    const int ch = (tid & 1) ? 96 + (tid >> 1) : (tid >> 1);
    s_fib2[tid] = fib[ch];
  }
  if (tid < 144) { s_opw[tid] = opw[tid]; s_ipw[tid] = ipw[tid]; }
  if (tid < 48) {
    s_aob[tid] = aob[tid]; s_lnw[tid] = lnw[tid]; s_lnb[tid] = lnb[tid];
    s_ipb[tid] = ipb[tid];
  }
  __syncthreads();
  char* rowp = region + (size_t)((b << 8) + gy) * ROWB + (tid << 4);
  float vv[48];
#pragma unroll
  for (int q = 0; q < 6; ++q) {
    F4U u; u.f4 = *(const float4*)(rowp + (18 + q) * 4096);
#pragma unroll
    for (int j = 0; j < 4; ++j) {
      const float2 f = uh2f(u.u[j]);
      vv[8 * q + 2 * j] = f.x; vv[8 * q + 2 * j + 1] = f.y;
    }
  }
  float y[48];
#pragma unroll
  for (int o = 0; o < 48; ++o) y[o] = s_aob[o];
#pragma unroll 4
  for (int j = 0; j < 48; ++j) {
    const float vj = vv[j];
    const float* mr = &MT[j * 48];
#pragma unroll
    for (int o4 = 0; o4 < 12; ++o4) {
      const float4 m = *(const float4*)&mr[o4 * 4];
      y[o4 * 4 + 0] += m.x * vj; y[o4 * 4 + 1] += m.y * vj;
      y[o4 * 4 + 2] += m.z * vj; y[o4 * 4 + 3] += m.w * vj;
    }
  }
  // recompute in_proj (xp) and add residual
  const float x0 = x[((size_t)b * 3 + 0) * NPIX + n];
  const float x1 = x[((size_t)b * 3 + 1) * NPIX + n];
  const float x2 = x[((size_t)b * 3 + 2) * NPIX + n];
  float mu = 0.f;
#pragma unroll
  for (int c = 0; c < 48; ++c) {
    y[c] += s_ipw[c * 3] * x0 + s_ipw[c * 3 + 1] * x1 + s_ipw[c * 3 + 2] * x2 + s_ipb[c];
    mu += y[c];
  }
  float s0 = 0.f, s1 = 0.f, s2 = 0.f;
#pragma unroll
  for (int c = 0; c < 48; ++c) {
    s0 += s_opw[c] * y[c]; s1 += s_opw[48 + c] * y[c]; s2 += s_opw[96 + c] * y[c];
  }
  float4 s0v; s0v.x = s0; s0v.y = s1; s0v.z = s2; s0v.w = 0.f;
  s0arr[(size_t)b * NPIX + n] = s0v;
  mu *= (1.f / 48.f);
  float var = 0.f;
#pragma unroll
  for (int c = 0; c < 48; ++c) { const float d = y[c] - mu; var += d * d; }
  const float rs2 = rsqrtf(var * (1.f / 48.f) + 1e-6f);
#pragma unroll
  for (int c = 0; c < 48; ++c) y[c] = (y[c] - mu) * rs2 * s_lnw[c] + s_lnb[c];
#pragma unroll
  for (int ob = 0; ob < 12; ++ob) {
    const int o0 = ob * 16;
    float acc[16];
#pragma unroll
    for (int j = 0; j < 16; ++j) acc[j] = s_fib2[o0 + j];
#pragma unroll 4
    for (int c = 0; c < 48; ++c) {
      const float xv = y[c];
      const float4 w0 = *(const float4*)&wT2[c * 192 + o0];
      const float4 w1 = *(const float4*)&wT2[c * 192 + o0 + 4];
      const float4 w2 = *(const float4*)&wT2[c * 192 + o0 + 8];
      const float4 w3 = *(const float4*)&wT2[c * 192 + o0 + 12];
      acc[0] += w0.x * xv; acc[1] += w0.y * xv; acc[2] += w0.z * xv; acc[3] += w0.w * xv;
      acc[4] += w1.x * xv; acc[5] += w1.y * xv; acc[6] += w1.z * xv; acc[7] += w1.w * xv;
      acc[8] += w2.x * xv; acc[9] += w2.y * xv; acc[10] += w2.z * xv; acc[11] += w2.w * xv;
      acc[12] += w3.x * xv; acc[13] += w3.y * xv; acc[14] += w3.z * xv; acc[15] += w3.w * xv;
    }
    F4U u;
    u.u[0] = fpack(acc[0], acc[1]);   u.u[1] = fpack(acc[2], acc[3]);
    u.u[2] = fpack(acc[4], acc[5]);   u.u[3] = fpack(acc[6], acc[7]);
    *(float4*)(rowp + (2 * ob) * 4096) = u.f4;
    u.u[0] = fpack(acc[8], acc[9]);   u.u[1] = fpack(acc[10], acc[11]);
    u.u[2] = fpack(acc[12], acc[13]); u.u[3] = fpack(acc[14], acc[15]);
    *(float4*)(rowp + (2 * ob + 1) * 4096) = u.f4;
  }
}

// ====== k5b: dw + SimpleGate + ffn_out + out_proj [r7 verbatim] ============
__global__ __launch_bounds__(256, 3) void k5b(
    const char* __restrict__ region, const float4* __restrict__ s0arr,
    const float* __restrict__ fdww, const float* __restrict__ fdwb,
    const float* __restrict__ fow, const float* __restrict__ fob,
    const float* __restrict__ opw, const float* __restrict__ opb,
    float* __restrict__ out) {
  __shared__ unsigned int halo[12 * HSTRIDE];
  __shared__ __align__(16) float fowT[96 * 48];   // fowT[c1][o] = fow[o][c1]
  __shared__ float s_dww2[1728], s_dwb2[192], s_opw[144], s_fob[48];
  const int tid = threadIdx.x;
  for (int i = tid; i < 4608; i += 256) {
    const int c = i / 48, o = i - c * 48;
    fowT[i] = fow[o * 96 + c];
  }
  for (int i = tid; i < 1728; i += 256) {
    const int P = i / 9, t = i - P * 9;
    const int ch = (P & 1) ? 96 + (P >> 1) : (P >> 1);
    s_dww2[i] = fdww[ch * 9 + t];
  }
  if (tid < 192) {
    const int ch = (tid & 1) ? 96 + (tid >> 1) : (tid >> 1);
    s_dwb2[tid] = fdwb[ch];
  }
  if (tid < 144) s_opw[tid] = opw[tid];
  if (tid < 48) s_fob[tid] = fob[tid];
  const int b = blockIdx.x >> 8;
  const int tile = blockIdx.x & 255;
  const int ty0 = (tile >> 4) << 4, tx0 = (tile & 15) << 4;
  const int py = tid >> 4, px = tid & 15;
  const int hp = (py + 1) * 18 + (px + 1);
  const int gn = ((ty0 + py) << 8) + (tx0 + px);
  const char* regb = region + (size_t)b * REGPB;

  float4 pf[4];
  auto prefetch = [&](int cb) {
#pragma unroll
    for (int r = 0; r < 4; ++r) {
      const int i = tid + (r << 8);
      float4 z = {0.f, 0.f, 0.f, 0.f}; pf[r] = z;
      if (i < 972) {
        const int c4 = i / 324, p = i - c4 * 324;
        const int hy = p / 18, hx = p - hy * 18;
        const int gy = ty0 + hy - 1, gx = tx0 + hx - 1;
        if (((unsigned)gy < 256u) && ((unsigned)gx < 256u))
          pf[r] = *(const float4*)(regb + (size_t)gy * ROWB + (cb + c4) * 4096 + (gx << 4));
      }
    }
  };
  auto commit = [&]() {
#pragma unroll
    for (int r = 0; r < 4; ++r) {
      const int i = tid + (r << 8);
      if (i < 972) {
        const int c4 = i / 324, p = i - c4 * 324;
        F4U u; u.f4 = pf[r];
        const int pb = c4 << 2;
#pragma unroll
        for (int j = 0; j < 4; ++j) halo[(pb + j) * HSTRIDE + p] = u.u[j];
      }
    }
  };

  float facc[48];
#pragma unroll
  for (int o = 0; o < 48; ++o) facc[o] = 0.f;
  prefetch(0);
  for (int s = 0; s < 8; ++s) {
    __syncthreads(); commit(); __syncthreads();
    if (s < 7) prefetch(3 * (s + 1));
    const int offs[9] = {-19, -18, -17, -1, 0, 1, 17, 18, 19};
#pragma unroll
    for (int pp = 0; pp < 12; ++pp) {
      const int P = 24 * s + 2 * pp;
      const float* w0 = &s_dww2[P * 9];
      const float* w1 = w0 + 9;
      const unsigned int* hrow = &halo[pp * HSTRIDE + hp];
      float a = s_dwb2[P], b2 = s_dwb2[P + 1];
#pragma unroll
      for (int t = 0; t < 9; ++t) {
        const float2 f = uh2f(hrow[offs[t]]);
        a += w0[t] * f.x; b2 += w1[t] * f.y;
      }
      const float gate = a * b2;
      const float* fr = &fowT[(12 * s + pp) * 48];
#pragma unroll
      for (int o4 = 0; o4 < 12; ++o4) {
        const float4 m = *(const float4*)&fr[o4 * 4];
        facc[o4 * 4 + 0] += m.x * gate; facc[o4 * 4 + 1] += m.y * gate;
        facc[o4 * 4 + 2] += m.z * gate; facc[o4 * 4 + 3] += m.w * gate;
      }
    }
  }
  const float4 s0v = s0arr[(size_t)b * NPIX + gn];
  float r0 = s0v.x + opb[0];
  float r1 = s0v.y + opb[1];
  float r2 = s0v.z + opb[2];
#pragma unroll
  for (int o = 0; o < 48; ++o) {
    const float f = facc[o] + s_fob[o];
    r0 += s_opw[o] * f; r1 += s_opw[48 + o] * f; r2 += s_opw[96 + o] * f;
  }
  out[((size_t)b * 3 + 0) * NPIX + gn] = r0;
  out[((size_t)b * 3 + 1) * NPIX + gn] = r1;
  out[((size_t)b * 3 + 2) * NPIX + gn] = r2;
}

extern "C" void kernel_launch(void* const* d_in, const int* in_sizes, int n_in,
                              void* d_out, int out_size, void* d_ws, size_t ws_size,
                              hipStream_t stream) {
  const float* x    = (const float*)d_in[0];
  const float* ipw  = (const float*)d_in[1];
  const float* ipb  = (const float*)d_in[2];
  const float* ln1w = (const float*)d_in[3];
  const float* ln1b = (const float*)d_in[4];
  const float* qw   = (const float*)d_in[5];
  const float* qb   = (const float*)d_in[6];
  const float* qdww = (const float*)d_in[7];
  const float* qdwb = (const float*)d_in[8];
  const float* temp = (const float*)d_in[9];
  const float* aow  = (const float*)d_in[10];
  const float* aob  = (const float*)d_in[11];
  const float* ln2w = (const float*)d_in[12];
  const float* ln2b = (const float*)d_in[13];
  const float* fiw  = (const float*)d_in[14];
  const float* fib  = (const float*)d_in[15];
  const float* fdww = (const float*)d_in[16];
  const float* fdwb = (const float*)d_in[17];
  const float* fow  = (const float*)d_in[18];
  const float* fob  = (const float*)d_in[19];
  const float* opw  = (const float*)d_in[20];
  const float* opb  = (const float*)d_in[21];

  const size_t s0Per = (size_t)NPIX * 16;
  int bc = 8;
  while (bc > 1 &&
         (size_t)bc * (REGPB + s0Per) + (5376 + 18432) * 4 > ws_size)
    bc >>= 1;
  char* region = (char*)d_ws;
  float4* s0arr = (float4*)(region + (size_t)bc * REGPB);
  float* red = (float*)((char*)s0arr + (size_t)bc * s0Per);
  float* Mws = red + 5376;
  hipMemsetAsync(red, 0, 5376 * sizeof(float), stream);
  for (int b0 = 0; b0 < 8; b0 += bc) {
    kA2<<<bc * 256, 256, 0, stream>>>(x + (size_t)b0 * 3 * NPIX, ipw, ipb,
                                      ln1w, ln1b, qw, qb, qdww, qdwb,
                                      region, red + b0 * 672);
    k3_attn<<<bc, 256, 0, stream>>>(red + b0 * 672, temp, aow,
                                    Mws + (size_t)b0 * 2304);
    k4a<<<bc * 256, 256, 0, stream>>>(region, s0arr, x + (size_t)b0 * 3 * NPIX,
                                      ipw, ipb, Mws + (size_t)b0 * 2304, aob,
                                      ln2w, ln2b, fiw, fib, opw);
    k5b<<<bc * 256, 256, 0, stream>>>(region, s0arr, fdww, fdwb, fow, fob,
                                      opw, opb,
                                      (float*)d_out + (size_t)b0 * 3 * NPIX);
  }
}

// Round 11
// 1052.422 us; speedup vs baseline: 2.5521x; 1.0501x over previous
//
#include <hip/hip_runtime.h>
#include <hip/hip_fp16.h>

// CAPTNet block. B=8, CIN=3, H=W=256, DIM=48, HEADS=4 (ch=12), HID=96.
// Round 11: r10 pipeline; kA2 -> kA3 (t packed fp16 in regs computed once,
// conv shares weight reads across the thread's 2 pixels, q/k LDS fp16 pairs
// in r7's proven k2b format + verbatim r7 Gram). k3/k4a/k5b verbatim r10.
// region layout (r7): (b*256+gy)*98304 + chunk*4096 + gx*16, 24 chunks.
//   chunks 18..23: vdw fp16 (kA3 -> k4a); k4a writes y fp16 chunks 0..23.
// s0 (3 fp32) separate float4/pixel array (k4a -> k5b).

#define NPIX 65536
#define ROWB 98304        // bytes per (batch,row): 24 chunks * 4096
#define REGPB 25165824ull // bytes per batch in region
#define HSTRIDE 332       // k4a/k5b halo LDS row stride (half2 elems) [r7]
#define HA 324            // kA3 halo LDS row stride (u32/half2 elems)
#define KQ 260            // kA3 q/k fp16 LDS row stride (u32), 16B-aligned

union F4U { float4 f4; unsigned int u[4]; };

__device__ __forceinline__ float2 uh2f(unsigned int u) {
  __half2 h; *(unsigned int*)&h = u; return __half22float2(h);
}
__device__ __forceinline__ unsigned int fpack(float a, float b) {
  __half2 h = __halves2half2(__float2half_rn(a), __float2half_rn(b));
  return *(unsigned int*)&h;
}

// ================= kA3: in_proj+LN1+qkv conv+dwconv+Gram+v =================
__global__ __launch_bounds__(256, 3) void kA3(
    const float* __restrict__ x, const float* __restrict__ ipw,
    const float* __restrict__ ipb, const float* __restrict__ lnw,
    const float* __restrict__ lnb, const float* __restrict__ qw,
    const float* __restrict__ qb, const float* __restrict__ dww,
    const float* __restrict__ dwb, char* __restrict__ region,
    float* __restrict__ red) {
  __shared__ unsigned int um[12 * HA];          // conv out 24ch fp16 pairs
  __shared__ unsigned int qsm[12 * KQ];         // q dwconv fp16 pairs (center)
  __shared__ unsigned int ksm[12 * KQ];         // k dwconv fp16 pairs
  __shared__ __align__(16) float wg[48 * 24];   // group conv w fp32 [c][o]
  __shared__ float qbf[24];
  __shared__ float s_dww[1296], s_dwb[144];
  __shared__ float s_ipw[144], s_ipb[48], s_lnw[48], s_lnb[48];
  const int tid = threadIdx.x;
  for (int i = tid; i < 1296; i += 256) s_dww[i] = dww[i];
  if (tid < 144) { s_dwb[tid] = dwb[tid]; s_ipw[tid] = ipw[tid]; }
  if (tid < 48) { s_ipb[tid] = ipb[tid]; s_lnw[tid] = lnw[tid]; s_lnb[tid] = lnb[tid]; }
  const int b = blockIdx.x >> 8;
  const int tile = blockIdx.x & 255;
  const int ty0 = (tile >> 4) << 4, tx0 = (tile & 15) << 4;
  const int py = tid >> 4, px = tid & 15;
  const int hp = (py + 1) * 18 + (px + 1);
  char* regb = region + (size_t)b * REGPB;
  const int offs[9] = {-19, -18, -17, -1, 0, 1, 17, 18, 19};

  // two halo pixels per thread
  const int p0 = tid, p1 = tid + 256;
  const int h0y = p0 / 18, h0x = p0 - h0y * 18;
  const int g0y = ty0 + h0y - 1, g0x = tx0 + h0x - 1;
  const bool ok0 = ((unsigned)g0y < 256u) && ((unsigned)g0x < 256u);
  const bool has1 = (p1 < 324);
  const int h1y = has1 ? p1 / 18 : 0, h1x = has1 ? p1 - h1y * 18 : 0;
  const int g1y = ty0 + h1y - 1, g1x = tx0 + h1x - 1;
  const bool ok1 = has1 && ((unsigned)g1y < 256u) && ((unsigned)g1x < 256u);
  float xA0 = 0.f, xA1 = 0.f, xA2 = 0.f, xB0 = 0.f, xB1 = 0.f, xB2 = 0.f;
  if (ok0) {
    const int gn = (g0y << 8) + g0x;
    xA0 = x[((size_t)b * 3 + 0) * NPIX + gn];
    xA1 = x[((size_t)b * 3 + 1) * NPIX + gn];
    xA2 = x[((size_t)b * 3 + 2) * NPIX + gn];
  }
  if (ok1) {
    const int gn = (g1y << 8) + g1x;
    xB0 = x[((size_t)b * 3 + 0) * NPIX + gn];
    xB1 = x[((size_t)b * 3 + 1) * NPIX + gn];
    xB2 = x[((size_t)b * 3 + 2) * NPIX + gn];
  }
  __syncthreads();   // shared params ready

  // t = LN1(in_proj(x)) computed ONCE per pixel, packed fp16 in registers
  unsigned int tA[24], tB[24];
  {
    float xn[48];
    float mu = 0.f;
#pragma unroll
    for (int c = 0; c < 48; ++c) {
      xn[c] = s_ipw[3*c]*xA0 + s_ipw[3*c+1]*xA1 + s_ipw[3*c+2]*xA2 + s_ipb[c];
      mu += xn[c];
    }
    mu *= (1.f / 48.f);
    float var = 0.f;
#pragma unroll
    for (int c = 0; c < 48; ++c) { const float d = xn[c] - mu; var += d * d; }
    float rs = rsqrtf(var * (1.f / 48.f) + 1e-6f);
#pragma unroll
    for (int c2 = 0; c2 < 24; ++c2)
      tA[c2] = fpack((xn[2*c2]   - mu) * rs * s_lnw[2*c2]   + s_lnb[2*c2],
                     (xn[2*c2+1] - mu) * rs * s_lnw[2*c2+1] + s_lnb[2*c2+1]);
    mu = 0.f;
#pragma unroll
    for (int c = 0; c < 48; ++c) {
      xn[c] = s_ipw[3*c]*xB0 + s_ipw[3*c+1]*xB1 + s_ipw[3*c+2]*xB2 + s_ipb[c];
      mu += xn[c];
    }
    mu *= (1.f / 48.f);
    var = 0.f;
#pragma unroll
    for (int c = 0; c < 48; ++c) { const float d = xn[c] - mu; var += d * d; }
    rs = rsqrtf(var * (1.f / 48.f) + 1e-6f);
#pragma unroll
    for (int c2 = 0; c2 < 24; ++c2)
      tB[c2] = fpack((xn[2*c2]   - mu) * rs * s_lnw[2*c2]   + s_lnb[2*c2],
                     (xn[2*c2+1] - mu) * rs * s_lnw[2*c2+1] + s_lnb[2*c2+1]);
  }

  auto loadwg = [&](int cb) {   // cb = qkv output channel base (24 ch)
    for (int i = tid; i < 1152; i += 256) {
      const int c = i / 24, o = i - (i / 24) * 24;
      wg[c * 24 + o] = qw[(cb + o) * 48 + c];
    }
    if (tid < 24) qbf[tid] = qb[cb + tid];
  };
  auto convPhase = [&]() {   // conv 48->24, both pixels share weight reads
    float a0[24], a1[24];
#pragma unroll
    for (int j = 0; j < 24; ++j) { a0[j] = qbf[j]; a1[j] = qbf[j]; }
#pragma unroll 4
    for (int c2 = 0; c2 < 24; ++c2) {
      const float2 t0 = uh2f(tA[c2]);
      const float2 t1 = uh2f(tB[c2]);
      const float* w0 = &wg[(2 * c2) * 24];
      const float* w1 = &wg[(2 * c2 + 1) * 24];
#pragma unroll
      for (int o4 = 0; o4 < 6; ++o4) {
        const float4 wa = *(const float4*)&w0[4 * o4];
        const float4 wb = *(const float4*)&w1[4 * o4];
        a0[4*o4+0] += wa.x * t0.x + wb.x * t0.y;
        a0[4*o4+1] += wa.y * t0.x + wb.y * t0.y;
        a0[4*o4+2] += wa.z * t0.x + wb.z * t0.y;
        a0[4*o4+3] += wa.w * t0.x + wb.w * t0.y;
        a1[4*o4+0] += wa.x * t1.x + wb.x * t1.y;
        a1[4*o4+1] += wa.y * t1.x + wb.y * t1.y;
        a1[4*o4+2] += wa.z * t1.x + wb.z * t1.y;
        a1[4*o4+3] += wa.w * t1.x + wb.w * t1.y;
      }
    }
#pragma unroll
    for (int j = 0; j < 12; ++j)
      um[j * HA + p0] = ok0 ? fpack(a0[2 * j], a0[2 * j + 1]) : 0u;
    if (has1) {
#pragma unroll
      for (int j = 0; j < 12; ++j)
        um[j * HA + p1] = ok1 ? fpack(a1[2 * j], a1[2 * j + 1]) : 0u;
    }
  };
  auto dwqk = [&](int cb, unsigned int* dst) {   // dwconv 24ch -> fp16 pairs
#pragma unroll
    for (int j = 0; j < 12; ++j) {
      float a = s_dwb[cb + 2 * j], bb = s_dwb[cb + 2 * j + 1];
      const unsigned int* hrow = &um[j * HA + hp];
      const float* w0 = &s_dww[(cb + 2 * j) * 9];
      const float* w1 = w0 + 9;
#pragma unroll
      for (int t = 0; t < 9; ++t) {
        const float2 f = uh2f(hrow[offs[t]]);
        a += w0[t] * f.x; bb += w1[t] * f.y;
      }
      dst[j * KQ + tid] = fpack(a, bb);
    }
  };
  auto dwv = [&](int cb, int chunk0) {   // dwconv v 24ch -> fp16 chunks
    unsigned int vp[12];
#pragma unroll
    for (int j = 0; j < 12; ++j) {
      float a = s_dwb[cb + 2 * j], bb = s_dwb[cb + 2 * j + 1];
      const unsigned int* hrow = &um[j * HA + hp];
      const float* w0 = &s_dww[(cb + 2 * j) * 9];
      const float* w1 = w0 + 9;
#pragma unroll
      for (int t = 0; t < 9; ++t) {
        const float2 f = uh2f(hrow[offs[t]]);
        a += w0[t] * f.x; bb += w1[t] * f.y;
      }
      vp[j] = fpack(a, bb);
    }
    char* vrow = regb + (size_t)(ty0 + py) * ROWB + ((tx0 + px) << 4);
#pragma unroll
    for (int q = 0; q < 3; ++q) {
      F4U u;
      u.u[0] = vp[4 * q]; u.u[1] = vp[4 * q + 1];
      u.u[2] = vp[4 * q + 2]; u.u[3] = vp[4 * q + 3];
      *(float4*)(vrow + (chunk0 + q) * 4096) = u.f4;
    }
  };
  auto gram2 = [&](int hbase) {   // 2 heads from fp16 qsm/ksm [r7 verbatim]
    for (int e = tid; e < 336; e += 256) {
      const int hh = e / 168, r2 = e - hh * 168;
      float s = 0.f;
      if (r2 < 144) {
        const int c = r2 / 12, d = r2 - (r2 / 12) * 12;
        const int qc = 12 * hh + c, kd = 12 * hh + d;
        const unsigned int* qr = &qsm[(qc >> 1) * KQ];
        const unsigned int* kr = &ksm[(kd >> 1) * KQ];
        const int q1 = qc & 1, k1 = kd & 1;
        for (int p = 0; p < 256; ++p) {
          const float2 fq = uh2f(qr[p]); const float2 fk = uh2f(kr[p]);
          s += (q1 ? fq.y : fq.x) * (k1 ? fk.y : fk.x);
        }
      } else if (r2 < 156) {
        const int qc = 12 * hh + (r2 - 144);
        const unsigned int* qr = &qsm[(qc >> 1) * KQ];
        const int q1 = qc & 1;
        for (int p = 0; p < 256; ++p) {
          const float2 fq = uh2f(qr[p]);
          const float v = q1 ? fq.y : fq.x;
          s += v * v;
        }
      } else {
        const int kd = 12 * hh + (r2 - 156);
        const unsigned int* kr = &ksm[(kd >> 1) * KQ];
        const int k1 = kd & 1;
        for (int p = 0; p < 256; ++p) {
          const float2 fk = uh2f(kr[p]);
          const float v = k1 ? fk.y : fk.x;
          s += v * v;
        }
      }
      atomicAdd(&red[b * 672 + (hbase + hh) * 168 + r2], s);
    }
  };

  loadwg(0);   __syncthreads(); convPhase(); __syncthreads(); dwqk(0, qsm);
  loadwg(48);  __syncthreads(); convPhase(); __syncthreads(); dwqk(48, ksm);
  __syncthreads(); gram2(0);
  loadwg(24);  __syncthreads(); convPhase(); __syncthreads(); dwqk(24, qsm);
  loadwg(72);  __syncthreads(); convPhase(); __syncthreads(); dwqk(72, ksm);
  __syncthreads(); gram2(2);
  loadwg(96);  __syncthreads(); convPhase(); __syncthreads(); dwv(96, 18);
  loadwg(120); __syncthreads(); convPhase(); __syncthreads(); dwv(120, 21);
}

// ================= k3: finalize attn, build fused M [r10 verbatim] ==========
__global__ __launch_bounds__(256) void k3_attn(const float* __restrict__ red,
                                               const float* __restrict__ temp,
                                               const float* __restrict__ aow,
                                               float* __restrict__ Mws) {
  __shared__ float attn[4 * 144];
  const int b = blockIdx.x, tid = threadIdx.x;
  const float* rb = red + b * 672;
  for (int e = tid; e < 576; e += 256) {
    const int h = e / 144, r = e - h * 144;
    const int c = r / 12, d = r - c * 12;
    const float g = rb[h * 168 + r];
    const float nq = fmaxf(sqrtf(rb[h * 168 + 144 + c]), 1e-12f);
    const float nk = fmaxf(sqrtf(rb[h * 168 + 156 + d]), 1e-12f);
    attn[e] = g / (nq * nk) * temp[h];
  }
  __syncthreads();
  if (tid < 48) {
    const int h = tid / 12, c = tid - h * 12;
    float* row = &attn[h * 144 + c * 12];
    float m = row[0];
    for (int d = 1; d < 12; ++d) m = fmaxf(m, row[d]);
    float s = 0.f;
    for (int d = 0; d < 12; ++d) { const float e2 = expf(row[d] - m); row[d] = e2; s += e2; }
    const float inv = 1.f / s;
    for (int d = 0; d < 12; ++d) row[d] *= inv;
  }
  __syncthreads();
  for (int e = tid; e < 2304; e += 256) {
    const int o = e / 48, j = e - o * 48;
    const int h = j / 12, d = j - h * 12;
    float s = 0.f;
    for (int c = 0; c < 12; ++c)
      s += aow[o * 48 + h * 12 + c] * attn[h * 144 + c * 12 + d];
    Mws[b * 2304 + e] = s;
  }
}

// ========== k4a: recompute in_proj, attn-out, LN2, ffn_in [r10 verbatim] ====
__global__ __launch_bounds__(256, 3) void k4a(
    char* __restrict__ region, float4* __restrict__ s0arr,
    const float* __restrict__ x, const float* __restrict__ ipw,
    const float* __restrict__ ipb, const float* __restrict__ Mws,
    const float* __restrict__ aob, const float* __restrict__ lnw,
    const float* __restrict__ lnb, const float* __restrict__ fiw,
    const float* __restrict__ fib, const float* __restrict__ opw) {
  __shared__ __align__(16) float MT[48 * 48];     // MT[j][o]
  __shared__ __align__(16) float wT2[48 * 192];   // wT2[c][pos], pos interleaved
  __shared__ float s_aob[48], s_lnw[48], s_lnb[48], s_fib2[192], s_opw[144];
  __shared__ float s_ipw[144], s_ipb[48];
  const int tid = threadIdx.x;
  const int b = blockIdx.x >> 8;
  const int gy = blockIdx.x & 255;
  const int n = (gy << 8) + tid;
  for (int i = tid; i < 2304; i += 256) {
    const int o = i / 48, j = i - o * 48;
    MT[j * 48 + o] = Mws[b * 2304 + i];
  }
  for (int i = tid; i < 9216; i += 256) {
    const int c = i / 192, pos = i - c * 192;
    const int ch = (pos & 1) ? 96 + (pos >> 1) : (pos >> 1);
    wT2[i] = fiw[ch * 48 + c];
  }
  if (tid < 192) {
    const int ch = (tid & 1) ? 96 + (tid >> 1) : (tid >> 1);
    s_fib2[tid] = fib[ch];
  }
  if (tid < 144) { s_opw[tid] = opw[tid]; s_ipw[tid] = ipw[tid]; }
  if (tid < 48) {
    s_aob[tid] = aob[tid]; s_lnw[tid] = lnw[tid]; s_lnb[tid] = lnb[tid];
    s_ipb[tid] = ipb[tid];
  }
  __syncthreads();
  char* rowp = region + (size_t)((b << 8) + gy) * ROWB + (tid << 4);
  float vv[48];
#pragma unroll
  for (int q = 0; q < 6; ++q) {
    F4U u; u.f4 = *(const float4*)(rowp + (18 + q) * 4096);
#pragma unroll
    for (int j = 0; j < 4; ++j) {
      const float2 f = uh2f(u.u[j]);
      vv[8 * q + 2 * j] = f.x; vv[8 * q + 2 * j + 1] = f.y;
    }
  }
  float y[48];
#pragma unroll
  for (int o = 0; o < 48; ++o) y[o] = s_aob[o];
#pragma unroll 4
  for (int j = 0; j < 48; ++j) {
    const float vj = vv[j];
    const float* mr = &MT[j * 48];
#pragma unroll
    for (int o4 = 0; o4 < 12; ++o4) {
      const float4 m = *(const float4*)&mr[o4 * 4];
      y[o4 * 4 + 0] += m.x * vj; y[o4 * 4 + 1] += m.y * vj;
      y[o4 * 4 + 2] += m.z * vj; y[o4 * 4 + 3] += m.w * vj;
    }
  }
  // recompute in_proj (xp) and add residual
  const float x0 = x[((size_t)b * 3 + 0) * NPIX + n];
  const float x1 = x[((size_t)b * 3 + 1) * NPIX + n];
  const float x2 = x[((size_t)b * 3 + 2) * NPIX + n];
  float mu = 0.f;
#pragma unroll
  for (int c = 0; c < 48; ++c) {
    y[c] += s_ipw[c * 3] * x0 + s_ipw[c * 3 + 1] * x1 + s_ipw[c * 3 + 2] * x2 + s_ipb[c];
    mu += y[c];
  }
  float s0 = 0.f, s1 = 0.f, s2 = 0.f;
#pragma unroll
  for (int c = 0; c < 48; ++c) {
    s0 += s_opw[c] * y[c]; s1 += s_opw[48 + c] * y[c]; s2 += s_opw[96 + c] * y[c];
  }
  float4 s0v; s0v.x = s0; s0v.y = s1; s0v.z = s2; s0v.w = 0.f;
  s0arr[(size_t)b * NPIX + n] = s0v;
  mu *= (1.f / 48.f);
  float var = 0.f;
#pragma unroll
  for (int c = 0; c < 48; ++c) { const float d = y[c] - mu; var += d * d; }
  const float rs2 = rsqrtf(var * (1.f / 48.f) + 1e-6f);
#pragma unroll
  for (int c = 0; c < 48; ++c) y[c] = (y[c] - mu) * rs2 * s_lnw[c] + s_lnb[c];
#pragma unroll
  for (int ob = 0; ob < 12; ++ob) {
    const int o0 = ob * 16;
    float acc[16];
#pragma unroll
    for (int j = 0; j < 16; ++j) acc[j] = s_fib2[o0 + j];
#pragma unroll 4
    for (int c = 0; c < 48; ++c) {
      const float xv = y[c];
      const float4 w0 = *(const float4*)&wT2[c * 192 + o0];
      const float4 w1 = *(const float4*)&wT2[c * 192 + o0 + 4];
      const float4 w2 = *(const float4*)&wT2[c * 192 + o0 + 8];
      const float4 w3 = *(const float4*)&wT2[c * 192 + o0 + 12];
      acc[0] += w0.x * xv; acc[1] += w0.y * xv; acc[2] += w0.z * xv; acc[3] += w0.w * xv;
      acc[4] += w1.x * xv; acc[5] += w1.y * xv; acc[6] += w1.z * xv; acc[7] += w1.w * xv;
      acc[8] += w2.x * xv; acc[9] += w2.y * xv; acc[10] += w2.z * xv; acc[11] += w2.w * xv;
      acc[12] += w3.x * xv; acc[13] += w3.y * xv; acc[14] += w3.z * xv; acc[15] += w3.w * xv;
    }
    F4U u;
    u.u[0] = fpack(acc[0], acc[1]);   u.u[1] = fpack(acc[2], acc[3]);
    u.u[2] = fpack(acc[4], acc[5]);   u.u[3] = fpack(acc[6], acc[7]);
    *(float4*)(rowp + (2 * ob) * 4096) = u.f4;
    u.u[0] = fpack(acc[8], acc[9]);   u.u[1] = fpack(acc[10], acc[11]);
    u.u[2] = fpack(acc[12], acc[13]); u.u[3] = fpack(acc[14], acc[15]);
    *(float4*)(rowp + (2 * ob + 1) * 4096) = u.f4;
  }
}

// ====== k5b: dw + SimpleGate + ffn_out + out_proj [r10 verbatim] ============
__global__ __launch_bounds__(256, 3) void k5b(
    const char* __restrict__ region, const float4* __restrict__ s0arr,
    const float* __restrict__ fdww, const float* __restrict__ fdwb,
    const float* __restrict__ fow, const float* __restrict__ fob,
    const float* __restrict__ opw, const float* __restrict__ opb,
    float* __restrict__ out) {
  __shared__ unsigned int halo[12 * HSTRIDE];
  __shared__ __align__(16) float fowT[96 * 48];   // fowT[c1][o] = fow[o][c1]
  __shared__ float s_dww2[1728], s_dwb2[192], s_opw[144], s_fob[48];
  const int tid = threadIdx.x;
  for (int i = tid; i < 4608; i += 256) {
    const int c = i / 48, o = i - c * 48;
    fowT[i] = fow[o * 96 + c];
  }
  for (int i = tid; i < 1728; i += 256) {
    const int P = i / 9, t = i - P * 9;
    const int ch = (P & 1) ? 96 + (P >> 1) : (P >> 1);
    s_dww2[i] = fdww[ch * 9 + t];
  }
  if (tid < 192) {
    const int ch = (tid & 1) ? 96 + (tid >> 1) : (tid >> 1);
    s_dwb2[tid] = fdwb[ch];
  }
  if (tid < 144) s_opw[tid] = opw[tid];
  if (tid < 48) s_fob[tid] = fob[tid];
  const int b = blockIdx.x >> 8;
  const int tile = blockIdx.x & 255;
  const int ty0 = (tile >> 4) << 4, tx0 = (tile & 15) << 4;
  const int py = tid >> 4, px = tid & 15;
  const int hp = (py + 1) * 18 + (px + 1);
  const int gn = ((ty0 + py) << 8) + (tx0 + px);
  const char* regb = region + (size_t)b * REGPB;

  float4 pf[4];
  auto prefetch = [&](int cb) {
#pragma unroll
    for (int r = 0; r < 4; ++r) {
      const int i = tid + (r << 8);
      float4 z = {0.f, 0.f, 0.f, 0.f}; pf[r] = z;
      if (i < 972) {
        const int c4 = i / 324, p = i - c4 * 324;
        const int hy = p / 18, hx = p - hy * 18;
        const int gy = ty0 + hy - 1, gx = tx0 + hx - 1;
        if (((unsigned)gy < 256u) && ((unsigned)gx < 256u))
          pf[r] = *(const float4*)(regb + (size_t)gy * ROWB + (cb + c4) * 4096 + (gx << 4));
      }
    }
  };
  auto commit = [&]() {
#pragma unroll
    for (int r = 0; r < 4; ++r) {
      const int i = tid + (r << 8);
      if (i < 972) {
        const int c4 = i / 324, p = i - c4 * 324;
        F4U u; u.f4 = pf[r];
        const int pb = c4 << 2;
#pragma unroll
        for (int j = 0; j < 4; ++j) halo[(pb + j) * HSTRIDE + p] = u.u[j];
      }
    }
  };

  float facc[48];
#pragma unroll
  for (int o = 0; o < 48; ++o) facc[o] = 0.f;
  prefetch(0);
  for (int s = 0; s < 8; ++s) {
    __syncthreads(); commit(); __syncthreads();
    if (s < 7) prefetch(3 * (s + 1));
    const int offs[9] = {-19, -18, -17, -1, 0, 1, 17, 18, 19};
#pragma unroll
    for (int pp = 0; pp < 12; ++pp) {
      const int P = 24 * s + 2 * pp;
      const float* w0 = &s_dww2[P * 9];
      const float* w1 = w0 + 9;
      const unsigned int* hrow = &halo[pp * HSTRIDE + hp];
      float a = s_dwb2[P], b2 = s_dwb2[P + 1];
#pragma unroll
      for (int t = 0; t < 9; ++t) {
        const float2 f = uh2f(hrow[offs[t]]);
        a += w0[t] * f.x; b2 += w1[t] * f.y;
      }
      const float gate = a * b2;
      const float* fr = &fowT[(12 * s + pp) * 48];
#pragma unroll
      for (int o4 = 0; o4 < 12; ++o4) {
        const float4 m = *(const float4*)&fr[o4 * 4];
        facc[o4 * 4 + 0] += m.x * gate; facc[o4 * 4 + 1] += m.y * gate;
        facc[o4 * 4 + 2] += m.z * gate; facc[o4 * 4 + 3] += m.w * gate;
      }
    }
  }
  const float4 s0v = s0arr[(size_t)b * NPIX + gn];
  float r0 = s0v.x + opb[0];
  float r1 = s0v.y + opb[1];
  float r2 = s0v.z + opb[2];
#pragma unroll
  for (int o = 0; o < 48; ++o) {
    const float f = facc[o] + s_fob[o];
    r0 += s_opw[o] * f; r1 += s_opw[48 + o] * f; r2 += s_opw[96 + o] * f;
  }
  out[((size_t)b * 3 + 0) * NPIX + gn] = r0;
  out[((size_t)b * 3 + 1) * NPIX + gn] = r1;
  out[((size_t)b * 3 + 2) * NPIX + gn] = r2;
}

extern "C" void kernel_launch(void* const* d_in, const int* in_sizes, int n_in,
                              void* d_out, int out_size, void* d_ws, size_t ws_size,
                              hipStream_t stream) {
  const float* x    = (const float*)d_in[0];
  const float* ipw  = (const float*)d_in[1];
  const float* ipb  = (const float*)d_in[2];
  const float* ln1w = (const float*)d_in[3];
  const float* ln1b = (const float*)d_in[4];
  const float* qw   = (const float*)d_in[5];
  const float* qb   = (const float*)d_in[6];
  const float* qdww = (const float*)d_in[7];
  const float* qdwb = (const float*)d_in[8];
  const float* temp = (const float*)d_in[9];
  const float* aow  = (const float*)d_in[10];
  const float* aob  = (const float*)d_in[11];
  const float* ln2w = (const float*)d_in[12];
  const float* ln2b = (const float*)d_in[13];
  const float* fiw  = (const float*)d_in[14];
  const float* fib  = (const float*)d_in[15];
  const float* fdww = (const float*)d_in[16];
  const float* fdwb = (const float*)d_in[17];
  const float* fow  = (const float*)d_in[18];
  const float* fob  = (const float*)d_in[19];
  const float* opw  = (const float*)d_in[20];
  const float* opb  = (const float*)d_in[21];

  const size_t s0Per = (size_t)NPIX * 16;
  int bc = 8;
  while (bc > 1 &&
         (size_t)bc * (REGPB + s0Per) + (5376 + 18432) * 4 > ws_size)
    bc >>= 1;
  char* region = (char*)d_ws;
  float4* s0arr = (float4*)(region + (size_t)bc * REGPB);
  float* red = (float*)((char*)s0arr + (size_t)bc * s0Per);
  float* Mws = red + 5376;
  hipMemsetAsync(red, 0, 5376 * sizeof(float), stream);
  for (int b0 = 0; b0 < 8; b0 += bc) {
    kA3<<<bc * 256, 256, 0, stream>>>(x + (size_t)b0 * 3 * NPIX, ipw, ipb,
                                      ln1w, ln1b, qw, qb, qdww, qdwb,
                                      region, red + b0 * 672);
    k3_attn<<<bc, 256, 0, stream>>>(red + b0 * 672, temp, aow,
                                    Mws + (size_t)b0 * 2304);
    k4a<<<bc * 256, 256, 0, stream>>>(region, s0arr, x + (size_t)b0 * 3 * NPIX,
                                      ipw, ipb, Mws + (size_t)b0 * 2304, aob,
                                      ln2w, ln2b, fiw, fib, opw);
    k5b<<<bc * 256, 256, 0, stream>>>(region, s0arr, fdww, fdwb, fow, fob,
                                      opw, opb,
                                      (float*)d_out + (size_t)b0 * 3 * NPIX);
  }
}

// Round 12
// 1020.419 us; speedup vs baseline: 2.6322x; 1.0314x over previous
//
#include <hip/hip_runtime.h>
#include <hip/hip_fp16.h>

// CAPTNet block. B=8, CIN=3, H=W=256, DIM=48, HEADS=4 (ch=12), HID=96.
// Round 12: identical to round 11 except kA3 __launch_bounds__(256,3)->(256,2).
// r11's (256,3) capped VGPR at 84 and spilled tA/tB/a0/a1 to scratch
// (FETCH 281MB + WRITE 473MB of spill traffic = the whole 515us). (256,2)
// lifts the cap to 256 VGPRs -> no spill, 2 blocks/CU (r10's spill-free
// occupancy) with r11's recompute-free conv.
// region layout (r7): (b*256+gy)*98304 + chunk*4096 + gx*16, 24 chunks.
//   chunks 18..23: vdw fp16 (kA3 -> k4a); k4a writes y fp16 chunks 0..23.
// s0 (3 fp32) separate float4/pixel array (k4a -> k5b).

#define NPIX 65536
#define ROWB 98304        // bytes per (batch,row): 24 chunks * 4096
#define REGPB 25165824ull // bytes per batch in region
#define HSTRIDE 332       // k4a/k5b halo LDS row stride (half2 elems) [r7]
#define HA 324            // kA3 halo LDS row stride (u32/half2 elems)
#define KQ 260            // kA3 q/k fp16 LDS row stride (u32), 16B-aligned

union F4U { float4 f4; unsigned int u[4]; };

__device__ __forceinline__ float2 uh2f(unsigned int u) {
  __half2 h; *(unsigned int*)&h = u; return __half22float2(h);
}
__device__ __forceinline__ unsigned int fpack(float a, float b) {
  __half2 h = __halves2half2(__float2half_rn(a), __float2half_rn(b));
  return *(unsigned int*)&h;
}

// ================= kA3: in_proj+LN1+qkv conv+dwconv+Gram+v =================
__global__ __launch_bounds__(256, 2) void kA3(
    const float* __restrict__ x, const float* __restrict__ ipw,
    const float* __restrict__ ipb, const float* __restrict__ lnw,
    const float* __restrict__ lnb, const float* __restrict__ qw,
    const float* __restrict__ qb, const float* __restrict__ dww,
    const float* __restrict__ dwb, char* __restrict__ region,
    float* __restrict__ red) {
  __shared__ unsigned int um[12 * HA];          // conv out 24ch fp16 pairs
  __shared__ unsigned int qsm[12 * KQ];         // q dwconv fp16 pairs (center)
  __shared__ unsigned int ksm[12 * KQ];         // k dwconv fp16 pairs
  __shared__ __align__(16) float wg[48 * 24];   // group conv w fp32 [c][o]
  __shared__ float qbf[24];
  __shared__ float s_dww[1296], s_dwb[144];
  __shared__ float s_ipw[144], s_ipb[48], s_lnw[48], s_lnb[48];
  const int tid = threadIdx.x;
  for (int i = tid; i < 1296; i += 256) s_dww[i] = dww[i];
  if (tid < 144) { s_dwb[tid] = dwb[tid]; s_ipw[tid] = ipw[tid]; }
  if (tid < 48) { s_ipb[tid] = ipb[tid]; s_lnw[tid] = lnw[tid]; s_lnb[tid] = lnb[tid]; }
  const int b = blockIdx.x >> 8;
  const int tile = blockIdx.x & 255;
  const int ty0 = (tile >> 4) << 4, tx0 = (tile & 15) << 4;
  const int py = tid >> 4, px = tid & 15;
  const int hp = (py + 1) * 18 + (px + 1);
  char* regb = region + (size_t)b * REGPB;
  const int offs[9] = {-19, -18, -17, -1, 0, 1, 17, 18, 19};

  // two halo pixels per thread
  const int p0 = tid, p1 = tid + 256;
  const int h0y = p0 / 18, h0x = p0 - h0y * 18;
  const int g0y = ty0 + h0y - 1, g0x = tx0 + h0x - 1;
  const bool ok0 = ((unsigned)g0y < 256u) && ((unsigned)g0x < 256u);
  const bool has1 = (p1 < 324);
  const int h1y = has1 ? p1 / 18 : 0, h1x = has1 ? p1 - h1y * 18 : 0;
  const int g1y = ty0 + h1y - 1, g1x = tx0 + h1x - 1;
  const bool ok1 = has1 && ((unsigned)g1y < 256u) && ((unsigned)g1x < 256u);
  float xA0 = 0.f, xA1 = 0.f, xA2 = 0.f, xB0 = 0.f, xB1 = 0.f, xB2 = 0.f;
  if (ok0) {
    const int gn = (g0y << 8) + g0x;
    xA0 = x[((size_t)b * 3 + 0) * NPIX + gn];
    xA1 = x[((size_t)b * 3 + 1) * NPIX + gn];
    xA2 = x[((size_t)b * 3 + 2) * NPIX + gn];
  }
  if (ok1) {
    const int gn = (g1y << 8) + g1x;
    xB0 = x[((size_t)b * 3 + 0) * NPIX + gn];
    xB1 = x[((size_t)b * 3 + 1) * NPIX + gn];
    xB2 = x[((size_t)b * 3 + 2) * NPIX + gn];
  }
  __syncthreads();   // shared params ready

  // t = LN1(in_proj(x)) computed ONCE per pixel, packed fp16 in registers
  unsigned int tA[24], tB[24];
  {
    float xn[48];
    float mu = 0.f;
#pragma unroll
    for (int c = 0; c < 48; ++c) {
      xn[c] = s_ipw[3*c]*xA0 + s_ipw[3*c+1]*xA1 + s_ipw[3*c+2]*xA2 + s_ipb[c];
      mu += xn[c];
    }
    mu *= (1.f / 48.f);
    float var = 0.f;
#pragma unroll
    for (int c = 0; c < 48; ++c) { const float d = xn[c] - mu; var += d * d; }
    float rs = rsqrtf(var * (1.f / 48.f) + 1e-6f);
#pragma unroll
    for (int c2 = 0; c2 < 24; ++c2)
      tA[c2] = fpack((xn[2*c2]   - mu) * rs * s_lnw[2*c2]   + s_lnb[2*c2],
                     (xn[2*c2+1] - mu) * rs * s_lnw[2*c2+1] + s_lnb[2*c2+1]);
    mu = 0.f;
#pragma unroll
    for (int c = 0; c < 48; ++c) {
      xn[c] = s_ipw[3*c]*xB0 + s_ipw[3*c+1]*xB1 + s_ipw[3*c+2]*xB2 + s_ipb[c];
      mu += xn[c];
    }
    mu *= (1.f / 48.f);
    var = 0.f;
#pragma unroll
    for (int c = 0; c < 48; ++c) { const float d = xn[c] - mu; var += d * d; }
    rs = rsqrtf(var * (1.f / 48.f) + 1e-6f);
#pragma unroll
    for (int c2 = 0; c2 < 24; ++c2)
      tB[c2] = fpack((xn[2*c2]   - mu) * rs * s_lnw[2*c2]   + s_lnb[2*c2],
                     (xn[2*c2+1] - mu) * rs * s_lnw[2*c2+1] + s_lnb[2*c2+1]);
  }

  auto loadwg = [&](int cb) {   // cb = qkv output channel base (24 ch)
    for (int i = tid; i < 1152; i += 256) {
      const int c = i / 24, o = i - (i / 24) * 24;
      wg[c * 24 + o] = qw[(cb + o) * 48 + c];
    }
    if (tid < 24) qbf[tid] = qb[cb + tid];
  };
  auto convPhase = [&]() {   // conv 48->24, both pixels share weight reads
    float a0[24], a1[24];
#pragma unroll
    for (int j = 0; j < 24; ++j) { a0[j] = qbf[j]; a1[j] = qbf[j]; }
#pragma unroll 4
    for (int c2 = 0; c2 < 24; ++c2) {
      const float2 t0 = uh2f(tA[c2]);
      const float2 t1 = uh2f(tB[c2]);
      const float* w0 = &wg[(2 * c2) * 24];
      const float* w1 = &wg[(2 * c2 + 1) * 24];
#pragma unroll
      for (int o4 = 0; o4 < 6; ++o4) {
        const float4 wa = *(const float4*)&w0[4 * o4];
        const float4 wb = *(const float4*)&w1[4 * o4];
        a0[4*o4+0] += wa.x * t0.x + wb.x * t0.y;
        a0[4*o4+1] += wa.y * t0.x + wb.y * t0.y;
        a0[4*o4+2] += wa.z * t0.x + wb.z * t0.y;
        a0[4*o4+3] += wa.w * t0.x + wb.w * t0.y;
        a1[4*o4+0] += wa.x * t1.x + wb.x * t1.y;
        a1[4*o4+1] += wa.y * t1.x + wb.y * t1.y;
        a1[4*o4+2] += wa.z * t1.x + wb.z * t1.y;
        a1[4*o4+3] += wa.w * t1.x + wb.w * t1.y;
      }
    }
#pragma unroll
    for (int j = 0; j < 12; ++j)
      um[j * HA + p0] = ok0 ? fpack(a0[2 * j], a0[2 * j + 1]) : 0u;
    if (has1) {
#pragma unroll
      for (int j = 0; j < 12; ++j)
        um[j * HA + p1] = ok1 ? fpack(a1[2 * j], a1[2 * j + 1]) : 0u;
    }
  };
  auto dwqk = [&](int cb, unsigned int* dst) {   // dwconv 24ch -> fp16 pairs
#pragma unroll
    for (int j = 0; j < 12; ++j) {
      float a = s_dwb[cb + 2 * j], bb = s_dwb[cb + 2 * j + 1];
      const unsigned int* hrow = &um[j * HA + hp];
      const float* w0 = &s_dww[(cb + 2 * j) * 9];
      const float* w1 = w0 + 9;
#pragma unroll
      for (int t = 0; t < 9; ++t) {
        const float2 f = uh2f(hrow[offs[t]]);
        a += w0[t] * f.x; bb += w1[t] * f.y;
      }
      dst[j * KQ + tid] = fpack(a, bb);
    }
  };
  auto dwv = [&](int cb, int chunk0) {   // dwconv v 24ch -> fp16 chunks
    unsigned int vp[12];
#pragma unroll
    for (int j = 0; j < 12; ++j) {
      float a = s_dwb[cb + 2 * j], bb = s_dwb[cb + 2 * j + 1];
      const unsigned int* hrow = &um[j * HA + hp];
      const float* w0 = &s_dww[(cb + 2 * j) * 9];
      const float* w1 = w0 + 9;
#pragma unroll
      for (int t = 0; t < 9; ++t) {
        const float2 f = uh2f(hrow[offs[t]]);
        a += w0[t] * f.x; bb += w1[t] * f.y;
      }
      vp[j] = fpack(a, bb);
    }
    char* vrow = regb + (size_t)(ty0 + py) * ROWB + ((tx0 + px) << 4);
#pragma unroll
    for (int q = 0; q < 3; ++q) {
      F4U u;
      u.u[0] = vp[4 * q]; u.u[1] = vp[4 * q + 1];
      u.u[2] = vp[4 * q + 2]; u.u[3] = vp[4 * q + 3];
      *(float4*)(vrow + (chunk0 + q) * 4096) = u.f4;
    }
  };
  auto gram2 = [&](int hbase) {   // 2 heads from fp16 qsm/ksm [r7 verbatim]
    for (int e = tid; e < 336; e += 256) {
      const int hh = e / 168, r2 = e - hh * 168;
      float s = 0.f;
      if (r2 < 144) {
        const int c = r2 / 12, d = r2 - (r2 / 12) * 12;
        const int qc = 12 * hh + c, kd = 12 * hh + d;
        const unsigned int* qr = &qsm[(qc >> 1) * KQ];
        const unsigned int* kr = &ksm[(kd >> 1) * KQ];
        const int q1 = qc & 1, k1 = kd & 1;
        for (int p = 0; p < 256; ++p) {
          const float2 fq = uh2f(qr[p]); const float2 fk = uh2f(kr[p]);
          s += (q1 ? fq.y : fq.x) * (k1 ? fk.y : fk.x);
        }
      } else if (r2 < 156) {
        const int qc = 12 * hh + (r2 - 144);
        const unsigned int* qr = &qsm[(qc >> 1) * KQ];
        const int q1 = qc & 1;
        for (int p = 0; p < 256; ++p) {
          const float2 fq = uh2f(qr[p]);
          const float v = q1 ? fq.y : fq.x;
          s += v * v;
        }
      } else {
        const int kd = 12 * hh + (r2 - 156);
        const unsigned int* kr = &ksm[(kd >> 1) * KQ];
        const int k1 = kd & 1;
        for (int p = 0; p < 256; ++p) {
          const float2 fk = uh2f(kr[p]);
          const float v = k1 ? fk.y : fk.x;
          s += v * v;
        }
      }
      atomicAdd(&red[b * 672 + (hbase + hh) * 168 + r2], s);
    }
  };

  loadwg(0);   __syncthreads(); convPhase(); __syncthreads(); dwqk(0, qsm);
  loadwg(48);  __syncthreads(); convPhase(); __syncthreads(); dwqk(48, ksm);
  __syncthreads(); gram2(0);
  loadwg(24);  __syncthreads(); convPhase(); __syncthreads(); dwqk(24, qsm);
  loadwg(72);  __syncthreads(); convPhase(); __syncthreads(); dwqk(72, ksm);
  __syncthreads(); gram2(2);
  loadwg(96);  __syncthreads(); convPhase(); __syncthreads(); dwv(96, 18);
  loadwg(120); __syncthreads(); convPhase(); __syncthreads(); dwv(120, 21);
}

// ================= k3: finalize attn, build fused M [r10 verbatim] ==========
__global__ __launch_bounds__(256) void k3_attn(const float* __restrict__ red,
                                               const float* __restrict__ temp,
                                               const float* __restrict__ aow,
                                               float* __restrict__ Mws) {
  __shared__ float attn[4 * 144];
  const int b = blockIdx.x, tid = threadIdx.x;
  const float* rb = red + b * 672;
  for (int e = tid; e < 576; e += 256) {
    const int h = e / 144, r = e - h * 144;
    const int c = r / 12, d = r - c * 12;
    const float g = rb[h * 168 + r];
    const float nq = fmaxf(sqrtf(rb[h * 168 + 144 + c]), 1e-12f);
    const float nk = fmaxf(sqrtf(rb[h * 168 + 156 + d]), 1e-12f);
    attn[e] = g / (nq * nk) * temp[h];
  }
  __syncthreads();
  if (tid < 48) {
    const int h = tid / 12, c = tid - h * 12;
    float* row = &attn[h * 144 + c * 12];
    float m = row[0];
    for (int d = 1; d < 12; ++d) m = fmaxf(m, row[d]);
    float s = 0.f;
    for (int d = 0; d < 12; ++d) { const float e2 = expf(row[d] - m); row[d] = e2; s += e2; }
    const float inv = 1.f / s;
    for (int d = 0; d < 12; ++d) row[d] *= inv;
  }
  __syncthreads();
  for (int e = tid; e < 2304; e += 256) {
    const int o = e / 48, j = e - o * 48;
    const int h = j / 12, d = j - h * 12;
    float s = 0.f;
    for (int c = 0; c < 12; ++c)
      s += aow[o * 48 + h * 12 + c] * attn[h * 144 + c * 12 + d];
    Mws[b * 2304 + e] = s;
  }
}

// ========== k4a: recompute in_proj, attn-out, LN2, ffn_in [r10 verbatim] ====
__global__ __launch_bounds__(256, 3) void k4a(
    char* __restrict__ region, float4* __restrict__ s0arr,
    const float* __restrict__ x, const float* __restrict__ ipw,
    const float* __restrict__ ipb, const float* __restrict__ Mws,
    const float* __restrict__ aob, const float* __restrict__ lnw,
    const float* __restrict__ lnb, const float* __restrict__ fiw,
    const float* __restrict__ fib, const float* __restrict__ opw) {
  __shared__ __align__(16) float MT[48 * 48];     // MT[j][o]
  __shared__ __align__(16) float wT2[48 * 192];   // wT2[c][pos], pos interleaved
  __shared__ float s_aob[48], s_lnw[48], s_lnb[48], s_fib2[192], s_opw[144];
  __shared__ float s_ipw[144], s_ipb[48];
  const int tid = threadIdx.x;
  const int b = blockIdx.x >> 8;
  const int gy = blockIdx.x & 255;
  const int n = (gy << 8) + tid;
  for (int i = tid; i < 2304; i += 256) {
    const int o = i / 48, j = i - o * 48;
    MT[j * 48 + o] = Mws[b * 2304 + i];
  }
  for (int i = tid; i < 9216; i += 256) {
    const int c = i / 192, pos = i - c * 192;
    const int ch = (pos & 1) ? 96 + (pos >> 1) : (pos >> 1);
    wT2[i] = fiw[ch * 48 + c];
  }
  if (tid < 192) {
    const int ch = (tid & 1) ? 96 + (tid >> 1) : (tid >> 1);
    s_fib2[tid] = fib[ch];
  }
  if (tid < 144) { s_opw[tid] = opw[tid]; s_ipw[tid] = ipw[tid]; }
  if (tid < 48) {
    s_aob[tid] = aob[tid]; s_lnw[tid] = lnw[tid]; s_lnb[tid] = lnb[tid];
    s_ipb[tid] = ipb[tid];
  }
  __syncthreads();
  char* rowp = region + (size_t)((b << 8) + gy) * ROWB + (tid << 4);
  float vv[48];
#pragma unroll
  for (int q = 0; q < 6; ++q) {
    F4U u; u.f4 = *(const float4*)(rowp + (18 + q) * 4096);
#pragma unroll
    for (int j = 0; j < 4; ++j) {
      const float2 f = uh2f(u.u[j]);
      vv[8 * q + 2 * j] = f.x; vv[8 * q + 2 * j + 1] = f.y;
    }
  }
  float y[48];
#pragma unroll
  for (int o = 0; o < 48; ++o) y[o] = s_aob[o];
#pragma unroll 4
  for (int j = 0; j < 48; ++j) {
    const float vj = vv[j];
    const float* mr = &MT[j * 48];
#pragma unroll
    for (int o4 = 0; o4 < 12; ++o4) {
      const float4 m = *(const float4*)&mr[o4 * 4];
      y[o4 * 4 + 0] += m.x * vj; y[o4 * 4 + 1] += m.y * vj;
      y[o4 * 4 + 2] += m.z * vj; y[o4 * 4 + 3] += m.w * vj;
    }
  }
  // recompute in_proj (xp) and add residual
  const float x0 = x[((size_t)b * 3 + 0) * NPIX + n];
  const float x1 = x[((size_t)b * 3 + 1) * NPIX + n];
  const float x2 = x[((size_t)b * 3 + 2) * NPIX + n];
  float mu = 0.f;
#pragma unroll
  for (int c = 0; c < 48; ++c) {
    y[c] += s_ipw[c * 3] * x0 + s_ipw[c * 3 + 1] * x1 + s_ipw[c * 3 + 2] * x2 + s_ipb[c];
    mu += y[c];
  }
  float s0 = 0.f, s1 = 0.f, s2 = 0.f;
#pragma unroll
  for (int c = 0; c < 48; ++c) {
    s0 += s_opw[c] * y[c]; s1 += s_opw[48 + c] * y[c]; s2 += s_opw[96 + c] * y[c];
  }
  float4 s0v; s0v.x = s0; s0v.y = s1; s0v.z = s2; s0v.w = 0.f;
  s0arr[(size_t)b * NPIX + n] = s0v;
  mu *= (1.f / 48.f);
  float var = 0.f;
#pragma unroll
  for (int c = 0; c < 48; ++c) { const float d = y[c] - mu; var += d * d; }
  const float rs2 = rsqrtf(var * (1.f / 48.f) + 1e-6f);
#pragma unroll
  for (int c = 0; c < 48; ++c) y[c] = (y[c] - mu) * rs2 * s_lnw[c] + s_lnb[c];
#pragma unroll
  for (int ob = 0; ob < 12; ++ob) {
    const int o0 = ob * 16;
    float acc[16];
#pragma unroll
    for (int j = 0; j < 16; ++j) acc[j] = s_fib2[o0 + j];
#pragma unroll 4
    for (int c = 0; c < 48; ++c) {
      const float xv = y[c];
      const float4 w0 = *(const float4*)&wT2[c * 192 + o0];
      const float4 w1 = *(const float4*)&wT2[c * 192 + o0 + 4];
      const float4 w2 = *(const float4*)&wT2[c * 192 + o0 + 8];
      const float4 w3 = *(const float4*)&wT2[c * 192 + o0 + 12];
      acc[0] += w0.x * xv; acc[1] += w0.y * xv; acc[2] += w0.z * xv; acc[3] += w0.w * xv;
      acc[4] += w1.x * xv; acc[5] += w1.y * xv; acc[6] += w1.z * xv; acc[7] += w1.w * xv;
      acc[8] += w2.x * xv; acc[9] += w2.y * xv; acc[10] += w2.z * xv; acc[11] += w2.w * xv;
      acc[12] += w3.x * xv; acc[13] += w3.y * xv; acc[14] += w3.z * xv; acc[15] += w3.w * xv;
    }
    F4U u;
    u.u[0] = fpack(acc[0], acc[1]);   u.u[1] = fpack(acc[2], acc[3]);
    u.u[2] = fpack(acc[4], acc[5]);   u.u[3] = fpack(acc[6], acc[7]);
    *(float4*)(rowp + (2 * ob) * 4096) = u.f4;
    u.u[0] = fpack(acc[8], acc[9]);   u.u[1] = fpack(acc[10], acc[11]);
    u.u[2] = fpack(acc[12], acc[13]); u.u[3] = fpack(acc[14], acc[15]);
    *(float4*)(rowp + (2 * ob + 1) * 4096) = u.f4;
  }
}

// ====== k5b: dw + SimpleGate + ffn_out + out_proj [r10 verbatim] ============
__global__ __launch_bounds__(256, 3) void k5b(
    const char* __restrict__ region, const float4* __restrict__ s0arr,
    const float* __restrict__ fdww, const float* __restrict__ fdwb,
    const float* __restrict__ fow, const float* __restrict__ fob,
    const float* __restrict__ opw, const float* __restrict__ opb,
    float* __restrict__ out) {
  __shared__ unsigned int halo[12 * HSTRIDE];
  __shared__ __align__(16) float fowT[96 * 48];   // fowT[c1][o] = fow[o][c1]
  __shared__ float s_dww2[1728], s_dwb2[192], s_opw[144], s_fob[48];
  const int tid = threadIdx.x;
  for (int i = tid; i < 4608; i += 256) {
    const int c = i / 48, o = i - c * 48;
    fowT[i] = fow[o * 96 + c];
  }
  for (int i = tid; i < 1728; i += 256) {
    const int P = i / 9, t = i - P * 9;
    const int ch = (P & 1) ? 96 + (P >> 1) : (P >> 1);
    s_dww2[i] = fdww[ch * 9 + t];
  }
  if (tid < 192) {
    const int ch = (tid & 1) ? 96 + (tid >> 1) : (tid >> 1);
    s_dwb2[tid] = fdwb[ch];
  }
  if (tid < 144) s_opw[tid] = opw[tid];
  if (tid < 48) s_fob[tid] = fob[tid];
  const int b = blockIdx.x >> 8;
  const int tile = blockIdx.x & 255;
  const int ty0 = (tile >> 4) << 4, tx0 = (tile & 15) << 4;
  const int py = tid >> 4, px = tid & 15;
  const int hp = (py + 1) * 18 + (px + 1);
  const int gn = ((ty0 + py) << 8) + (tx0 + px);
  const char* regb = region + (size_t)b * REGPB;

  float4 pf[4];
  auto prefetch = [&](int cb) {
#pragma unroll
    for (int r = 0; r < 4; ++r) {
      const int i = tid + (r << 8);
      float4 z = {0.f, 0.f, 0.f, 0.f}; pf[r] = z;
      if (i < 972) {
        const int c4 = i / 324, p = i - c4 * 324;
        const int hy = p / 18, hx = p - hy * 18;
        const int gy = ty0 + hy - 1, gx = tx0 + hx - 1;
        if (((unsigned)gy < 256u) && ((unsigned)gx < 256u))
          pf[r] = *(const float4*)(regb + (size_t)gy * ROWB + (cb + c4) * 4096 + (gx << 4));
      }
    }
  };
  auto commit = [&]() {
#pragma unroll
    for (int r = 0; r < 4; ++r) {
      const int i = tid + (r << 8);
      if (i < 972) {
        const int c4 = i / 324, p = i - c4 * 324;
        F4U u; u.f4 = pf[r];
        const int pb = c4 << 2;
#pragma unroll
        for (int j = 0; j < 4; ++j) halo[(pb + j) * HSTRIDE + p] = u.u[j];
      }
    }
  };

  float facc[48];
#pragma unroll
  for (int o = 0; o < 48; ++o) facc[o] = 0.f;
  prefetch(0);
  for (int s = 0; s < 8; ++s) {
    __syncthreads(); commit(); __syncthreads();
    if (s < 7) prefetch(3 * (s + 1));
    const int offs[9] = {-19, -18, -17, -1, 0, 1, 17, 18, 19};
#pragma unroll
    for (int pp = 0; pp < 12; ++pp) {
      const int P = 24 * s + 2 * pp;
      const float* w0 = &s_dww2[P * 9];
      const float* w1 = w0 + 9;
      const unsigned int* hrow = &halo[pp * HSTRIDE + hp];
      float a = s_dwb2[P], b2 = s_dwb2[P + 1];
#pragma unroll
      for (int t = 0; t < 9; ++t) {
        const float2 f = uh2f(hrow[offs[t]]);
        a += w0[t] * f.x; b2 += w1[t] * f.y;
      }
      const float gate = a * b2;
      const float* fr = &fowT[(12 * s + pp) * 48];
#pragma unroll
      for (int o4 = 0; o4 < 12; ++o4) {
        const float4 m = *(const float4*)&fr[o4 * 4];
        facc[o4 * 4 + 0] += m.x * gate; facc[o4 * 4 + 1] += m.y * gate;
        facc[o4 * 4 + 2] += m.z * gate; facc[o4 * 4 + 3] += m.w * gate;
      }
    }
  }
  const float4 s0v = s0arr[(size_t)b * NPIX + gn];
  float r0 = s0v.x + opb[0];
  float r1 = s0v.y + opb[1];
  float r2 = s0v.z + opb[2];
#pragma unroll
  for (int o = 0; o < 48; ++o) {
    const float f = facc[o] + s_fob[o];
    r0 += s_opw[o] * f; r1 += s_opw[48 + o] * f; r2 += s_opw[96 + o] * f;
  }
  out[((size_t)b * 3 + 0) * NPIX + gn] = r0;
  out[((size_t)b * 3 + 1) * NPIX + gn] = r1;
  out[((size_t)b * 3 + 2) * NPIX + gn] = r2;
}

extern "C" void kernel_launch(void* const* d_in, const int* in_sizes, int n_in,
                              void* d_out, int out_size, void* d_ws, size_t ws_size,
                              hipStream_t stream) {
  const float* x    = (const float*)d_in[0];
  const float* ipw  = (const float*)d_in[1];
  const float* ipb  = (const float*)d_in[2];
  const float* ln1w = (const float*)d_in[3];
  const float* ln1b = (const float*)d_in[4];
  const float* qw   = (const float*)d_in[5];
  const float* qb   = (const float*)d_in[6];
  const float* qdww = (const float*)d_in[7];
  const float* qdwb = (const float*)d_in[8];
  const float* temp = (const float*)d_in[9];
  const float* aow  = (const float*)d_in[10];
  const float* aob  = (const float*)d_in[11];
  const float* ln2w = (const float*)d_in[12];
  const float* ln2b = (const float*)d_in[13];
  const float* fiw  = (const float*)d_in[14];
  const float* fib  = (const float*)d_in[15];
  const float* fdww = (const float*)d_in[16];
  const float* fdwb = (const float*)d_in[17];
  const float* fow  = (const float*)d_in[18];
  const float* fob  = (const float*)d_in[19];
  const float* opw  = (const float*)d_in[20];
  const float* opb  = (const float*)d_in[21];

  const size_t s0Per = (size_t)NPIX * 16;
  int bc = 8;
  while (bc > 1 &&
         (size_t)bc * (REGPB + s0Per) + (5376 + 18432) * 4 > ws_size)
    bc >>= 1;
  char* region = (char*)d_ws;
  float4* s0arr = (float4*)(region + (size_t)bc * REGPB);
  float* red = (float*)((char*)s0arr + (size_t)bc * s0Per);
  float* Mws = red + 5376;
  hipMemsetAsync(red, 0, 5376 * sizeof(float), stream);
  for (int b0 = 0; b0 < 8; b0 += bc) {
    kA3<<<bc * 256, 256, 0, stream>>>(x + (size_t)b0 * 3 * NPIX, ipw, ipb,
                                      ln1w, ln1b, qw, qb, qdww, qdwb,
                                      region, red + b0 * 672);
    k3_attn<<<bc, 256, 0, stream>>>(red + b0 * 672, temp, aow,
                                    Mws + (size_t)b0 * 2304);
    k4a<<<bc * 256, 256, 0, stream>>>(region, s0arr, x + (size_t)b0 * 3 * NPIX,
                                      ipw, ipb, Mws + (size_t)b0 * 2304, aob,
                                      ln2w, ln2b, fiw, fib, opw);
    k5b<<<bc * 256, 256, 0, stream>>>(region, s0arr, fdww, fdwb, fow, fob,
                                      opw, opb,
                                      (float*)d_out + (size_t)b0 * 3 * NPIX);
  }
}

// Round 13
// 997.944 us; speedup vs baseline: 2.6914x; 1.0225x over previous
//
#include <hip/hip_runtime.h>
#include <hip/hip_fp16.h>

// CAPTNet block. B=8, CIN=3, H=W=256, DIM=48, HEADS=4 (ch=12), HID=96.
// Round 13: kA3 -> kA4: (1) qkv conv via v_dot2_f32_f16 on packed half2
// activations x packed half2 weights (halves conv VALU + LDS reads);
// (2) LN1 output t stored in LDS (not regs) -> ~70 live VGPRs, no spill.
// k3/k4a/k5b verbatim r12 (passing, absmax 4.88e-4).
// region layout (r7): (b*256+gy)*98304 + chunk*4096 + gx*16, 24 chunks.
//   chunks 18..23: vdw fp16 (kA4 -> k4a); k4a writes y fp16 chunks 0..23.
// s0 (3 fp32) separate float4/pixel array (k4a -> k5b).

#define NPIX 65536
#define ROWB 98304        // bytes per (batch,row): 24 chunks * 4096
#define REGPB 25165824ull // bytes per batch in region
#define HSTRIDE 332       // k4a/k5b halo LDS row stride (half2 elems) [r7]
#define HA 324            // kA4 halo LDS row stride (u32/half2 elems)
#define KQ 258            // kA4 q/k fp16 LDS row stride (u32)

union F4U { float4 f4; unsigned int u[4]; };

typedef _Float16 h2f __attribute__((ext_vector_type(2)));
union U32H2 { unsigned int u; h2f h; };

__device__ __forceinline__ float2 uh2f(unsigned int u) {
  __half2 h; *(unsigned int*)&h = u; return __half22float2(h);
}
__device__ __forceinline__ unsigned int fpack(float a, float b) {
  __half2 h = __halves2half2(__float2half_rn(a), __float2half_rn(b));
  return *(unsigned int*)&h;
}
__device__ __forceinline__ float fdot2u(unsigned int a, unsigned int b, float c) {
  U32H2 ua, ub; ua.u = a; ub.u = b;
  return __builtin_amdgcn_fdot2(ua.h, ub.h, c, false);
}

// ================= kA4: in_proj+LN1+qkv conv(dot2)+dwconv+Gram+v ==========
__global__ __launch_bounds__(256, 2) void kA4(
    const float* __restrict__ x, const float* __restrict__ ipw,
    const float* __restrict__ ipb, const float* __restrict__ lnw,
    const float* __restrict__ lnb, const float* __restrict__ qw,
    const float* __restrict__ qb, const float* __restrict__ dww,
    const float* __restrict__ dwb, char* __restrict__ region,
    float* __restrict__ red) {
  __shared__ unsigned int th[24 * HA];          // LN1 out, ch pairs fp16
  __shared__ unsigned int um[12 * HA];          // conv out 24ch fp16 pairs
  __shared__ unsigned int qsm[12 * KQ];         // q dwconv fp16 pairs (center)
  __shared__ unsigned int ksm[12 * KQ];         // k dwconv fp16 pairs
  __shared__ __align__(16) unsigned int wgp[576];  // conv w fp16 pairs [c2][o]
  __shared__ float qbf[24];
  __shared__ float s_dww[1296], s_dwb[144];
  __shared__ float s_ipw[144], s_ipb[48], s_lnw[48], s_lnb[48];
  const int tid = threadIdx.x;
  for (int i = tid; i < 1296; i += 256) s_dww[i] = dww[i];
  if (tid < 144) { s_dwb[tid] = dwb[tid]; s_ipw[tid] = ipw[tid]; }
  if (tid < 48) { s_ipb[tid] = ipb[tid]; s_lnw[tid] = lnw[tid]; s_lnb[tid] = lnb[tid]; }
  const int b = blockIdx.x >> 8;
  const int tile = blockIdx.x & 255;
  const int ty0 = (tile >> 4) << 4, tx0 = (tile & 15) << 4;
  const int py = tid >> 4, px = tid & 15;
  const int hp = (py + 1) * 18 + (px + 1);
  char* regb = region + (size_t)b * REGPB;
  const int offs[9] = {-19, -18, -17, -1, 0, 1, 17, 18, 19};

  const int p0 = tid, p1 = tid + 256;
  const bool has1 = (p1 < 324);
  bool okA[2];
  __syncthreads();   // params visible before th staging uses them

  // stage th = LN1(in_proj(x)) at all 324 halo px (fp16 pairs in LDS)
  for (int r = 0; r < 2; ++r) {
    const int p = r ? p1 : p0;
    if (p >= 324) break;
    const int hy = p / 18, hx = p - hy * 18;
    const int gy = ty0 + hy - 1, gx = tx0 + hx - 1;
    const bool ok = ((unsigned)gy < 256u) && ((unsigned)gx < 256u);
    okA[r] = ok;
    const int gn = (gy << 8) + gx;
    float x0 = 0.f, x1 = 0.f, x2 = 0.f;
    if (ok) {
      x0 = x[((size_t)b * 3 + 0) * NPIX + gn];
      x1 = x[((size_t)b * 3 + 1) * NPIX + gn];
      x2 = x[((size_t)b * 3 + 2) * NPIX + gn];
    }
    float xn[48]; float mu = 0.f;
#pragma unroll
    for (int c = 0; c < 48; ++c) {
      xn[c] = s_ipw[3*c]*x0 + s_ipw[3*c+1]*x1 + s_ipw[3*c+2]*x2 + s_ipb[c];
      mu += xn[c];
    }
    mu *= (1.f / 48.f);
    float var = 0.f;
#pragma unroll
    for (int c = 0; c < 48; ++c) { const float d = xn[c] - mu; var += d * d; }
    const float rs = rsqrtf(var * (1.f / 48.f) + 1e-6f);
#pragma unroll
    for (int c2 = 0; c2 < 24; ++c2)
      th[c2 * HA + p] = fpack((xn[2*c2]   - mu) * rs * s_lnw[2*c2]   + s_lnb[2*c2],
                              (xn[2*c2+1] - mu) * rs * s_lnw[2*c2+1] + s_lnb[2*c2+1]);
  }
  const bool ok0 = okA[0];
  const bool ok1 = has1 && okA[1];
  __syncthreads();

  auto loadwg = [&](int cb) {   // pack conv weights: wgp[c2*24+o]=(w[o][2c2],w[o][2c2+1])
    for (int i = tid; i < 576; i += 256) {
      const int c2 = i / 24, o = i - c2 * 24;
      wgp[i] = fpack(qw[(cb + o) * 48 + 2 * c2], qw[(cb + o) * 48 + 2 * c2 + 1]);
    }
    if (tid < 24) qbf[tid] = qb[cb + tid];
  };
  auto convPhase = [&]() {   // conv 48->24 via dot2; both px share weight reads
    float a0[24], a1[24];
#pragma unroll
    for (int j = 0; j < 24; ++j) { a0[j] = qbf[j]; a1[j] = qbf[j]; }
#pragma unroll 4
    for (int c2 = 0; c2 < 24; ++c2) {
      const unsigned int t0 = th[c2 * HA + p0];
      const unsigned int t1 = has1 ? th[c2 * HA + p1] : 0u;
      const uint4* wr = (const uint4*)&wgp[c2 * 24];
#pragma unroll
      for (int k = 0; k < 6; ++k) {
        const uint4 w = wr[k];
        a0[4*k+0] = fdot2u(t0, w.x, a0[4*k+0]);
        a0[4*k+1] = fdot2u(t0, w.y, a0[4*k+1]);
        a0[4*k+2] = fdot2u(t0, w.z, a0[4*k+2]);
        a0[4*k+3] = fdot2u(t0, w.w, a0[4*k+3]);
        a1[4*k+0] = fdot2u(t1, w.x, a1[4*k+0]);
        a1[4*k+1] = fdot2u(t1, w.y, a1[4*k+1]);
        a1[4*k+2] = fdot2u(t1, w.z, a1[4*k+2]);
        a1[4*k+3] = fdot2u(t1, w.w, a1[4*k+3]);
      }
    }
#pragma unroll
    for (int j = 0; j < 12; ++j)
      um[j * HA + p0] = ok0 ? fpack(a0[2 * j], a0[2 * j + 1]) : 0u;
    if (has1) {
#pragma unroll
      for (int j = 0; j < 12; ++j)
        um[j * HA + p1] = ok1 ? fpack(a1[2 * j], a1[2 * j + 1]) : 0u;
    }
  };
  auto dwqk = [&](int cb, unsigned int* dst) {   // dwconv 24ch -> fp16 pairs
#pragma unroll
    for (int j = 0; j < 12; ++j) {
      float a = s_dwb[cb + 2 * j], bb = s_dwb[cb + 2 * j + 1];
      const unsigned int* hrow = &um[j * HA + hp];
      const float* w0 = &s_dww[(cb + 2 * j) * 9];
      const float* w1 = w0 + 9;
#pragma unroll
      for (int t = 0; t < 9; ++t) {
        const float2 f = uh2f(hrow[offs[t]]);
        a += w0[t] * f.x; bb += w1[t] * f.y;
      }
      dst[j * KQ + tid] = fpack(a, bb);
    }
  };
  auto dwv = [&](int cb, int chunk0) {   // dwconv v 24ch -> fp16 chunks
    unsigned int vp[12];
#pragma unroll
    for (int j = 0; j < 12; ++j) {
      float a = s_dwb[cb + 2 * j], bb = s_dwb[cb + 2 * j + 1];
      const unsigned int* hrow = &um[j * HA + hp];
      const float* w0 = &s_dww[(cb + 2 * j) * 9];
      const float* w1 = w0 + 9;
#pragma unroll
      for (int t = 0; t < 9; ++t) {
        const float2 f = uh2f(hrow[offs[t]]);
        a += w0[t] * f.x; bb += w1[t] * f.y;
      }
      vp[j] = fpack(a, bb);
    }
    char* vrow = regb + (size_t)(ty0 + py) * ROWB + ((tx0 + px) << 4);
#pragma unroll
    for (int q = 0; q < 3; ++q) {
      F4U u;
      u.u[0] = vp[4 * q]; u.u[1] = vp[4 * q + 1];
      u.u[2] = vp[4 * q + 2]; u.u[3] = vp[4 * q + 3];
      *(float4*)(vrow + (chunk0 + q) * 4096) = u.f4;
    }
  };
  auto gram2 = [&](int hbase) {   // 2 heads from fp16 qsm/ksm [r7 verbatim]
    for (int e = tid; e < 336; e += 256) {
      const int hh = e / 168, r2 = e - hh * 168;
      float s = 0.f;
      if (r2 < 144) {
        const int c = r2 / 12, d = r2 - (r2 / 12) * 12;
        const int qc = 12 * hh + c, kd = 12 * hh + d;
        const unsigned int* qr = &qsm[(qc >> 1) * KQ];
        const unsigned int* kr = &ksm[(kd >> 1) * KQ];
        const int q1 = qc & 1, k1 = kd & 1;
        for (int p = 0; p < 256; ++p) {
          const float2 fq = uh2f(qr[p]); const float2 fk = uh2f(kr[p]);
          s += (q1 ? fq.y : fq.x) * (k1 ? fk.y : fk.x);
        }
      } else if (r2 < 156) {
        const int qc = 12 * hh + (r2 - 144);
        const unsigned int* qr = &qsm[(qc >> 1) * KQ];
        const int q1 = qc & 1;
        for (int p = 0; p < 256; ++p) {
          const float2 fq = uh2f(qr[p]);
          const float v = q1 ? fq.y : fq.x;
          s += v * v;
        }
      } else {
        const int kd = 12 * hh + (r2 - 156);
        const unsigned int* kr = &ksm[(kd >> 1) * KQ];
        const int k1 = kd & 1;
        for (int p = 0; p < 256; ++p) {
          const float2 fk = uh2f(kr[p]);
          const float v = k1 ? fk.y : fk.x;
          s += v * v;
        }
      }
      atomicAdd(&red[b * 672 + (hbase + hh) * 168 + r2], s);
    }
  };

  loadwg(0);   __syncthreads(); convPhase(); __syncthreads(); dwqk(0, qsm);
  loadwg(48);  __syncthreads(); convPhase(); __syncthreads(); dwqk(48, ksm);
  __syncthreads(); gram2(0);
  loadwg(24);  __syncthreads(); convPhase(); __syncthreads(); dwqk(24, qsm);
  loadwg(72);  __syncthreads(); convPhase(); __syncthreads(); dwqk(72, ksm);
  __syncthreads(); gram2(2);
  loadwg(96);  __syncthreads(); convPhase(); __syncthreads(); dwv(96, 18);
  loadwg(120); __syncthreads(); convPhase(); __syncthreads(); dwv(120, 21);
}

// ================= k3: finalize attn, build fused M [r12 verbatim] ==========
__global__ __launch_bounds__(256) void k3_attn(const float* __restrict__ red,
                                               const float* __restrict__ temp,
                                               const float* __restrict__ aow,
                                               float* __restrict__ Mws) {
  __shared__ float attn[4 * 144];
  const int b = blockIdx.x, tid = threadIdx.x;
  const float* rb = red + b * 672;
  for (int e = tid; e < 576; e += 256) {
    const int h = e / 144, r = e - h * 144;
    const int c = r / 12, d = r - c * 12;
    const float g = rb[h * 168 + r];
    const float nq = fmaxf(sqrtf(rb[h * 168 + 144 + c]), 1e-12f);
    const float nk = fmaxf(sqrtf(rb[h * 168 + 156 + d]), 1e-12f);
    attn[e] = g / (nq * nk) * temp[h];
  }
  __syncthreads();
  if (tid < 48) {
    const int h = tid / 12, c = tid - h * 12;
    float* row = &attn[h * 144 + c * 12];
    float m = row[0];
    for (int d = 1; d < 12; ++d) m = fmaxf(m, row[d]);
    float s = 0.f;
    for (int d = 0; d < 12; ++d) { const float e2 = expf(row[d] - m); row[d] = e2; s += e2; }
    const float inv = 1.f / s;
    for (int d = 0; d < 12; ++d) row[d] *= inv;
  }
  __syncthreads();
  for (int e = tid; e < 2304; e += 256) {
    const int o = e / 48, j = e - o * 48;
    const int h = j / 12, d = j - h * 12;
    float s = 0.f;
    for (int c = 0; c < 12; ++c)
      s += aow[o * 48 + h * 12 + c] * attn[h * 144 + c * 12 + d];
    Mws[b * 2304 + e] = s;
  }
}

// ========== k4a: recompute in_proj, attn-out, LN2, ffn_in [r12 verbatim] ====
__global__ __launch_bounds__(256, 3) void k4a(
    char* __restrict__ region, float4* __restrict__ s0arr,
    const float* __restrict__ x, const float* __restrict__ ipw,
    const float* __restrict__ ipb, const float* __restrict__ Mws,
    const float* __restrict__ aob, const float* __restrict__ lnw,
    const float* __restrict__ lnb, const float* __restrict__ fiw,
    const float* __restrict__ fib, const float* __restrict__ opw) {
  __shared__ __align__(16) float MT[48 * 48];     // MT[j][o]
  __shared__ __align__(16) float wT2[48 * 192];   // wT2[c][pos], pos interleaved
  __shared__ float s_aob[48], s_lnw[48], s_lnb[48], s_fib2[192], s_opw[144];
  __shared__ float s_ipw[144], s_ipb[48];
  const int tid = threadIdx.x;
  const int b = blockIdx.x >> 8;
  const int gy = blockIdx.x & 255;
  const int n = (gy << 8) + tid;
  for (int i = tid; i < 2304; i += 256) {
    const int o = i / 48, j = i - o * 48;
    MT[j * 48 + o] = Mws[b * 2304 + i];
  }
  for (int i = tid; i < 9216; i += 256) {
    const int c = i / 192, pos = i - c * 192;
    const int ch = (pos & 1) ? 96 + (pos >> 1) : (pos >> 1);
    wT2[i] = fiw[ch * 48 + c];
  }
  if (tid < 192) {
    const int ch = (tid & 1) ? 96 + (tid >> 1) : (tid >> 1);
    s_fib2[tid] = fib[ch];
  }
  if (tid < 144) { s_opw[tid] = opw[tid]; s_ipw[tid] = ipw[tid]; }
  if (tid < 48) {
    s_aob[tid] = aob[tid]; s_lnw[tid] = lnw[tid]; s_lnb[tid] = lnb[tid];
    s_ipb[tid] = ipb[tid];
  }
  __syncthreads();
  char* rowp = region + (size_t)((b << 8) + gy) * ROWB + (tid << 4);
  float vv[48];
#pragma unroll
  for (int q = 0; q < 6; ++q) {
    F4U u; u.f4 = *(const float4*)(rowp + (18 + q) * 4096);
#pragma unroll
    for (int j = 0; j < 4; ++j) {
      const float2 f = uh2f(u.u[j]);
      vv[8 * q + 2 * j] = f.x; vv[8 * q + 2 * j + 1] = f.y;
    }
  }
  float y[48];
#pragma unroll
  for (int o = 0; o < 48; ++o) y[o] = s_aob[o];
#pragma unroll 4
  for (int j = 0; j < 48; ++j) {
    const float vj = vv[j];
    const float* mr = &MT[j * 48];
#pragma unroll
    for (int o4 = 0; o4 < 12; ++o4) {
      const float4 m = *(const float4*)&mr[o4 * 4];
      y[o4 * 4 + 0] += m.x * vj; y[o4 * 4 + 1] += m.y * vj;
      y[o4 * 4 + 2] += m.z * vj; y[o4 * 4 + 3] += m.w * vj;
    }
  }
  // recompute in_proj (xp) and add residual
  const float x0 = x[((size_t)b * 3 + 0) * NPIX + n];
  const float x1 = x[((size_t)b * 3 + 1) * NPIX + n];
  const float x2 = x[((size_t)b * 3 + 2) * NPIX + n];
  float mu = 0.f;
#pragma unroll
  for (int c = 0; c < 48; ++c) {
    y[c] += s_ipw[c * 3] * x0 + s_ipw[c * 3 + 1] * x1 + s_ipw[c * 3 + 2] * x2 + s_ipb[c];
    mu += y[c];
  }
  float s0 = 0.f, s1 = 0.f, s2 = 0.f;
#pragma unroll
  for (int c = 0; c < 48; ++c) {
    s0 += s_opw[c] * y[c]; s1 += s_opw[48 + c] * y[c]; s2 += s_opw[96 + c] * y[c];
  }
  float4 s0v; s0v.x = s0; s0v.y = s1; s0v.z = s2; s0v.w = 0.f;
  s0arr[(size_t)b * NPIX + n] = s0v;
  mu *= (1.f / 48.f);
  float var = 0.f;
#pragma unroll
  for (int c = 0; c < 48; ++c) { const float d = y[c] - mu; var += d * d; }
  const float rs2 = rsqrtf(var * (1.f / 48.f) + 1e-6f);
#pragma unroll
  for (int c = 0; c < 48; ++c) y[c] = (y[c] - mu) * rs2 * s_lnw[c] + s_lnb[c];
#pragma unroll
  for (int ob = 0; ob < 12; ++ob) {
    const int o0 = ob * 16;
    float acc[16];
#pragma unroll
    for (int j = 0; j < 16; ++j) acc[j] = s_fib2[o0 + j];
#pragma unroll 4
    for (int c = 0; c < 48; ++c) {
      const float xv = y[c];
      const float4 w0 = *(const float4*)&wT2[c * 192 + o0];
      const float4 w1 = *(const float4*)&wT2[c * 192 + o0 + 4];
      const float4 w2 = *(const float4*)&wT2[c * 192 + o0 + 8];
      const float4 w3 = *(const float4*)&wT2[c * 192 + o0 + 12];
      acc[0] += w0.x * xv; acc[1] += w0.y * xv; acc[2] += w0.z * xv; acc[3] += w0.w * xv;
      acc[4] += w1.x * xv; acc[5] += w1.y * xv; acc[6] += w1.z * xv; acc[7] += w1.w * xv;
      acc[8] += w2.x * xv; acc[9] += w2.y * xv; acc[10] += w2.z * xv; acc[11] += w2.w * xv;
      acc[12] += w3.x * xv; acc[13] += w3.y * xv; acc[14] += w3.z * xv; acc[15] += w3.w * xv;
    }
    F4U u;
    u.u[0] = fpack(acc[0], acc[1]);   u.u[1] = fpack(acc[2], acc[3]);
    u.u[2] = fpack(acc[4], acc[5]);   u.u[3] = fpack(acc[6], acc[7]);
    *(float4*)(rowp + (2 * ob) * 4096) = u.f4;
    u.u[0] = fpack(acc[8], acc[9]);   u.u[1] = fpack(acc[10], acc[11]);
    u.u[2] = fpack(acc[12], acc[13]); u.u[3] = fpack(acc[14], acc[15]);
    *(float4*)(rowp + (2 * ob + 1) * 4096) = u.f4;
  }
}

// ====== k5b: dw + SimpleGate + ffn_out + out_proj [r12 verbatim] ============
__global__ __launch_bounds__(256, 3) void k5b(
    const char* __restrict__ region, const float4* __restrict__ s0arr,
    const float* __restrict__ fdww, const float* __restrict__ fdwb,
    const float* __restrict__ fow, const float* __restrict__ fob,
    const float* __restrict__ opw, const float* __restrict__ opb,
    float* __restrict__ out) {
  __shared__ unsigned int halo[12 * HSTRIDE];
  __shared__ __align__(16) float fowT[96 * 48];   // fowT[c1][o] = fow[o][c1]
  __shared__ float s_dww2[1728], s_dwb2[192], s_opw[144], s_fob[48];
  const int tid = threadIdx.x;
  for (int i = tid; i < 4608; i += 256) {
    const int c = i / 48, o = i - c * 48;
    fowT[i] = fow[o * 96 + c];
  }
  for (int i = tid; i < 1728; i += 256) {
    const int P = i / 9, t = i - P * 9;
    const int ch = (P & 1) ? 96 + (P >> 1) : (P >> 1);
    s_dww2[i] = fdww[ch * 9 + t];
  }
  if (tid < 192) {
    const int ch = (tid & 1) ? 96 + (tid >> 1) : (tid >> 1);
    s_dwb2[tid] = fdwb[ch];
  }
  if (tid < 144) s_opw[tid] = opw[tid];
  if (tid < 48) s_fob[tid] = fob[tid];
  const int b = blockIdx.x >> 8;
  const int tile = blockIdx.x & 255;
  const int ty0 = (tile >> 4) << 4, tx0 = (tile & 15) << 4;
  const int py = tid >> 4, px = tid & 15;
  const int hp = (py + 1) * 18 + (px + 1);
  const int gn = ((ty0 + py) << 8) + (tx0 + px);
  const char* regb = region + (size_t)b * REGPB;

  float4 pf[4];
  auto prefetch = [&](int cb) {
#pragma unroll
    for (int r = 0; r < 4; ++r) {
      const int i = tid + (r << 8);
      float4 z = {0.f, 0.f, 0.f, 0.f}; pf[r] = z;
      if (i < 972) {
        const int c4 = i / 324, p = i - c4 * 324;
        const int hy = p / 18, hx = p - hy * 18;
        const int gy = ty0 + hy - 1, gx = tx0 + hx - 1;
        if (((unsigned)gy < 256u) && ((unsigned)gx < 256u))
          pf[r] = *(const float4*)(regb + (size_t)gy * ROWB + (cb + c4) * 4096 + (gx << 4));
      }
    }
  };
  auto commit = [&]() {
#pragma unroll
    for (int r = 0; r < 4; ++r) {
      const int i = tid + (r << 8);
      if (i < 972) {
        const int c4 = i / 324, p = i - c4 * 324;
        F4U u; u.f4 = pf[r];
        const int pb = c4 << 2;
#pragma unroll
        for (int j = 0; j < 4; ++j) halo[(pb + j) * HSTRIDE + p] = u.u[j];
      }
    }
  };

  float facc[48];
#pragma unroll
  for (int o = 0; o < 48; ++o) facc[o] = 0.f;
  prefetch(0);
  for (int s = 0; s < 8; ++s) {
    __syncthreads(); commit(); __syncthreads();
    if (s < 7) prefetch(3 * (s + 1));
    const int offs[9] = {-19, -18, -17, -1, 0, 1, 17, 18, 19};
#pragma unroll
    for (int pp = 0; pp < 12; ++pp) {
      const int P = 24 * s + 2 * pp;
      const float* w0 = &s_dww2[P * 9];
      const float* w1 = w0 + 9;
      const unsigned int* hrow = &halo[pp * HSTRIDE + hp];
      float a = s_dwb2[P], b2 = s_dwb2[P + 1];
#pragma unroll
      for (int t = 0; t < 9; ++t) {
        const float2 f = uh2f(hrow[offs[t]]);
        a += w0[t] * f.x; b2 += w1[t] * f.y;
      }
      const float gate = a * b2;
      const float* fr = &fowT[(12 * s + pp) * 48];
#pragma unroll
      for (int o4 = 0; o4 < 12; ++o4) {
        const float4 m = *(const float4*)&fr[o4 * 4];
        facc[o4 * 4 + 0] += m.x * gate; facc[o4 * 4 + 1] += m.y * gate;
        facc[o4 * 4 + 2] += m.z * gate; facc[o4 * 4 + 3] += m.w * gate;
      }
    }
  }
  const float4 s0v = s0arr[(size_t)b * NPIX + gn];
  float r0 = s0v.x + opb[0];
  float r1 = s0v.y + opb[1];
  float r2 = s0v.z + opb[2];
#pragma unroll
  for (int o = 0; o < 48; ++o) {
    const float f = facc[o] + s_fob[o];
    r0 += s_opw[o] * f; r1 += s_opw[48 + o] * f; r2 += s_opw[96 + o] * f;
  }
  out[((size_t)b * 3 + 0) * NPIX + gn] = r0;
  out[((size_t)b * 3 + 1) * NPIX + gn] = r1;
  out[((size_t)b * 3 + 2) * NPIX + gn] = r2;
}

extern "C" void kernel_launch(void* const* d_in, const int* in_sizes, int n_in,
                              void* d_out, int out_size, void* d_ws, size_t ws_size,
                              hipStream_t stream) {
  const float* x    = (const float*)d_in[0];
  const float* ipw  = (const float*)d_in[1];
  const float* ipb  = (const float*)d_in[2];
  const float* ln1w = (const float*)d_in[3];
  const float* ln1b = (const float*)d_in[4];
  const float* qw   = (const float*)d_in[5];
  const float* qb   = (const float*)d_in[6];
  const float* qdww = (const float*)d_in[7];
  const float* qdwb = (const float*)d_in[8];
  const float* temp = (const float*)d_in[9];
  const float* aow  = (const float*)d_in[10];
  const float* aob  = (const float*)d_in[11];
  const float* ln2w = (const float*)d_in[12];
  const float* ln2b = (const float*)d_in[13];
  const float* fiw  = (const float*)d_in[14];
  const float* fib  = (const float*)d_in[15];
  const float* fdww = (const float*)d_in[16];
  const float* fdwb = (const float*)d_in[17];
  const float* fow  = (const float*)d_in[18];
  const float* fob  = (const float*)d_in[19];
  const float* opw  = (const float*)d_in[20];
  const float* opb  = (const float*)d_in[21];

  const size_t s0Per = (size_t)NPIX * 16;
  int bc = 8;
  while (bc > 1 &&
         (size_t)bc * (REGPB + s0Per) + (5376 + 18432) * 4 > ws_size)
    bc >>= 1;
  char* region = (char*)d_ws;
  float4* s0arr = (float4*)(region + (size_t)bc * REGPB);
  float* red = (float*)((char*)s0arr + (size_t)bc * s0Per);
  float* Mws = red + 5376;
  hipMemsetAsync(red, 0, 5376 * sizeof(float), stream);
  for (int b0 = 0; b0 < 8; b0 += bc) {
    kA4<<<bc * 256, 256, 0, stream>>>(x + (size_t)b0 * 3 * NPIX, ipw, ipb,
                                      ln1w, ln1b, qw, qb, qdww, qdwb,
                                      region, red + b0 * 672);
    k3_attn<<<bc, 256, 0, stream>>>(red + b0 * 672, temp, aow,
                                    Mws + (size_t)b0 * 2304);
    k4a<<<bc * 256, 256, 0, stream>>>(region, s0arr, x + (size_t)b0 * 3 * NPIX,
                                      ipw, ipb, Mws + (size_t)b0 * 2304, aob,
                                      ln2w, ln2b, fiw, fib, opw);
    k5b<<<bc * 256, 256, 0, stream>>>(region, s0arr, fdww, fdwb, fow, fob,
                                      opw, opb,
                                      (float*)d_out + (size_t)b0 * 3 * NPIX);
  }
}